// Round 1
// baseline (6654.765 us; speedup 1.0000x reference)
//
#include <hip/hip_runtime.h>
#include <math.h>

#define R1C 16384

enum { OP_STORE = 0, OP_SILU = 1, OP_RESID = 2, OP_TR = 3 };

__device__ __forceinline__ float silu_f(float x) { return x / (1.0f + expf(-x)); }
__device__ __forceinline__ float gelu_f(float x) {
  return 0.5f * x * (1.0f + erff(x * 0.70710678118654752f));
}

// ---------------- generic fp32 GEMM: C = A(MxK) @ B(KxN), tile 64x64 ----------------
__global__ __launch_bounds__(256) void gemm_f32(
    const float* __restrict__ A, int lda,
    const float* __restrict__ B, int ldb,
    float* __restrict__ C, int ldc,
    int M, int N, int K,
    const float* __restrict__ bias, int mode,
    const int* __restrict__ ids,
    const float* __restrict__ X,
    const float* __restrict__ alpha)
{
  __shared__ float As[16][68];
  __shared__ float Bs[16][68];
  int tid = threadIdx.x;
  int tx = tid & 15, ty = tid >> 4;
  int col0 = blockIdx.x * 64, row0 = blockIdx.y * 64;
  float acc[4][4] = {};
  int arow = tid >> 2;          // 0..63
  int ak   = (tid & 3) * 4;     // 0,4,8,12
  int bk   = tid >> 4;          // 0..15
  int bn   = (tid & 15) * 4;    // 0..60

  for (int kt = 0; kt < K; kt += 16) {
    float4 av = make_float4(0.f, 0.f, 0.f, 0.f);
    if (row0 + arow < M)
      av = *(const float4*)&A[(size_t)(row0 + arow) * lda + kt + ak];
    As[ak + 0][arow] = av.x; As[ak + 1][arow] = av.y;
    As[ak + 2][arow] = av.z; As[ak + 3][arow] = av.w;
    float4 bv = *(const float4*)&B[(size_t)(kt + bk) * ldb + col0 + bn];
    *(float4*)&Bs[bk][bn] = bv;
    __syncthreads();
#pragma unroll
    for (int k = 0; k < 16; ++k) {
      const float4 a4 = *(const float4*)&As[k][ty * 4];
      const float4 b4 = *(const float4*)&Bs[k][tx * 4];
      float a_[4] = {a4.x, a4.y, a4.z, a4.w};
      float b_[4] = {b4.x, b4.y, b4.z, b4.w};
#pragma unroll
      for (int i = 0; i < 4; ++i)
#pragma unroll
        for (int j = 0; j < 4; ++j)
          acc[i][j] = fmaf(a_[i], b_[j], acc[i][j]);
    }
    __syncthreads();
  }

#pragma unroll
  for (int i = 0; i < 4; ++i) {
    int r = row0 + ty * 4 + i;
    if (r >= M) continue;
#pragma unroll
    for (int j = 0; j < 4; ++j) {
      int c = col0 + tx * 4 + j;
      float val = acc[i][j] + (bias ? bias[c] : 0.0f);
      if (mode == OP_STORE) {
        C[(size_t)r * ldc + c] = val;
      } else if (mode == OP_SILU) {
        C[(size_t)r * ldc + c] = silu_f(val);
      } else if (mode == OP_RESID) {
        int hr = ids ? ids[r] : r;
        C[(size_t)hr * ldc + c] += val;
      } else { // OP_TR: X + gelu(val)*alpha
        C[(size_t)r * ldc + c] = X[(size_t)r * ldc + c] + gelu_f(val) * alpha[0];
      }
    }
  }
}

// ---------------- layernorm over 512, optional gather + leaky ----------------
__global__ __launch_bounds__(256) void ln_kernel(
    const float* __restrict__ src, const int* __restrict__ ids,
    float* __restrict__ dst, const float* __restrict__ g,
    const float* __restrict__ b, float eps, int leaky)
{
  int r = blockIdx.x;
  int sr = ids ? ids[r] : r;
  int tid = threadIdx.x;
  float v0 = src[(size_t)sr * 512 + tid];
  float v1 = src[(size_t)sr * 512 + tid + 256];
  __shared__ float red[256], red2[256];
  red[tid] = v0 + v1;
  red2[tid] = v0 * v0 + v1 * v1;
  __syncthreads();
  for (int s = 128; s > 0; s >>= 1) {
    if (tid < s) { red[tid] += red[tid + s]; red2[tid] += red2[tid + s]; }
    __syncthreads();
  }
  float mean = red[0] * (1.0f / 512.0f);
  float var  = red2[0] * (1.0f / 512.0f) - mean * mean;
  float rs = rsqrtf(var + eps);
  float o0 = (v0 - mean) * rs * g[tid] + b[tid];
  float o1 = (v1 - mean) * rs * g[tid + 256] + b[tid + 256];
  if (leaky) {
    o0 = o0 > 0.0f ? o0 : 0.1f * o0;
    o1 = o1 > 0.0f ? o1 : 0.1f * o1;
  }
  dst[(size_t)r * 512 + tid] = o0;
  dst[(size_t)r * 512 + tid + 256] = o1;
}

// ---------------- squared row norms (one wave per row) ----------------
__global__ __launch_bounds__(256) void norm2_kernel(const float* __restrict__ h,
                                                    float* __restrict__ out)
{
  int wave = threadIdx.x >> 6, lane = threadIdx.x & 63;
  int r = blockIdx.x * 4 + wave;
  const float* p = h + (size_t)r * 512;
  float s = 0.0f;
#pragma unroll
  for (int t = 0; t < 8; ++t) { float v = p[lane + t * 64]; s += v * v; }
#pragma unroll
  for (int off = 32; off > 0; off >>= 1) s += __shfl_down(s, off, 64);
  if (lane == 0) out[r] = s;
}

// ---------------- bitonic argsort of 4096 keys per sample (stable via idx tiebreak) ----------------
__global__ __launch_bounds__(1024) void sort_kernel(const float* __restrict__ norm2,
                                                    int* __restrict__ ids)
{
  __shared__ float key[4096];
  __shared__ int   val[4096];
  int s = blockIdx.x, tid = threadIdx.x;
  for (int i = tid; i < 4096; i += 1024) { key[i] = norm2[s * 4096 + i]; val[i] = i; }
  __syncthreads();
  for (int len = 2; len <= 4096; len <<= 1) {
    for (int j = len >> 1; j > 0; j >>= 1) {
      for (int t = tid; t < 2048; t += 1024) {
        int i1 = (t << 1) - (t & (j - 1));
        int i2 = i1 + j;
        bool up = ((i1 & len) == 0);
        float ka = key[i1], kb = key[i2];
        int va = val[i1], vb = val[i2];
        bool gt = (ka > kb) || (ka == kb && va > vb);
        if (gt == up) {
          key[i1] = kb; key[i2] = ka;
          val[i1] = vb; val[i2] = va;
        }
      }
      __syncthreads();
    }
  }
  for (int i = tid; i < 4096; i += 1024) ids[s * 4096 + i] = s * 4096 + val[i];
}

// ---------------- per-bucket attention scores: a = (relu(q k^T / 64))^2 ----------------
__global__ __launch_bounds__(256) void attn_kernel(
    const float* __restrict__ base,  // rows (sorted space), 256 wide
    const float* __restrict__ gb,    // gamma block: g0 at +0, g1 at +256
    const float* __restrict__ bb,    // beta block
    float* __restrict__ a_out)
{
  int g = blockIdx.x, tid = threadIdx.x;
  int tx = tid & 15, ty = tid >> 4;
  __shared__ float qT[64][68], kT[64][68];
  float acc[4][4] = {};
  for (int s0 = 0; s0 < 256; s0 += 64) {
    for (int idx = tid; idx < 64 * 64; idx += 256) {
      int l = idx >> 6, s = idx & 63;
      float v = base[((size_t)g * 64 + l) * 256 + s0 + s];
      qT[s][l] = v * gb[s0 + s] + bb[s0 + s];
      kT[s][l] = v * gb[256 + s0 + s] + bb[256 + s0 + s];
    }
    __syncthreads();
#pragma unroll 4
    for (int s = 0; s < 64; ++s) {
      const float4 q4 = *(const float4*)&qT[s][ty * 4];
      const float4 k4 = *(const float4*)&kT[s][tx * 4];
      float q_[4] = {q4.x, q4.y, q4.z, q4.w};
      float k_[4] = {k4.x, k4.y, k4.z, k4.w};
#pragma unroll
      for (int i = 0; i < 4; ++i)
#pragma unroll
        for (int j = 0; j < 4; ++j)
          acc[i][j] = fmaf(q_[i], k_[j], acc[i][j]);
    }
    __syncthreads();
  }
#pragma unroll
  for (int i = 0; i < 4; ++i)
#pragma unroll
    for (int j = 0; j < 4; ++j) {
      float v = acc[i][j] * (1.0f / 64.0f);
      v = v > 0.0f ? v : 0.0f;
      v = v * v;
      a_out[((size_t)g * 64 + ty * 4 + i) * 64 + tx * 4 + j] = v;
    }
}

// ---------------- t = (a @ v) * u, in place over u (per bucket) ----------------
__global__ __launch_bounds__(256) void attnapply_kernel(
    const float* __restrict__ a, const float* __restrict__ v,
    float* __restrict__ t, int CH)
{
  int g = blockIdx.x, tid = threadIdx.x;
  int tx = tid & 15, ty = tid >> 4;
  __shared__ float As_[64][68], Vs[64][68];
  for (int idx = tid; idx < 64 * 64; idx += 256) {
    int l = idx >> 6, m = idx & 63;
    As_[l][m] = a[((size_t)g * 64 + l) * 64 + m];
  }
  for (int e0 = 0; e0 < CH; e0 += 64) {
    for (int idx = tid; idx < 64 * 64; idx += 256) {
      int m = idx >> 6, e = idx & 63;
      Vs[m][e] = v[((size_t)g * 64 + m) * CH + e0 + e];
    }
    __syncthreads();
    float acc[4][4] = {};
#pragma unroll 4
    for (int m = 0; m < 64; ++m) {
      float a_[4];
#pragma unroll
      for (int i = 0; i < 4; ++i) a_[i] = As_[ty * 4 + i][m];
      const float4 v4 = *(const float4*)&Vs[m][tx * 4];
      float v_[4] = {v4.x, v4.y, v4.z, v4.w};
#pragma unroll
      for (int i = 0; i < 4; ++i)
#pragma unroll
        for (int j = 0; j < 4; ++j)
          acc[i][j] = fmaf(a_[i], v_[j], acc[i][j]);
    }
#pragma unroll
    for (int i = 0; i < 4; ++i)
#pragma unroll
      for (int j = 0; j < 4; ++j) {
        size_t off = ((size_t)g * 64 + ty * 4 + i) * CH + e0 + tx * 4 + j;
        t[off] = acc[i][j] * t[off];
      }
    __syncthreads();
  }
}

// ---------------- mean over groups of 64 rows (optional gather) ----------------
__global__ __launch_bounds__(256) void bucketmean_kernel(
    const float* __restrict__ src, const int* __restrict__ ids,
    float* __restrict__ dst)
{
  int g = blockIdx.x, tid = threadIdx.x;
  float s0 = 0.0f, s1 = 0.0f;
  for (int i = 0; i < 64; ++i) {
    int r = g * 64 + i;
    if (ids) r = ids[r];
    s0 += src[(size_t)r * 512 + tid];
    s1 += src[(size_t)r * 512 + tid + 256];
  }
  dst[(size_t)g * 512 + tid] = s0 * (1.0f / 64.0f);
  dst[(size_t)g * 512 + tid + 256] = s1 * (1.0f / 64.0f);
}

__global__ void avg_kernel(const float* __restrict__ a, const float* __restrict__ b,
                           float* __restrict__ o, int n)
{
  int i = blockIdx.x * 256 + threadIdx.x;
  if (i < n) o[i] = 0.5f * (a[i] + b[i]);
}

__global__ void out_kernel(const float* __restrict__ y, const float* __restrict__ W,
                           const float* __restrict__ b, float* __restrict__ out)
{
  int tid = threadIdx.x;
  if (tid < 8) {
    int s = tid >> 1, j = tid & 1;
    float acc = b[j];
    for (int d = 0; d < 512; ++d) acc += y[s * 512 + d] * W[d * 2 + j];
    out[s * 2 + j] = acc;
  }
}

extern "C" void kernel_launch(void* const* d_in, const int* in_sizes, int n_in,
                              void* d_out, int out_size, void* d_ws, size_t ws_size,
                              hipStream_t stream)
{
  const float* xs       = (const float*)d_in[0];
  const float* W_in     = (const float*)d_in[1];
  const float* b_in     = (const float*)d_in[2];
  const float* ln_in_g  = (const float*)d_in[3];
  const float* ln_in_b  = (const float*)d_in[4];
  const float* blk_ln_g = (const float*)d_in[5];
  const float* blk_ln_b = (const float*)d_in[6];
  const float* blk_Wuv  = (const float*)d_in[7];
  const float* blk_buv  = (const float*)d_in[8];
  const float* blk_gam  = (const float*)d_in[9];
  const float* blk_bet  = (const float*)d_in[10];
  const float* blk_Wo   = (const float*)d_in[11];
  const float* blk_bo   = (const float*)d_in[12];
  const float* tr_W     = (const float*)d_in[13];
  const float* tr_b     = (const float*)d_in[14];
  const float* tr_a     = (const float*)d_in[15];
  const float* tr2_W    = (const float*)d_in[16];
  const float* tr2_b    = (const float*)d_in[17];
  const float* tr2_a    = (const float*)d_in[18];
  const float* out_W    = (const float*)d_in[19];
  const float* out_b    = (const float*)d_in[20];
  float* outp = (float*)d_out;

  const size_t R1 = R1C;
  size_t fixedf = R1 * 512 * 2 + R1 * 256 + (size_t)256 * 64 * 64 + R1 + R1
                + (size_t)256 * 512 * 2 + 5 * 4 * 512;
  int CH = 64;
  const int cand[4] = {768, 384, 256, 128};
  for (int ci = 0; ci < 4; ++ci) {
    size_t need = (fixedf + 2 * R1 * (size_t)cand[ci]) * 4;
    if (need <= ws_size) { CH = cand[ci]; break; }
  }

  float* p = (float*)d_ws;
  float* h      = p; p += R1 * 512;
  float* nb     = p; p += R1 * 512;
  float* baseb  = p; p += R1 * 256;
  float* ab     = p; p += (size_t)256 * 64 * 64;
  float* norm2b = p; p += R1;
  int*   idsb   = (int*)p; p += R1;
  float* gy     = p; p += (size_t)256 * 512;
  float* tl     = p; p += (size_t)256 * 512;
  float* gy2    = p; p += 4 * 512;
  float* ys0    = p; p += 4 * 512;
  float* ys1    = p; p += 4 * 512;
  float* yv     = p; p += 4 * 512;
  float* y2     = p; p += 4 * 512;
  float* ub     = p; p += R1 * (size_t)CH;
  float* vb     = p;

  dim3 blk(256);

  // ---- Stage A: input projection + LN(1e-8) + leaky ----
  gemm_f32<<<dim3(8, 256), blk, 0, stream>>>(xs, 768, W_in, 512, nb, 512,
      16384, 512, 768, b_in, OP_STORE, nullptr, nullptr, nullptr);
  ln_kernel<<<16384, 256, 0, stream>>>(nb, nullptr, h, ln_in_g, ln_in_b, 1e-8f, 1);

  // ---- Iteration 1: sort into 64 buckets per sample ----
  norm2_kernel<<<4096, 256, 0, stream>>>(h, norm2b);
  sort_kernel<<<4, 1024, 0, stream>>>(norm2b, idsb);

  for (int b = 0; b < 6; ++b) {
    const float* Wuv = blk_Wuv + (size_t)b * 512 * 1792;
    const float* buv = blk_buv + b * 1792;
    const float* Wo  = blk_Wo + (size_t)b * 768 * 512;
    ln_kernel<<<16384, 256, 0, stream>>>(h, idsb, nb, blk_ln_g + b * 512,
                                         blk_ln_b + b * 512, 1e-5f, 0);
    gemm_f32<<<dim3(4, 256), blk, 0, stream>>>(nb, 512, Wuv + 1536, 1792, baseb, 256,
        16384, 256, 512, buv + 1536, OP_SILU, nullptr, nullptr, nullptr);
    attn_kernel<<<256, 256, 0, stream>>>(baseb, blk_gam + b * 512, blk_bet + b * 512, ab);
    for (int c0 = 0; c0 < 768; c0 += CH) {
      gemm_f32<<<dim3(CH / 64, 256), blk, 0, stream>>>(nb, 512, Wuv + c0, 1792, ub, CH,
          16384, CH, 512, buv + c0, OP_SILU, nullptr, nullptr, nullptr);
      gemm_f32<<<dim3(CH / 64, 256), blk, 0, stream>>>(nb, 512, Wuv + 768 + c0, 1792, vb, CH,
          16384, CH, 512, buv + 768 + c0, OP_SILU, nullptr, nullptr, nullptr);
      attnapply_kernel<<<256, 256, 0, stream>>>(ab, vb, ub, CH);
      const float* bo = (c0 + CH == 768) ? (blk_bo + b * 512) : nullptr;
      gemm_f32<<<dim3(8, 256), blk, 0, stream>>>(ub, CH, Wo + (size_t)c0 * 512, 512,
          h, 512, 16384, 512, CH, bo, OP_RESID, idsb, nullptr, nullptr);
    }
  }
  bucketmean_kernel<<<256, 256, 0, stream>>>(h, idsb, gy);

  // ---- ys0 = mean_buckets(tr_layer(gy)) ----
  gemm_f32<<<dim3(8, 4), blk, 0, stream>>>(gy, 512, tr_W, 512, tl, 512,
      256, 512, 512, tr_b, OP_TR, nullptr, gy, tr_a);
  bucketmean_kernel<<<4, 256, 0, stream>>>(tl, nullptr, ys0);

  // ---- Iteration 2: 64 rows/sample == single bucket; sort provably unnecessary ----
  for (int b = 0; b < 6; ++b) {
    const float* Wuv = blk_Wuv + (size_t)b * 512 * 1792;
    const float* buv = blk_buv + b * 1792;
    const float* Wo  = blk_Wo + (size_t)b * 768 * 512;
    ln_kernel<<<256, 256, 0, stream>>>(gy, nullptr, nb, blk_ln_g + b * 512,
                                       blk_ln_b + b * 512, 1e-5f, 0);
    gemm_f32<<<dim3(4, 4), blk, 0, stream>>>(nb, 512, Wuv + 1536, 1792, baseb, 256,
        256, 256, 512, buv + 1536, OP_SILU, nullptr, nullptr, nullptr);
    attn_kernel<<<4, 256, 0, stream>>>(baseb, blk_gam + b * 512, blk_bet + b * 512, ab);
    for (int c0 = 0; c0 < 768; c0 += CH) {
      gemm_f32<<<dim3(CH / 64, 4), blk, 0, stream>>>(nb, 512, Wuv + c0, 1792, ub, CH,
          256, CH, 512, buv + c0, OP_SILU, nullptr, nullptr, nullptr);
      gemm_f32<<<dim3(CH / 64, 4), blk, 0, stream>>>(nb, 512, Wuv + 768 + c0, 1792, vb, CH,
          256, CH, 512, buv + 768 + c0, OP_SILU, nullptr, nullptr, nullptr);
      attnapply_kernel<<<4, 256, 0, stream>>>(ab, vb, ub, CH);
      const float* bo = (c0 + CH == 768) ? (blk_bo + b * 512) : nullptr;
      gemm_f32<<<dim3(8, 4), blk, 0, stream>>>(ub, CH, Wo + (size_t)c0 * 512, 512,
          gy, 512, 256, 512, CH, bo, OP_RESID, nullptr, nullptr, nullptr);
    }
  }
  bucketmean_kernel<<<4, 256, 0, stream>>>(gy, nullptr, gy2);

  // ---- ys1 = tr_layer(gy2); y = (ys0+ys1)/2; y = tr_layer(y, tr2); out ----
  gemm_f32<<<dim3(8, 1), blk, 0, stream>>>(gy2, 512, tr_W, 512, ys1, 512,
      4, 512, 512, tr_b, OP_TR, nullptr, gy2, tr_a);
  avg_kernel<<<8, 256, 0, stream>>>(ys0, ys1, yv, 2048);
  gemm_f32<<<dim3(8, 1), blk, 0, stream>>>(yv, 512, tr2_W, 512, y2, 512,
      4, 512, 512, tr2_b, OP_TR, nullptr, yv, tr2_a);
  out_kernel<<<1, 64, 0, stream>>>(y2, out_W, out_b, outp);
}

// Round 3
// 3123.774 us; speedup vs baseline: 2.1304x; 2.1304x over previous
//
#include <hip/hip_runtime.h>
#include <math.h>

#define R1C 16384

enum { OP_STORE = 0, OP_SILU = 1, OP_RESID = 2, OP_TR = 3 };

typedef _Float16 f16x8 __attribute__((ext_vector_type(8)));
typedef float f32x4 __attribute__((ext_vector_type(4)));

__device__ __forceinline__ float silu_f(float x) { return x / (1.0f + expf(-x)); }
__device__ __forceinline__ float gelu_f(float x) {
  return 0.5f * x * (1.0f + erff(x * 0.70710678118654752f));
}

__device__ __forceinline__ void gll16(const void* g, const void* l) {
  __builtin_amdgcn_global_load_lds(
      (const __attribute__((address_space(1))) unsigned int*)g,
      (__attribute__((address_space(3))) unsigned int*)l, 16, 0, 0);
}

// ============ f16 MFMA GEMM: C(MxN f32) = A(MxK f16,row) @ Bt(NxK f16,row)^T ======
// Requires M%128==0, N%128==0, K%32==0. 128x128 tile, 4 waves of 4x4 16x16x32 MFMA.
__global__ __launch_bounds__(256) void gemm_f16(
    const _Float16* __restrict__ A, int lda,
    const _Float16* __restrict__ Bt, int ldb,
    float* __restrict__ C, int ldc, int K,
    const float* __restrict__ bias, int mode,
    const int* __restrict__ ids)
{
  __shared__ _Float16 As[128 * 32];
  __shared__ _Float16 Bs[128 * 32];
  int tid = threadIdx.x;
  int lane = tid & 63, w = tid >> 6;
  int wm = w >> 1, wn = w & 1;
  int row0 = blockIdx.y * 128, col0 = blockIdx.x * 128;

  // staging: 512 slots of 16B per tile; thread handles slots tid and tid+256.
  // physical slot for logical (row m, kgroup kg) is m*4 + (kg ^ (m&3))  (XOR swizzle)
  int p0 = w * 64 + lane;
  int p1 = 256 + w * 64 + lane;
  int m0 = p0 >> 2, k0e = ((p0 & 3) ^ (m0 & 3)) * 8;
  int m1 = p1 >> 2, k1e = ((p1 & 3) ^ (m1 & 3)) * 8;
  const _Float16* gA0 = A + (size_t)(row0 + m0) * lda + k0e;
  const _Float16* gA1 = A + (size_t)(row0 + m1) * lda + k1e;
  const _Float16* gB0 = Bt + (size_t)(col0 + m0) * ldb + k0e;
  const _Float16* gB1 = Bt + (size_t)(col0 + m1) * ldb + k1e;
  const _Float16* lA0 = As + (size_t)(w * 64) * 8;       // wave-uniform LDS bases
  const _Float16* lA1 = As + (size_t)(256 + w * 64) * 8;
  const _Float16* lB0 = Bs + (size_t)(w * 64) * 8;
  const _Float16* lB1 = Bs + (size_t)(256 + w * 64) * 8;

  // fragment LDS offsets (swizzled): A[m=lane&15][k=quad*8+j]
  int mrow = lane & 15, quad = lane >> 4;
  const f16x8* aptr[4];
  const f16x8* bptr[4];
#pragma unroll
  for (int t = 0; t < 4; ++t) {
    int ml = wm * 64 + t * 16 + mrow;
    aptr[t] = (const f16x8*)(As + (size_t)(ml * 4 + (quad ^ (ml & 3))) * 8);
    int nl = wn * 64 + t * 16 + mrow;
    bptr[t] = (const f16x8*)(Bs + (size_t)(nl * 4 + (quad ^ (nl & 3))) * 8);
  }

  f32x4 acc[4][4] = {};

  for (int kt = 0; kt < K; kt += 32) {
    gll16(gA0, lA0); gll16(gA1, lA1);
    gll16(gB0, lB0); gll16(gB1, lB1);
    gA0 += 32; gA1 += 32; gB0 += 32; gB1 += 32;
    __syncthreads();
    f16x8 af[4], bfr[4];
#pragma unroll
    for (int t = 0; t < 4; ++t) { af[t] = *aptr[t]; bfr[t] = *bptr[t]; }
#pragma unroll
    for (int mt = 0; mt < 4; ++mt)
#pragma unroll
      for (int nt = 0; nt < 4; ++nt)
        acc[mt][nt] = __builtin_amdgcn_mfma_f32_16x16x32_f16(
            af[mt], bfr[nt], acc[mt][nt], 0, 0, 0);
    __syncthreads();
  }

  // epilogue: C/D layout col=lane&15, row=quad*4+reg
#pragma unroll
  for (int mt = 0; mt < 4; ++mt) {
#pragma unroll
    for (int nt = 0; nt < 4; ++nt) {
      int c = col0 + wn * 64 + nt * 16 + mrow;
      float bv = bias ? bias[c] : 0.0f;
#pragma unroll
      for (int reg = 0; reg < 4; ++reg) {
        int r = row0 + wm * 64 + mt * 16 + quad * 4 + reg;
        float val = acc[mt][nt][reg] + bv;
        if (mode == OP_STORE) {
          C[(size_t)r * ldc + c] = val;
        } else if (mode == OP_SILU) {
          C[(size_t)r * ldc + c] = silu_f(val);
        } else { // OP_RESID
          int hr = ids ? ids[r] : r;
          C[(size_t)hr * ldc + c] += val;
        }
      }
    }
  }
}

// ---------------- generic fp32 GEMM (stage A + small tails) ----------------
__global__ __launch_bounds__(256) void gemm_f32(
    const float* __restrict__ A, int lda,
    const float* __restrict__ B, int ldb,
    float* __restrict__ C, int ldc,
    int M, int N, int K,
    const float* __restrict__ bias, int mode,
    const int* __restrict__ ids,
    const float* __restrict__ X,
    const float* __restrict__ alpha)
{
  __shared__ float As[16][68];
  __shared__ float Bs[16][68];
  int tid = threadIdx.x;
  int tx = tid & 15, ty = tid >> 4;
  int col0 = blockIdx.x * 64, row0 = blockIdx.y * 64;
  float acc[4][4] = {};
  int arow = tid >> 2;
  int ak   = (tid & 3) * 4;
  int bk   = tid >> 4;
  int bn   = (tid & 15) * 4;

  for (int kt = 0; kt < K; kt += 16) {
    float4 av = make_float4(0.f, 0.f, 0.f, 0.f);
    if (row0 + arow < M)
      av = *(const float4*)&A[(size_t)(row0 + arow) * lda + kt + ak];
    As[ak + 0][arow] = av.x; As[ak + 1][arow] = av.y;
    As[ak + 2][arow] = av.z; As[ak + 3][arow] = av.w;
    float4 bv = *(const float4*)&B[(size_t)(kt + bk) * ldb + col0 + bn];
    *(float4*)&Bs[bk][bn] = bv;
    __syncthreads();
#pragma unroll
    for (int k = 0; k < 16; ++k) {
      const float4 a4 = *(const float4*)&As[k][ty * 4];
      const float4 b4 = *(const float4*)&Bs[k][tx * 4];
      float a_[4] = {a4.x, a4.y, a4.z, a4.w};
      float b_[4] = {b4.x, b4.y, b4.z, b4.w};
#pragma unroll
      for (int i = 0; i < 4; ++i)
#pragma unroll
        for (int j = 0; j < 4; ++j)
          acc[i][j] = fmaf(a_[i], b_[j], acc[i][j]);
    }
    __syncthreads();
  }

#pragma unroll
  for (int i = 0; i < 4; ++i) {
    int r = row0 + ty * 4 + i;
    if (r >= M) continue;
#pragma unroll
    for (int j = 0; j < 4; ++j) {
      int c = col0 + tx * 4 + j;
      float val = acc[i][j] + (bias ? bias[c] : 0.0f);
      if (mode == OP_STORE) {
        C[(size_t)r * ldc + c] = val;
      } else if (mode == OP_SILU) {
        C[(size_t)r * ldc + c] = silu_f(val);
      } else if (mode == OP_RESID) {
        int hr = ids ? ids[r] : r;
        C[(size_t)hr * ldc + c] += val;
      } else { // OP_TR
        C[(size_t)r * ldc + c] = X[(size_t)r * ldc + c] + gelu_f(val) * alpha[0];
      }
    }
  }
}

// ---------------- weight transpose + cast: in(K x N f32) -> out(N x K f16) ----------
__global__ __launch_bounds__(256) void transpose_cast(
    const float* __restrict__ in, _Float16* __restrict__ out, int K, int N)
{
  in  += (size_t)blockIdx.z * K * N;
  out += (size_t)blockIdx.z * K * N;
  __shared__ float t[32][33];
  int k0 = blockIdx.y * 32, n0 = blockIdx.x * 32;
  int tx = threadIdx.x & 31, ty = threadIdx.x >> 5;
  for (int i = ty; i < 32; i += 8) {
    int k = k0 + i, n = n0 + tx;
    t[i][tx] = (k < K && n < N) ? in[(size_t)k * N + n] : 0.0f;
  }
  __syncthreads();
  for (int i = ty; i < 32; i += 8) {
    int n = n0 + i, k = k0 + tx;
    if (n < N && k < K) out[(size_t)n * K + k] = (_Float16)t[tx][i];
  }
}

// ---------------- layernorm over 512, optional gather + leaky, templated out --------
template <typename OUT>
__global__ __launch_bounds__(256) void ln_kernel(
    const float* __restrict__ src, const int* __restrict__ ids,
    OUT* __restrict__ dst, const float* __restrict__ g,
    const float* __restrict__ b, float eps, int leaky)
{
  int r = blockIdx.x;
  int sr = ids ? ids[r] : r;
  int tid = threadIdx.x;
  float v0 = src[(size_t)sr * 512 + tid];
  float v1 = src[(size_t)sr * 512 + tid + 256];
  __shared__ float red[256], red2[256];
  red[tid] = v0 + v1;
  red2[tid] = v0 * v0 + v1 * v1;
  __syncthreads();
  for (int s = 128; s > 0; s >>= 1) {
    if (tid < s) { red[tid] += red[tid + s]; red2[tid] += red2[tid + s]; }
    __syncthreads();
  }
  float mean = red[0] * (1.0f / 512.0f);
  float var  = red2[0] * (1.0f / 512.0f) - mean * mean;
  float rs = rsqrtf(var + eps);
  float o0 = (v0 - mean) * rs * g[tid] + b[tid];
  float o1 = (v1 - mean) * rs * g[tid + 256] + b[tid + 256];
  if (leaky) {
    o0 = o0 > 0.0f ? o0 : 0.1f * o0;
    o1 = o1 > 0.0f ? o1 : 0.1f * o1;
  }
  dst[(size_t)r * 512 + tid] = (OUT)o0;
  dst[(size_t)r * 512 + tid + 256] = (OUT)o1;
}

// ---------------- squared row norms ----------------
__global__ __launch_bounds__(256) void norm2_kernel(const float* __restrict__ h,
                                                    float* __restrict__ out)
{
  int wave = threadIdx.x >> 6, lane = threadIdx.x & 63;
  int r = blockIdx.x * 4 + wave;
  const float* p = h + (size_t)r * 512;
  float s = 0.0f;
#pragma unroll
  for (int t = 0; t < 8; ++t) { float v = p[lane + t * 64]; s += v * v; }
#pragma unroll
  for (int off = 32; off > 0; off >>= 1) s += __shfl_down(s, off, 64);
  if (lane == 0) out[r] = s;
}

// ---------------- bitonic argsort of 4096 keys per sample ----------------
__global__ __launch_bounds__(1024) void sort_kernel(const float* __restrict__ norm2,
                                                    int* __restrict__ ids)
{
  __shared__ float key[4096];
  __shared__ int   val[4096];
  int s = blockIdx.x, tid = threadIdx.x;
  for (int i = tid; i < 4096; i += 1024) { key[i] = norm2[s * 4096 + i]; val[i] = i; }
  __syncthreads();
  for (int len = 2; len <= 4096; len <<= 1) {
    for (int j = len >> 1; j > 0; j >>= 1) {
      for (int t = tid; t < 2048; t += 1024) {
        int i1 = (t << 1) - (t & (j - 1));
        int i2 = i1 + j;
        bool up = ((i1 & len) == 0);
        float ka = key[i1], kb = key[i2];
        int va = val[i1], vb = val[i2];
        bool gt = (ka > kb) || (ka == kb && va > vb);
        if (gt == up) {
          key[i1] = kb; key[i2] = ka;
          val[i1] = vb; val[i2] = va;
        }
      }
      __syncthreads();
    }
  }
  for (int i = tid; i < 4096; i += 1024) ids[s * 4096 + i] = s * 4096 + val[i];
}

// ---------------- per-bucket attention scores: a = (relu(q k^T / 64))^2 ----------
__global__ __launch_bounds__(256) void attn_kernel(
    const float* __restrict__ base, const float* __restrict__ gb,
    const float* __restrict__ bb, float* __restrict__ a_out)
{
  int g = blockIdx.x, tid = threadIdx.x;
  int tx = tid & 15, ty = tid >> 4;
  __shared__ float qT[64][68], kT[64][68];
  float acc[4][4] = {};
  for (int s0 = 0; s0 < 256; s0 += 64) {
    for (int idx = tid; idx < 64 * 64; idx += 256) {
      int l = idx >> 6, s = idx & 63;
      float v = base[((size_t)g * 64 + l) * 256 + s0 + s];
      qT[s][l] = v * gb[s0 + s] + bb[s0 + s];
      kT[s][l] = v * gb[256 + s0 + s] + bb[256 + s0 + s];
    }
    __syncthreads();
#pragma unroll 4
    for (int s = 0; s < 64; ++s) {
      const float4 q4 = *(const float4*)&qT[s][ty * 4];
      const float4 k4 = *(const float4*)&kT[s][tx * 4];
      float q_[4] = {q4.x, q4.y, q4.z, q4.w};
      float k_[4] = {k4.x, k4.y, k4.z, k4.w};
#pragma unroll
      for (int i = 0; i < 4; ++i)
#pragma unroll
        for (int j = 0; j < 4; ++j)
          acc[i][j] = fmaf(q_[i], k_[j], acc[i][j]);
    }
    __syncthreads();
  }
#pragma unroll
  for (int i = 0; i < 4; ++i)
#pragma unroll
    for (int j = 0; j < 4; ++j) {
      float v = acc[i][j] * (1.0f / 64.0f);
      v = v > 0.0f ? v : 0.0f;
      v = v * v;
      a_out[((size_t)g * 64 + ty * 4 + i) * 64 + tx * 4 + j] = v;
    }
}

// ---------------- t = (a @ v) * u  (a,v,u fp32; t fp16 for Wo MFMA input) ---------
__global__ __launch_bounds__(256) void attnapply_kernel(
    const float* __restrict__ a, const float* __restrict__ v,
    const float* __restrict__ u, _Float16* __restrict__ t, int CH)
{
  int g = blockIdx.x, tid = threadIdx.x;
  int tx = tid & 15, ty = tid >> 4;
  __shared__ float As_[64][68], Vs[64][68];
  for (int idx = tid; idx < 64 * 64; idx += 256) {
    int l = idx >> 6, m = idx & 63;
    As_[l][m] = a[((size_t)g * 64 + l) * 64 + m];
  }
  for (int e0 = 0; e0 < CH; e0 += 64) {
    for (int idx = tid; idx < 64 * 64; idx += 256) {
      int m = idx >> 6, e = idx & 63;
      Vs[m][e] = v[((size_t)g * 64 + m) * CH + e0 + e];
    }
    __syncthreads();
    float acc[4][4] = {};
#pragma unroll 4
    for (int m = 0; m < 64; ++m) {
      float a_[4];
#pragma unroll
      for (int i = 0; i < 4; ++i) a_[i] = As_[ty * 4 + i][m];
      const float4 v4 = *(const float4*)&Vs[m][tx * 4];
      float v_[4] = {v4.x, v4.y, v4.z, v4.w};
#pragma unroll
      for (int i = 0; i < 4; ++i)
#pragma unroll
        for (int j = 0; j < 4; ++j)
          acc[i][j] = fmaf(a_[i], v_[j], acc[i][j]);
    }
#pragma unroll
    for (int i = 0; i < 4; ++i)
#pragma unroll
      for (int j = 0; j < 4; ++j) {
        size_t off = ((size_t)g * 64 + ty * 4 + i) * CH + e0 + tx * 4 + j;
        t[off] = (_Float16)(acc[i][j] * u[off]);
      }
    __syncthreads();
  }
}

// ---------------- mean over groups of 64 rows (optional gather) ----------------
__global__ __launch_bounds__(256) void bucketmean_kernel(
    const float* __restrict__ src, const int* __restrict__ ids,
    float* __restrict__ dst)
{
  int g = blockIdx.x, tid = threadIdx.x;
  float s0 = 0.0f, s1 = 0.0f;
  for (int i = 0; i < 64; ++i) {
    int r = g * 64 + i;
    if (ids) r = ids[r];
    s0 += src[(size_t)r * 512 + tid];
    s1 += src[(size_t)r * 512 + tid + 256];
  }
  dst[(size_t)g * 512 + tid] = s0 * (1.0f / 64.0f);
  dst[(size_t)g * 512 + tid + 256] = s1 * (1.0f / 64.0f);
}

__global__ void avg_kernel(const float* __restrict__ a, const float* __restrict__ b,
                           float* __restrict__ o, int n)
{
  int i = blockIdx.x * 256 + threadIdx.x;
  if (i < n) o[i] = 0.5f * (a[i] + b[i]);
}

__global__ void out_kernel(const float* __restrict__ y, const float* __restrict__ W,
                           const float* __restrict__ b, float* __restrict__ out)
{
  int tid = threadIdx.x;
  if (tid < 8) {
    int s = tid >> 1, j = tid & 1;
    float acc = b[j];
    for (int d = 0; d < 512; ++d) acc += y[s * 512 + d] * W[d * 2 + j];
    out[s * 2 + j] = acc;
  }
}

extern "C" void kernel_launch(void* const* d_in, const int* in_sizes, int n_in,
                              void* d_out, int out_size, void* d_ws, size_t ws_size,
                              hipStream_t stream)
{
  const float* xs       = (const float*)d_in[0];
  const float* W_in     = (const float*)d_in[1];
  const float* b_in     = (const float*)d_in[2];
  const float* ln_in_g  = (const float*)d_in[3];
  const float* ln_in_b  = (const float*)d_in[4];
  const float* blk_ln_g = (const float*)d_in[5];
  const float* blk_ln_b = (const float*)d_in[6];
  const float* blk_Wuv  = (const float*)d_in[7];
  const float* blk_buv  = (const float*)d_in[8];
  const float* blk_gam  = (const float*)d_in[9];
  const float* blk_bet  = (const float*)d_in[10];
  const float* blk_Wo   = (const float*)d_in[11];
  const float* blk_bo   = (const float*)d_in[12];
  const float* tr_W     = (const float*)d_in[13];
  const float* tr_b     = (const float*)d_in[14];
  const float* tr_a     = (const float*)d_in[15];
  const float* tr2_W    = (const float*)d_in[16];
  const float* tr2_b    = (const float*)d_in[17];
  const float* tr2_a    = (const float*)d_in[18];
  const float* out_W    = (const float*)d_in[19];
  const float* out_b    = (const float*)d_in[20];
  float* outp = (float*)d_out;

  const size_t R1 = R1C;

  // ---- workspace carve (bytes) ----
  char* base = (char*)d_ws;
  size_t off = 0;
  auto carve = [&](size_t bytes) {
    char* r = base + off;
    off = (off + bytes + 255) & ~(size_t)255;
    return (void*)r;
  };
  float* h      = (float*)carve(R1 * 512 * 4);
  float* nb     = (float*)carve(R1 * 512 * 4);        // f32 view (stage A)
  _Float16* nb_f16 = (_Float16*)nb;                   // f16 view (block LNs)
  float* baseb  = (float*)carve(R1 * 256 * 4);
  float* ab     = (float*)carve((size_t)256 * 64 * 64 * 4);
  float* norm2b = (float*)carve(R1 * 4);
  int*   idsb   = (int*)carve(R1 * 4);
  float* gy     = (float*)carve((size_t)256 * 512 * 4);
  float* tl     = (float*)carve((size_t)256 * 512 * 4);
  float* gy2    = (float*)carve(4 * 512 * 4);
  float* ys0    = (float*)carve(4 * 512 * 4);
  float* ys1    = (float*)carve(4 * 512 * 4);
  float* yv     = (float*)carve(4 * 512 * 4);
  float* y2     = (float*)carve(4 * 512 * 4);
  _Float16* Wuvt = (_Float16*)carve((size_t)6 * 1792 * 512 * 2);
  _Float16* Wot  = (_Float16*)carve((size_t)6 * 512 * 768 * 2);
  size_t fixed_bytes = off;

  int CH = 128;
  const int cand[4] = {768, 384, 256, 128};
  for (int ci = 0; ci < 4; ++ci) {
    // ub f32 + vb f32 + tb f16 = 10 bytes per element
    size_t need = fixed_bytes + 3 * 256 + 10 * R1 * (size_t)cand[ci];
    if (need <= ws_size) { CH = cand[ci]; break; }
  }
  float*    ub = (float*)carve(R1 * (size_t)CH * 4);
  float*    vb = (float*)carve(R1 * (size_t)CH * 4);
  _Float16* tb = (_Float16*)carve(R1 * (size_t)CH * 2);

  dim3 blk(256);

  // ---- weight prep: transpose+cast to f16 N x K ----
  transpose_cast<<<dim3(56, 16, 6), blk, 0, stream>>>(blk_Wuv, Wuvt, 512, 1792);
  transpose_cast<<<dim3(16, 24, 6), blk, 0, stream>>>(blk_Wo, Wot, 768, 512);

  // ---- Stage A: input projection (fp32 => exact sort keys) + LN(1e-8) + leaky ----
  gemm_f32<<<dim3(8, 256), blk, 0, stream>>>(xs, 768, W_in, 512, nb, 512,
      16384, 512, 768, b_in, OP_STORE, nullptr, nullptr, nullptr);
  ln_kernel<float><<<16384, 256, 0, stream>>>(nb, nullptr, h, ln_in_g, ln_in_b, 1e-8f, 1);

  // ---- Iteration 1: sort into 64 buckets per sample ----
  norm2_kernel<<<4096, 256, 0, stream>>>(h, norm2b);
  sort_kernel<<<4, 1024, 0, stream>>>(norm2b, idsb);

  for (int b = 0; b < 6; ++b) {
    const _Float16* Wuv_t = Wuvt + (size_t)b * 1792 * 512;  // (1792 x 512) = Wuv^T
    const float*    buv   = blk_buv + b * 1792;
    const _Float16* Wo_t  = Wot + (size_t)b * 512 * 768;    // (512 x 768) = Wo^T
    ln_kernel<_Float16><<<16384, 256, 0, stream>>>(h, idsb, nb_f16, blk_ln_g + b * 512,
                                                   blk_ln_b + b * 512, 1e-5f, 0);
    gemm_f16<<<dim3(2, 128), blk, 0, stream>>>(nb_f16, 512, Wuv_t + (size_t)1536 * 512, 512,
        baseb, 256, 512, buv + 1536, OP_SILU, nullptr);
    attn_kernel<<<256, 256, 0, stream>>>(baseb, blk_gam + b * 512, blk_bet + b * 512, ab);
    for (int c0 = 0; c0 < 768; c0 += CH) {
      gemm_f16<<<dim3(CH / 128, 128), blk, 0, stream>>>(nb_f16, 512,
          Wuv_t + (size_t)c0 * 512, 512, ub, CH, 512, buv + c0, OP_SILU, nullptr);
      gemm_f16<<<dim3(CH / 128, 128), blk, 0, stream>>>(nb_f16, 512,
          Wuv_t + (size_t)(768 + c0) * 512, 512, vb, CH, 512, buv + 768 + c0, OP_SILU, nullptr);
      attnapply_kernel<<<256, 256, 0, stream>>>(ab, vb, ub, tb, CH);
      const float* bo = (c0 + CH == 768) ? (blk_bo + b * 512) : nullptr;
      gemm_f16<<<dim3(4, 128), blk, 0, stream>>>(tb, CH, Wo_t + c0, 768,
          h, 512, CH, bo, OP_RESID, idsb);
    }
  }
  bucketmean_kernel<<<256, 256, 0, stream>>>(h, idsb, gy);

  // ---- ys0 = mean_buckets(tr_layer(gy)) ----
  gemm_f32<<<dim3(8, 4), blk, 0, stream>>>(gy, 512, tr_W, 512, tl, 512,
      256, 512, 512, tr_b, OP_TR, nullptr, gy, tr_a);
  bucketmean_kernel<<<4, 256, 0, stream>>>(tl, nullptr, ys0);

  // ---- Iteration 2: 64 rows/sample == 1 bucket; sort permutation provably cancels --
  for (int b = 0; b < 6; ++b) {
    const _Float16* Wuv_t = Wuvt + (size_t)b * 1792 * 512;
    const float*    buv   = blk_buv + b * 1792;
    const _Float16* Wo_t  = Wot + (size_t)b * 512 * 768;
    ln_kernel<_Float16><<<256, 256, 0, stream>>>(gy, nullptr, nb_f16, blk_ln_g + b * 512,
                                                 blk_ln_b + b * 512, 1e-5f, 0);
    gemm_f16<<<dim3(2, 2), blk, 0, stream>>>(nb_f16, 512, Wuv_t + (size_t)1536 * 512, 512,
        baseb, 256, 512, buv + 1536, OP_SILU, nullptr);
    attn_kernel<<<4, 256, 0, stream>>>(baseb, blk_gam + b * 512, blk_bet + b * 512, ab);
    for (int c0 = 0; c0 < 768; c0 += CH) {
      gemm_f16<<<dim3(CH / 128, 2), blk, 0, stream>>>(nb_f16, 512,
          Wuv_t + (size_t)c0 * 512, 512, ub, CH, 512, buv + c0, OP_SILU, nullptr);
      gemm_f16<<<dim3(CH / 128, 2), blk, 0, stream>>>(nb_f16, 512,
          Wuv_t + (size_t)(768 + c0) * 512, 512, vb, CH, 512, buv + 768 + c0, OP_SILU, nullptr);
      attnapply_kernel<<<4, 256, 0, stream>>>(ab, vb, ub, tb, CH);
      const float* bo = (c0 + CH == 768) ? (blk_bo + b * 512) : nullptr;
      gemm_f16<<<dim3(4, 2), blk, 0, stream>>>(tb, CH, Wo_t + c0, 768,
          gy, 512, CH, bo, OP_RESID, nullptr);
    }
  }
  bucketmean_kernel<<<4, 256, 0, stream>>>(gy, nullptr, gy2);

  // ---- tails ----
  gemm_f32<<<dim3(8, 1), blk, 0, stream>>>(gy2, 512, tr_W, 512, ys1, 512,
      4, 512, 512, tr_b, OP_TR, nullptr, gy2, tr_a);
  avg_kernel<<<8, 256, 0, stream>>>(ys0, ys1, yv, 2048);
  gemm_f32<<<dim3(8, 1), blk, 0, stream>>>(yv, 512, tr2_W, 512, y2, 512,
      4, 512, 512, tr2_b, OP_TR, nullptr, yv, tr2_a);
  out_kernel<<<1, 64, 0, stream>>>(y2, out_W, out_b, outp);
}

// Round 4
// 2592.282 us; speedup vs baseline: 2.5671x; 1.2050x over previous
//
#include <hip/hip_runtime.h>
#include <math.h>

#define R1C 16384

enum { OP_STORE = 0, OP_SILU = 1, OP_RESID = 2, OP_TR = 3 };

typedef _Float16 f16x8 __attribute__((ext_vector_type(8)));
typedef float f32x4 __attribute__((ext_vector_type(4)));

__device__ __forceinline__ float silu_f(float x) { return x / (1.0f + expf(-x)); }
__device__ __forceinline__ float gelu_f(float x) {
  return 0.5f * x * (1.0f + erff(x * 0.70710678118654752f));
}

__device__ __forceinline__ void gll16(const void* g, const void* l) {
  __builtin_amdgcn_global_load_lds(
      (const __attribute__((address_space(1))) unsigned int*)g,
      (__attribute__((address_space(3))) unsigned int*)l, 16, 0, 0);
}

// ============ f16 MFMA GEMM: C(MxN f32) = A(MxK f16,row) @ Bt(NxK f16,row)^T ======
// Requires M%128==0, N%128==0, K%32==0. 128x128 tile, 4 waves of 4x4 16x16x32 MFMA.
__global__ __launch_bounds__(256) void gemm_f16(
    const _Float16* __restrict__ A, int lda,
    const _Float16* __restrict__ Bt, int ldb,
    float* __restrict__ C, int ldc, int K,
    const float* __restrict__ bias, int mode,
    const int* __restrict__ ids)
{
  __shared__ _Float16 As[128 * 32];
  __shared__ _Float16 Bs[128 * 32];
  int tid = threadIdx.x;
  int lane = tid & 63, w = tid >> 6;
  int wm = w >> 1, wn = w & 1;
  int row0 = blockIdx.y * 128, col0 = blockIdx.x * 128;

  int p0 = w * 64 + lane;
  int p1 = 256 + w * 64 + lane;
  int m0 = p0 >> 2, k0e = ((p0 & 3) ^ (m0 & 3)) * 8;
  int m1 = p1 >> 2, k1e = ((p1 & 3) ^ (m1 & 3)) * 8;
  const _Float16* gA0 = A + (size_t)(row0 + m0) * lda + k0e;
  const _Float16* gA1 = A + (size_t)(row0 + m1) * lda + k1e;
  const _Float16* gB0 = Bt + (size_t)(col0 + m0) * ldb + k0e;
  const _Float16* gB1 = Bt + (size_t)(col0 + m1) * ldb + k1e;
  const _Float16* lA0 = As + (size_t)(w * 64) * 8;
  const _Float16* lA1 = As + (size_t)(256 + w * 64) * 8;
  const _Float16* lB0 = Bs + (size_t)(w * 64) * 8;
  const _Float16* lB1 = Bs + (size_t)(256 + w * 64) * 8;

  int mrow = lane & 15, quad = lane >> 4;
  const f16x8* aptr[4];
  const f16x8* bptr[4];
#pragma unroll
  for (int t = 0; t < 4; ++t) {
    int ml = wm * 64 + t * 16 + mrow;
    aptr[t] = (const f16x8*)(As + (size_t)(ml * 4 + (quad ^ (ml & 3))) * 8);
    int nl = wn * 64 + t * 16 + mrow;
    bptr[t] = (const f16x8*)(Bs + (size_t)(nl * 4 + (quad ^ (nl & 3))) * 8);
  }

  f32x4 acc[4][4] = {};

  for (int kt = 0; kt < K; kt += 32) {
    gll16(gA0, lA0); gll16(gA1, lA1);
    gll16(gB0, lB0); gll16(gB1, lB1);
    gA0 += 32; gA1 += 32; gB0 += 32; gB1 += 32;
    __syncthreads();
    f16x8 af[4], bfr[4];
#pragma unroll
    for (int t = 0; t < 4; ++t) { af[t] = *aptr[t]; bfr[t] = *bptr[t]; }
#pragma unroll
    for (int mt = 0; mt < 4; ++mt)
#pragma unroll
      for (int nt = 0; nt < 4; ++nt)
        acc[mt][nt] = __builtin_amdgcn_mfma_f32_16x16x32_f16(
            af[mt], bfr[nt], acc[mt][nt], 0, 0, 0);
    __syncthreads();
  }

#pragma unroll
  for (int mt = 0; mt < 4; ++mt) {
#pragma unroll
    for (int nt = 0; nt < 4; ++nt) {
      int c = col0 + wn * 64 + nt * 16 + mrow;
      float bv = bias ? bias[c] : 0.0f;
#pragma unroll
      for (int reg = 0; reg < 4; ++reg) {
        int r = row0 + wm * 64 + mt * 16 + quad * 4 + reg;
        float val = acc[mt][nt][reg] + bv;
        if (mode == OP_STORE) {
          C[(size_t)r * ldc + c] = val;
        } else if (mode == OP_SILU) {
          C[(size_t)r * ldc + c] = silu_f(val);
        } else { // OP_RESID
          int hr = ids ? ids[r] : r;
          C[(size_t)hr * ldc + c] += val;
        }
      }
    }
  }
}

// ============ fused UVB GEMM: one dispatch computes silu(n @ Wuv + buv) routed to
// u (cols c0..c0+CH), v (cols 768+c0..), base (cols 1536..1792, only when incl_base).
// grid.x = 2*nu (+2 if incl_base), nu = CH/128. Numerically identical to 3 dispatches.
__global__ __launch_bounds__(256) void gemm_f16_uvb(
    const _Float16* __restrict__ A, int lda,
    const _Float16* __restrict__ Bt,           // Wuv^T block (1792 x 512)
    int c0, int nu,
    float* __restrict__ ub, float* __restrict__ vb, float* __restrict__ baseb,
    int CH, int K, const float* __restrict__ buv)
{
  __shared__ _Float16 As[128 * 32];
  __shared__ _Float16 Bs[128 * 32];
  int tid = threadIdx.x;
  int lane = tid & 63, w = tid >> 6;
  int wm = w >> 1, wn = w & 1;
  int row0 = blockIdx.y * 128;

  int x = blockIdx.x;
  int xl, regbase, ldc_;
  float* dst;
  if (x < nu)            { xl = x;          regbase = c0;        dst = ub;    ldc_ = CH; }
  else if (x < 2 * nu)   { xl = x - nu;     regbase = 768 + c0;  dst = vb;    ldc_ = CH; }
  else                   { xl = x - 2 * nu; regbase = 1536;      dst = baseb; ldc_ = 256; }
  int brow0 = regbase + xl * 128;  // row in Wuv^T == output column in Wuv
  int dcol0 = xl * 128;            // column in dst buffer

  int p0 = w * 64 + lane;
  int p1 = 256 + w * 64 + lane;
  int m0 = p0 >> 2, k0e = ((p0 & 3) ^ (m0 & 3)) * 8;
  int m1 = p1 >> 2, k1e = ((p1 & 3) ^ (m1 & 3)) * 8;
  const _Float16* gA0 = A + (size_t)(row0 + m0) * lda + k0e;
  const _Float16* gA1 = A + (size_t)(row0 + m1) * lda + k1e;
  const _Float16* gB0 = Bt + (size_t)(brow0 + m0) * 512 + k0e;
  const _Float16* gB1 = Bt + (size_t)(brow0 + m1) * 512 + k1e;
  const _Float16* lA0 = As + (size_t)(w * 64) * 8;
  const _Float16* lA1 = As + (size_t)(256 + w * 64) * 8;
  const _Float16* lB0 = Bs + (size_t)(w * 64) * 8;
  const _Float16* lB1 = Bs + (size_t)(256 + w * 64) * 8;

  int mrow = lane & 15, quad = lane >> 4;
  const f16x8* aptr[4];
  const f16x8* bptr[4];
#pragma unroll
  for (int t = 0; t < 4; ++t) {
    int ml = wm * 64 + t * 16 + mrow;
    aptr[t] = (const f16x8*)(As + (size_t)(ml * 4 + (quad ^ (ml & 3))) * 8);
    int nl = wn * 64 + t * 16 + mrow;
    bptr[t] = (const f16x8*)(Bs + (size_t)(nl * 4 + (quad ^ (nl & 3))) * 8);
  }

  f32x4 acc[4][4] = {};

  for (int kt = 0; kt < K; kt += 32) {
    gll16(gA0, lA0); gll16(gA1, lA1);
    gll16(gB0, lB0); gll16(gB1, lB1);
    gA0 += 32; gA1 += 32; gB0 += 32; gB1 += 32;
    __syncthreads();
    f16x8 af[4], bfr[4];
#pragma unroll
    for (int t = 0; t < 4; ++t) { af[t] = *aptr[t]; bfr[t] = *bptr[t]; }
#pragma unroll
    for (int mt = 0; mt < 4; ++mt)
#pragma unroll
      for (int nt = 0; nt < 4; ++nt)
        acc[mt][nt] = __builtin_amdgcn_mfma_f32_16x16x32_f16(
            af[mt], bfr[nt], acc[mt][nt], 0, 0, 0);
    __syncthreads();
  }

#pragma unroll
  for (int mt = 0; mt < 4; ++mt) {
#pragma unroll
    for (int nt = 0; nt < 4; ++nt) {
      int lc = wn * 64 + nt * 16 + mrow;          // 0..127 within tile
      float bv = buv[brow0 + lc];
#pragma unroll
      for (int reg = 0; reg < 4; ++reg) {
        int r = row0 + wm * 64 + mt * 16 + quad * 4 + reg;
        dst[(size_t)r * ldc_ + dcol0 + lc] = silu_f(acc[mt][nt][reg] + bv);
      }
    }
  }
}

// ---------------- generic fp32 GEMM (stage A + small tails) ----------------
__global__ __launch_bounds__(256) void gemm_f32(
    const float* __restrict__ A, int lda,
    const float* __restrict__ B, int ldb,
    float* __restrict__ C, int ldc,
    int M, int N, int K,
    const float* __restrict__ bias, int mode,
    const int* __restrict__ ids,
    const float* __restrict__ X,
    const float* __restrict__ alpha)
{
  __shared__ float As[16][68];
  __shared__ float Bs[16][68];
  int tid = threadIdx.x;
  int tx = tid & 15, ty = tid >> 4;
  int col0 = blockIdx.x * 64, row0 = blockIdx.y * 64;
  float acc[4][4] = {};
  int arow = tid >> 2;
  int ak   = (tid & 3) * 4;
  int bk   = tid >> 4;
  int bn   = (tid & 15) * 4;

  for (int kt = 0; kt < K; kt += 16) {
    float4 av = make_float4(0.f, 0.f, 0.f, 0.f);
    if (row0 + arow < M)
      av = *(const float4*)&A[(size_t)(row0 + arow) * lda + kt + ak];
    As[ak + 0][arow] = av.x; As[ak + 1][arow] = av.y;
    As[ak + 2][arow] = av.z; As[ak + 3][arow] = av.w;
    float4 bv = *(const float4*)&B[(size_t)(kt + bk) * ldb + col0 + bn];
    *(float4*)&Bs[bk][bn] = bv;
    __syncthreads();
#pragma unroll
    for (int k = 0; k < 16; ++k) {
      const float4 a4 = *(const float4*)&As[k][ty * 4];
      const float4 b4 = *(const float4*)&Bs[k][tx * 4];
      float a_[4] = {a4.x, a4.y, a4.z, a4.w};
      float b_[4] = {b4.x, b4.y, b4.z, b4.w};
#pragma unroll
      for (int i = 0; i < 4; ++i)
#pragma unroll
        for (int j = 0; j < 4; ++j)
          acc[i][j] = fmaf(a_[i], b_[j], acc[i][j]);
    }
    __syncthreads();
  }

#pragma unroll
  for (int i = 0; i < 4; ++i) {
    int r = row0 + ty * 4 + i;
    if (r >= M) continue;
#pragma unroll
    for (int j = 0; j < 4; ++j) {
      int c = col0 + tx * 4 + j;
      float val = acc[i][j] + (bias ? bias[c] : 0.0f);
      if (mode == OP_STORE) {
        C[(size_t)r * ldc + c] = val;
      } else if (mode == OP_SILU) {
        C[(size_t)r * ldc + c] = silu_f(val);
      } else if (mode == OP_RESID) {
        int hr = ids ? ids[r] : r;
        C[(size_t)hr * ldc + c] += val;
      } else { // OP_TR
        C[(size_t)r * ldc + c] = X[(size_t)r * ldc + c] + gelu_f(val) * alpha[0];
      }
    }
  }
}

// ---------------- weight transpose + cast: in(K x N f32) -> out(N x K f16) ----------
__global__ __launch_bounds__(256) void transpose_cast(
    const float* __restrict__ in, _Float16* __restrict__ out, int K, int N)
{
  in  += (size_t)blockIdx.z * K * N;
  out += (size_t)blockIdx.z * K * N;
  __shared__ float t[32][33];
  int k0 = blockIdx.y * 32, n0 = blockIdx.x * 32;
  int tx = threadIdx.x & 31, ty = threadIdx.x >> 5;
  for (int i = ty; i < 32; i += 8) {
    int k = k0 + i, n = n0 + tx;
    t[i][tx] = (k < K && n < N) ? in[(size_t)k * N + n] : 0.0f;
  }
  __syncthreads();
  for (int i = ty; i < 32; i += 8) {
    int n = n0 + i, k = k0 + tx;
    if (n < N && k < K) out[(size_t)n * K + k] = (_Float16)t[tx][i];
  }
}

// ---------------- layernorm over 512 + optional gather/leaky/norm2-out ----------
template <typename OUT>
__global__ __launch_bounds__(256) void ln_kernel(
    const float* __restrict__ src, const int* __restrict__ ids,
    OUT* __restrict__ dst, const float* __restrict__ g,
    const float* __restrict__ b, float eps, int leaky,
    float* __restrict__ nrm2)
{
  int r = blockIdx.x;
  int sr = ids ? ids[r] : r;
  int tid = threadIdx.x;
  float v0 = src[(size_t)sr * 512 + tid];
  float v1 = src[(size_t)sr * 512 + tid + 256];
  __shared__ float red[256], red2[256];
  red[tid] = v0 + v1;
  red2[tid] = v0 * v0 + v1 * v1;
  __syncthreads();
  for (int s = 128; s > 0; s >>= 1) {
    if (tid < s) { red[tid] += red[tid + s]; red2[tid] += red2[tid + s]; }
    __syncthreads();
  }
  float mean = red[0] * (1.0f / 512.0f);
  float var  = red2[0] * (1.0f / 512.0f) - mean * mean;
  float rs = rsqrtf(var + eps);
  float o0 = (v0 - mean) * rs * g[tid] + b[tid];
  float o1 = (v1 - mean) * rs * g[tid + 256] + b[tid + 256];
  if (leaky) {
    o0 = o0 > 0.0f ? o0 : 0.1f * o0;
    o1 = o1 > 0.0f ? o1 : 0.1f * o1;
  }
  dst[(size_t)r * 512 + tid] = (OUT)o0;
  dst[(size_t)r * 512 + tid + 256] = (OUT)o1;
  if (nrm2) {
    __syncthreads();
    red[tid] = o0 * o0 + o1 * o1;
    __syncthreads();
    for (int s = 128; s > 0; s >>= 1) {
      if (tid < s) red[tid] += red[tid + s];
      __syncthreads();
    }
    if (tid == 0) nrm2[r] = red[0];
  }
}

// ---------------- bitonic argsort of 4096 keys per sample ----------------
__global__ __launch_bounds__(1024) void sort_kernel(const float* __restrict__ norm2,
                                                    int* __restrict__ ids)
{
  __shared__ float key[4096];
  __shared__ int   val[4096];
  int s = blockIdx.x, tid = threadIdx.x;
  for (int i = tid; i < 4096; i += 1024) { key[i] = norm2[s * 4096 + i]; val[i] = i; }
  __syncthreads();
  for (int len = 2; len <= 4096; len <<= 1) {
    for (int j = len >> 1; j > 0; j >>= 1) {
      for (int t = tid; t < 2048; t += 1024) {
        int i1 = (t << 1) - (t & (j - 1));
        int i2 = i1 + j;
        bool up = ((i1 & len) == 0);
        float ka = key[i1], kb = key[i2];
        int va = val[i1], vb = val[i2];
        bool gt = (ka > kb) || (ka == kb && va > vb);
        if (gt == up) {
          key[i1] = kb; key[i2] = ka;
          val[i1] = vb; val[i2] = va;
        }
      }
      __syncthreads();
    }
  }
  for (int i = tid; i < 4096; i += 1024) ids[s * 4096 + i] = s * 4096 + val[i];
}

// ---------------- per-bucket attention scores: a = (relu(q k^T / 64))^2 ----------
__global__ __launch_bounds__(256) void attn_kernel(
    const float* __restrict__ base, const float* __restrict__ gb,
    const float* __restrict__ bb, float* __restrict__ a_out)
{
  int g = blockIdx.x, tid = threadIdx.x;
  int tx = tid & 15, ty = tid >> 4;
  __shared__ float qT[64][68], kT[64][68];
  float acc[4][4] = {};
  for (int s0 = 0; s0 < 256; s0 += 64) {
    for (int idx = tid; idx < 64 * 64; idx += 256) {
      int l = idx >> 6, s = idx & 63;
      float v = base[((size_t)g * 64 + l) * 256 + s0 + s];
      qT[s][l] = v * gb[s0 + s] + bb[s0 + s];
      kT[s][l] = v * gb[256 + s0 + s] + bb[256 + s0 + s];
    }
    __syncthreads();
#pragma unroll 4
    for (int s = 0; s < 64; ++s) {
      const float4 q4 = *(const float4*)&qT[s][ty * 4];
      const float4 k4 = *(const float4*)&kT[s][tx * 4];
      float q_[4] = {q4.x, q4.y, q4.z, q4.w};
      float k_[4] = {k4.x, k4.y, k4.z, k4.w};
#pragma unroll
      for (int i = 0; i < 4; ++i)
#pragma unroll
        for (int j = 0; j < 4; ++j)
          acc[i][j] = fmaf(q_[i], k_[j], acc[i][j]);
    }
    __syncthreads();
  }
#pragma unroll
  for (int i = 0; i < 4; ++i)
#pragma unroll
    for (int j = 0; j < 4; ++j) {
      float v = acc[i][j] * (1.0f / 64.0f);
      v = v > 0.0f ? v : 0.0f;
      v = v * v;
      a_out[((size_t)g * 64 + ty * 4 + i) * 64 + tx * 4 + j] = v;
    }
}

// ---------------- t = (a @ v) * u  (a,v,u fp32; t fp16 for Wo MFMA input) ---------
__global__ __launch_bounds__(256) void attnapply_kernel(
    const float* __restrict__ a, const float* __restrict__ v,
    const float* __restrict__ u, _Float16* __restrict__ t, int CH)
{
  int g = blockIdx.x, tid = threadIdx.x;
  int tx = tid & 15, ty = tid >> 4;
  __shared__ float As_[64][68], Vs[64][68];
  for (int idx = tid; idx < 64 * 64; idx += 256) {
    int l = idx >> 6, m = idx & 63;
    As_[l][m] = a[((size_t)g * 64 + l) * 64 + m];
  }
  for (int e0 = 0; e0 < CH; e0 += 64) {
    for (int idx = tid; idx < 64 * 64; idx += 256) {
      int m = idx >> 6, e = idx & 63;
      Vs[m][e] = v[((size_t)g * 64 + m) * CH + e0 + e];
    }
    __syncthreads();
    float acc[4][4] = {};
#pragma unroll 4
    for (int m = 0; m < 64; ++m) {
      float a_[4];
#pragma unroll
      for (int i = 0; i < 4; ++i) a_[i] = As_[ty * 4 + i][m];
      const float4 v4 = *(const float4*)&Vs[m][tx * 4];
      float v_[4] = {v4.x, v4.y, v4.z, v4.w};
#pragma unroll
      for (int i = 0; i < 4; ++i)
#pragma unroll
        for (int j = 0; j < 4; ++j)
          acc[i][j] = fmaf(a_[i], v_[j], acc[i][j]);
    }
#pragma unroll
    for (int i = 0; i < 4; ++i)
#pragma unroll
      for (int j = 0; j < 4; ++j) {
        size_t off = ((size_t)g * 64 + ty * 4 + i) * CH + e0 + tx * 4 + j;
        t[off] = (_Float16)(acc[i][j] * u[off]);
      }
    __syncthreads();
  }
}

// ---------------- mean over groups of 64 rows (optional gather) ----------------
__global__ __launch_bounds__(256) void bucketmean_kernel(
    const float* __restrict__ src, const int* __restrict__ ids,
    float* __restrict__ dst)
{
  int g = blockIdx.x, tid = threadIdx.x;
  float s0 = 0.0f, s1 = 0.0f;
  for (int i = 0; i < 64; ++i) {
    int r = g * 64 + i;
    if (ids) r = ids[r];
    s0 += src[(size_t)r * 512 + tid];
    s1 += src[(size_t)r * 512 + tid + 256];
  }
  dst[(size_t)g * 512 + tid] = s0 * (1.0f / 64.0f);
  dst[(size_t)g * 512 + tid + 256] = s1 * (1.0f / 64.0f);
}

__global__ void avg_kernel(const float* __restrict__ a, const float* __restrict__ b,
                           float* __restrict__ o, int n)
{
  int i = blockIdx.x * 256 + threadIdx.x;
  if (i < n) o[i] = 0.5f * (a[i] + b[i]);
}

__global__ void out_kernel(const float* __restrict__ y, const float* __restrict__ W,
                           const float* __restrict__ b, float* __restrict__ out)
{
  int tid = threadIdx.x;
  if (tid < 8) {
    int s = tid >> 1, j = tid & 1;
    float acc = b[j];
    for (int d = 0; d < 512; ++d) acc += y[s * 512 + d] * W[d * 2 + j];
    out[s * 2 + j] = acc;
  }
}

extern "C" void kernel_launch(void* const* d_in, const int* in_sizes, int n_in,
                              void* d_out, int out_size, void* d_ws, size_t ws_size,
                              hipStream_t stream)
{
  const float* xs       = (const float*)d_in[0];
  const float* W_in     = (const float*)d_in[1];
  const float* b_in     = (const float*)d_in[2];
  const float* ln_in_g  = (const float*)d_in[3];
  const float* ln_in_b  = (const float*)d_in[4];
  const float* blk_ln_g = (const float*)d_in[5];
  const float* blk_ln_b = (const float*)d_in[6];
  const float* blk_Wuv  = (const float*)d_in[7];
  const float* blk_buv  = (const float*)d_in[8];
  const float* blk_gam  = (const float*)d_in[9];
  const float* blk_bet  = (const float*)d_in[10];
  const float* blk_Wo   = (const float*)d_in[11];
  const float* blk_bo   = (const float*)d_in[12];
  const float* tr_W     = (const float*)d_in[13];
  const float* tr_b     = (const float*)d_in[14];
  const float* tr_a     = (const float*)d_in[15];
  const float* tr2_W    = (const float*)d_in[16];
  const float* tr2_b    = (const float*)d_in[17];
  const float* tr2_a    = (const float*)d_in[18];
  const float* out_W    = (const float*)d_in[19];
  const float* out_b    = (const float*)d_in[20];
  float* outp = (float*)d_out;

  const size_t R1 = R1C;

  // ---- workspace carve (bytes) ----
  char* base = (char*)d_ws;
  size_t off = 0;
  auto carve = [&](size_t bytes) {
    char* r = base + off;
    off = (off + bytes + 255) & ~(size_t)255;
    return (void*)r;
  };
  float* h      = (float*)carve(R1 * 512 * 4);
  float* nb     = (float*)carve(R1 * 512 * 4);        // f32 view (stage A)
  _Float16* nb_f16 = (_Float16*)nb;                   // f16 view (block LNs)
  float* baseb  = (float*)carve(R1 * 256 * 4);
  float* ab     = (float*)carve((size_t)256 * 64 * 64 * 4);
  float* norm2b = (float*)carve(R1 * 4);
  int*   idsb   = (int*)carve(R1 * 4);
  float* gy     = (float*)carve((size_t)256 * 512 * 4);
  float* tl     = (float*)carve((size_t)256 * 512 * 4);
  float* gy2    = (float*)carve(4 * 512 * 4);
  float* ys0    = (float*)carve(4 * 512 * 4);
  float* ys1    = (float*)carve(4 * 512 * 4);
  float* yv     = (float*)carve(4 * 512 * 4);
  float* y2     = (float*)carve(4 * 512 * 4);
  _Float16* Wuvt = (_Float16*)carve((size_t)6 * 1792 * 512 * 2);
  _Float16* Wot  = (_Float16*)carve((size_t)6 * 512 * 768 * 2);
  size_t fixed_bytes = off;

  int CH = 128;
  const int cand[4] = {768, 384, 256, 128};
  for (int ci = 0; ci < 4; ++ci) {
    // ub f32 + vb f32 + tb f16 = 10 bytes per element
    size_t need = fixed_bytes + 3 * 256 + 10 * R1 * (size_t)cand[ci];
    if (need <= ws_size) { CH = cand[ci]; break; }
  }
  float*    ub = (float*)carve(R1 * (size_t)CH * 4);
  float*    vb = (float*)carve(R1 * (size_t)CH * 4);
  _Float16* tb = (_Float16*)carve(R1 * (size_t)CH * 2);
  int nu = CH / 128;

  dim3 blk(256);

  // ---- weight prep: transpose+cast to f16 N x K ----
  transpose_cast<<<dim3(56, 16, 6), blk, 0, stream>>>(blk_Wuv, Wuvt, 512, 1792);
  transpose_cast<<<dim3(16, 24, 6), blk, 0, stream>>>(blk_Wo, Wot, 768, 512);

  // ---- Stage A: input projection (fp32 => exact sort keys) + LN(1e-8) + leaky + norm2
  gemm_f32<<<dim3(8, 256), blk, 0, stream>>>(xs, 768, W_in, 512, nb, 512,
      16384, 512, 768, b_in, OP_STORE, nullptr, nullptr, nullptr);
  ln_kernel<float><<<16384, 256, 0, stream>>>(nb, nullptr, h, ln_in_g, ln_in_b,
                                              1e-8f, 1, norm2b);
  sort_kernel<<<4, 1024, 0, stream>>>(norm2b, idsb);

  // ---- Iteration 1: 6 subnet blocks over 256 buckets ----
  for (int b = 0; b < 6; ++b) {
    const _Float16* Wuv_t = Wuvt + (size_t)b * 1792 * 512;  // (1792 x 512) = Wuv^T
    const float*    buv   = blk_buv + b * 1792;
    const _Float16* Wo_t  = Wot + (size_t)b * 512 * 768;    // (512 x 768) = Wo^T
    ln_kernel<_Float16><<<16384, 256, 0, stream>>>(h, idsb, nb_f16, blk_ln_g + b * 512,
                                                   blk_ln_b + b * 512, 1e-5f, 0, nullptr);
    for (int c0 = 0; c0 < 768; c0 += CH) {
      int incl = (c0 == 0) ? 2 : 0;
      gemm_f16_uvb<<<dim3(2 * nu + incl, 128), blk, 0, stream>>>(nb_f16, 512, Wuv_t,
          c0, nu, ub, vb, baseb, CH, 512, buv);
      if (c0 == 0)
        attn_kernel<<<256, 256, 0, stream>>>(baseb, blk_gam + b * 512,
                                             blk_bet + b * 512, ab);
      attnapply_kernel<<<256, 256, 0, stream>>>(ab, vb, ub, tb, CH);
      const float* bo = (c0 + CH == 768) ? (blk_bo + b * 512) : nullptr;
      gemm_f16<<<dim3(4, 128), blk, 0, stream>>>(tb, CH, Wo_t + c0, 768,
          h, 512, CH, bo, OP_RESID, idsb);
    }
  }
  bucketmean_kernel<<<256, 256, 0, stream>>>(h, idsb, gy);

  // ---- ys0 = mean_buckets(tr_layer(gy)) ----
  gemm_f32<<<dim3(8, 4), blk, 0, stream>>>(gy, 512, tr_W, 512, tl, 512,
      256, 512, 512, tr_b, OP_TR, nullptr, gy, tr_a);
  bucketmean_kernel<<<4, 256, 0, stream>>>(tl, nullptr, ys0);

  // ---- Iteration 2: 64 rows/sample == 1 bucket; sort permutation provably cancels --
  for (int b = 0; b < 6; ++b) {
    const _Float16* Wuv_t = Wuvt + (size_t)b * 1792 * 512;
    const float*    buv   = blk_buv + b * 1792;
    const _Float16* Wo_t  = Wot + (size_t)b * 512 * 768;
    ln_kernel<_Float16><<<256, 256, 0, stream>>>(gy, nullptr, nb_f16, blk_ln_g + b * 512,
                                                 blk_ln_b + b * 512, 1e-5f, 0, nullptr);
    for (int c0 = 0; c0 < 768; c0 += CH) {
      int incl = (c0 == 0) ? 2 : 0;
      gemm_f16_uvb<<<dim3(2 * nu + incl, 2), blk, 0, stream>>>(nb_f16, 512, Wuv_t,
          c0, nu, ub, vb, baseb, CH, 512, buv);
      if (c0 == 0)
        attn_kernel<<<4, 256, 0, stream>>>(baseb, blk_gam + b * 512,
                                           blk_bet + b * 512, ab);
      attnapply_kernel<<<4, 256, 0, stream>>>(ab, vb, ub, tb, CH);
      const float* bo = (c0 + CH == 768) ? (blk_bo + b * 512) : nullptr;
      gemm_f16<<<dim3(4, 2), blk, 0, stream>>>(tb, CH, Wo_t + c0, 768,
          gy, 512, CH, bo, OP_RESID, nullptr);
    }
  }
  bucketmean_kernel<<<4, 256, 0, stream>>>(gy, nullptr, gy2);

  // ---- tails ----
  gemm_f32<<<dim3(8, 1), blk, 0, stream>>>(gy2, 512, tr_W, 512, ys1, 512,
      4, 512, 512, tr_b, OP_TR, nullptr, gy2, tr_a);
  avg_kernel<<<8, 256, 0, stream>>>(ys0, ys1, yv, 2048);
  gemm_f32<<<dim3(8, 1), blk, 0, stream>>>(yv, 512, tr2_W, 512, y2, 512,
      4, 512, 512, tr2_b, OP_TR, nullptr, yv, tr2_a);
  out_kernel<<<1, 64, 0, stream>>>(y2, out_W, out_b, outp);
}

// Round 5
// 1996.112 us; speedup vs baseline: 3.3339x; 1.2987x over previous
//
#include <hip/hip_runtime.h>
#include <math.h>

#define R1C 16384

enum { OP_STORE = 0, OP_SILU = 1, OP_RESID = 2, OP_TR = 3 };

typedef _Float16 f16x8 __attribute__((ext_vector_type(8)));
typedef float f32x4 __attribute__((ext_vector_type(4)));

__device__ __forceinline__ float silu_f(float x) { return x / (1.0f + expf(-x)); }
__device__ __forceinline__ float gelu_f(float x) {
  return 0.5f * x * (1.0f + erff(x * 0.70710678118654752f));
}

__device__ __forceinline__ void gll16(const void* g, const void* l) {
  __builtin_amdgcn_global_load_lds(
      (const __attribute__((address_space(1))) unsigned int*)g,
      (__attribute__((address_space(3))) unsigned int*)l, 16, 0, 0);
}

// ============ f16 MFMA GEMM: C(MxN f32) = A(MxK f16,row) @ Bt(NxK f16,row)^T ======
__global__ __launch_bounds__(256) void gemm_f16(
    const _Float16* __restrict__ A, int lda,
    const _Float16* __restrict__ Bt, int ldb,
    float* __restrict__ C, int ldc, int K,
    const float* __restrict__ bias, int mode,
    const int* __restrict__ ids)
{
  __shared__ _Float16 As[128 * 32];
  __shared__ _Float16 Bs[128 * 32];
  int tid = threadIdx.x;
  int lane = tid & 63, w = tid >> 6;
  int wm = w >> 1, wn = w & 1;
  int row0 = blockIdx.y * 128, col0 = blockIdx.x * 128;

  int p0 = w * 64 + lane;
  int p1 = 256 + w * 64 + lane;
  int m0 = p0 >> 2, k0e = ((p0 & 3) ^ (m0 & 3)) * 8;
  int m1 = p1 >> 2, k1e = ((p1 & 3) ^ (m1 & 3)) * 8;
  const _Float16* gA0 = A + (size_t)(row0 + m0) * lda + k0e;
  const _Float16* gA1 = A + (size_t)(row0 + m1) * lda + k1e;
  const _Float16* gB0 = Bt + (size_t)(col0 + m0) * ldb + k0e;
  const _Float16* gB1 = Bt + (size_t)(col0 + m1) * ldb + k1e;
  const _Float16* lA0 = As + (size_t)(w * 64) * 8;
  const _Float16* lA1 = As + (size_t)(256 + w * 64) * 8;
  const _Float16* lB0 = Bs + (size_t)(w * 64) * 8;
  const _Float16* lB1 = Bs + (size_t)(256 + w * 64) * 8;

  int mrow = lane & 15, quad = lane >> 4;
  const f16x8* aptr[4];
  const f16x8* bptr[4];
#pragma unroll
  for (int t = 0; t < 4; ++t) {
    int ml = wm * 64 + t * 16 + mrow;
    aptr[t] = (const f16x8*)(As + (size_t)(ml * 4 + (quad ^ (ml & 3))) * 8);
    int nl = wn * 64 + t * 16 + mrow;
    bptr[t] = (const f16x8*)(Bs + (size_t)(nl * 4 + (quad ^ (nl & 3))) * 8);
  }

  f32x4 acc[4][4] = {};

  for (int kt = 0; kt < K; kt += 32) {
    gll16(gA0, lA0); gll16(gA1, lA1);
    gll16(gB0, lB0); gll16(gB1, lB1);
    gA0 += 32; gA1 += 32; gB0 += 32; gB1 += 32;
    __syncthreads();
    f16x8 af[4], bfr[4];
#pragma unroll
    for (int t = 0; t < 4; ++t) { af[t] = *aptr[t]; bfr[t] = *bptr[t]; }
#pragma unroll
    for (int mt = 0; mt < 4; ++mt)
#pragma unroll
      for (int nt = 0; nt < 4; ++nt)
        acc[mt][nt] = __builtin_amdgcn_mfma_f32_16x16x32_f16(
            af[mt], bfr[nt], acc[mt][nt], 0, 0, 0);
    __syncthreads();
  }

#pragma unroll
  for (int mt = 0; mt < 4; ++mt) {
#pragma unroll
    for (int nt = 0; nt < 4; ++nt) {
      int c = col0 + wn * 64 + nt * 16 + mrow;
      float bv = bias ? bias[c] : 0.0f;
#pragma unroll
      for (int reg = 0; reg < 4; ++reg) {
        int r = row0 + wm * 64 + mt * 16 + quad * 4 + reg;
        float val = acc[mt][nt][reg] + bv;
        if (mode == OP_STORE) {
          C[(size_t)r * ldc + c] = val;
        } else if (mode == OP_SILU) {
          C[(size_t)r * ldc + c] = silu_f(val);
        } else { // OP_RESID
          int hr = ids ? ids[r] : r;
          C[(size_t)hr * ldc + c] += val;
        }
      }
    }
  }
}

// ============ split-f16 GEMM for stage A: C = (Ah+Al)@(Bh+Bl)^T, 3-term ==========
// error ~ f16eps^2 => sort keys effectively fp32-exact.
__global__ __launch_bounds__(256) void gemm_f16_split(
    const _Float16* __restrict__ Ah, const _Float16* __restrict__ Al, int lda,
    const _Float16* __restrict__ Bh, const _Float16* __restrict__ Bl, int ldb,
    float* __restrict__ C, int ldc, int K, const float* __restrict__ bias)
{
  __shared__ _Float16 AsH[128 * 32], AsL[128 * 32];
  __shared__ _Float16 BsH[128 * 32], BsL[128 * 32];
  int tid = threadIdx.x;
  int lane = tid & 63, w = tid >> 6;
  int wm = w >> 1, wn = w & 1;
  int row0 = blockIdx.y * 128, col0 = blockIdx.x * 128;

  int p0 = w * 64 + lane;
  int p1 = 256 + w * 64 + lane;
  int m0 = p0 >> 2, k0e = ((p0 & 3) ^ (m0 & 3)) * 8;
  int m1 = p1 >> 2, k1e = ((p1 & 3) ^ (m1 & 3)) * 8;
  size_t a0 = (size_t)(row0 + m0) * lda + k0e;
  size_t a1 = (size_t)(row0 + m1) * lda + k1e;
  size_t b0 = (size_t)(col0 + m0) * ldb + k0e;
  size_t b1 = (size_t)(col0 + m1) * ldb + k1e;
  size_t l0 = (size_t)(w * 64) * 8;
  size_t l1 = (size_t)(256 + w * 64) * 8;

  int mrow = lane & 15, quad = lane >> 4;
  size_t aoff[4], boff[4];
#pragma unroll
  for (int t = 0; t < 4; ++t) {
    int ml = wm * 64 + t * 16 + mrow;
    aoff[t] = (size_t)(ml * 4 + (quad ^ (ml & 3))) * 8;
    int nl = wn * 64 + t * 16 + mrow;
    boff[t] = (size_t)(nl * 4 + (quad ^ (nl & 3))) * 8;
  }

  f32x4 acc[4][4] = {};

  for (int kt = 0; kt < K; kt += 32) {
    gll16(Ah + a0, AsH + l0); gll16(Ah + a1, AsH + l1);
    gll16(Al + a0, AsL + l0); gll16(Al + a1, AsL + l1);
    gll16(Bh + b0, BsH + l0); gll16(Bh + b1, BsH + l1);
    gll16(Bl + b0, BsL + l0); gll16(Bl + b1, BsL + l1);
    a0 += 32; a1 += 32; b0 += 32; b1 += 32;
    __syncthreads();
    f16x8 ah[4], al_[4], bh[4], bl[4];
#pragma unroll
    for (int t = 0; t < 4; ++t) {
      ah[t]  = *(const f16x8*)(AsH + aoff[t]);
      al_[t] = *(const f16x8*)(AsL + aoff[t]);
      bh[t]  = *(const f16x8*)(BsH + boff[t]);
      bl[t]  = *(const f16x8*)(BsL + boff[t]);
    }
#pragma unroll
    for (int mt = 0; mt < 4; ++mt)
#pragma unroll
      for (int nt = 0; nt < 4; ++nt) {
        acc[mt][nt] = __builtin_amdgcn_mfma_f32_16x16x32_f16(
            ah[mt], bh[nt], acc[mt][nt], 0, 0, 0);
        acc[mt][nt] = __builtin_amdgcn_mfma_f32_16x16x32_f16(
            ah[mt], bl[nt], acc[mt][nt], 0, 0, 0);
        acc[mt][nt] = __builtin_amdgcn_mfma_f32_16x16x32_f16(
            al_[mt], bh[nt], acc[mt][nt], 0, 0, 0);
      }
    __syncthreads();
  }

#pragma unroll
  for (int mt = 0; mt < 4; ++mt)
#pragma unroll
    for (int nt = 0; nt < 4; ++nt) {
      int c = col0 + wn * 64 + nt * 16 + mrow;
      float bv = bias ? bias[c] : 0.0f;
#pragma unroll
      for (int reg = 0; reg < 4; ++reg) {
        int r = row0 + wm * 64 + mt * 16 + quad * 4 + reg;
        C[(size_t)r * ldc + c] = acc[mt][nt][reg] + bv;
      }
    }
}

// ============ fused UVB GEMM: silu(n @ Wuv + buv) -> u/v (f16, CH-wide), base (f32) ==
__global__ __launch_bounds__(256) void gemm_f16_uvb(
    const _Float16* __restrict__ A, int lda,
    const _Float16* __restrict__ Bt,           // Wuv^T block (1792 x 512)
    int c0, int nu,
    _Float16* __restrict__ ub, _Float16* __restrict__ vb, float* __restrict__ baseb,
    int CH, int K, const float* __restrict__ buv)
{
  __shared__ _Float16 As[128 * 32];
  __shared__ _Float16 Bs[128 * 32];
  int tid = threadIdx.x;
  int lane = tid & 63, w = tid >> 6;
  int wm = w >> 1, wn = w & 1;
  int row0 = blockIdx.y * 128;

  int x = blockIdx.x;
  int xl, regbase, ldc_, is_base = 0;
  _Float16* dst16 = nullptr;
  if (x < nu)            { xl = x;          regbase = c0;        dst16 = ub; ldc_ = CH; }
  else if (x < 2 * nu)   { xl = x - nu;     regbase = 768 + c0;  dst16 = vb; ldc_ = CH; }
  else                   { xl = x - 2 * nu; regbase = 1536;      is_base = 1; ldc_ = 256; }
  int brow0 = regbase + xl * 128;
  int dcol0 = xl * 128;

  int p0 = w * 64 + lane;
  int p1 = 256 + w * 64 + lane;
  int m0 = p0 >> 2, k0e = ((p0 & 3) ^ (m0 & 3)) * 8;
  int m1 = p1 >> 2, k1e = ((p1 & 3) ^ (m1 & 3)) * 8;
  const _Float16* gA0 = A + (size_t)(row0 + m0) * lda + k0e;
  const _Float16* gA1 = A + (size_t)(row0 + m1) * lda + k1e;
  const _Float16* gB0 = Bt + (size_t)(brow0 + m0) * 512 + k0e;
  const _Float16* gB1 = Bt + (size_t)(brow0 + m1) * 512 + k1e;
  const _Float16* lA0 = As + (size_t)(w * 64) * 8;
  const _Float16* lA1 = As + (size_t)(256 + w * 64) * 8;
  const _Float16* lB0 = Bs + (size_t)(w * 64) * 8;
  const _Float16* lB1 = Bs + (size_t)(256 + w * 64) * 8;

  int mrow = lane & 15, quad = lane >> 4;
  const f16x8* aptr[4];
  const f16x8* bptr[4];
#pragma unroll
  for (int t = 0; t < 4; ++t) {
    int ml = wm * 64 + t * 16 + mrow;
    aptr[t] = (const f16x8*)(As + (size_t)(ml * 4 + (quad ^ (ml & 3))) * 8);
    int nl = wn * 64 + t * 16 + mrow;
    bptr[t] = (const f16x8*)(Bs + (size_t)(nl * 4 + (quad ^ (nl & 3))) * 8);
  }

  f32x4 acc[4][4] = {};

  for (int kt = 0; kt < K; kt += 32) {
    gll16(gA0, lA0); gll16(gA1, lA1);
    gll16(gB0, lB0); gll16(gB1, lB1);
    gA0 += 32; gA1 += 32; gB0 += 32; gB1 += 32;
    __syncthreads();
    f16x8 af[4], bfr[4];
#pragma unroll
    for (int t = 0; t < 4; ++t) { af[t] = *aptr[t]; bfr[t] = *bptr[t]; }
#pragma unroll
    for (int mt = 0; mt < 4; ++mt)
#pragma unroll
      for (int nt = 0; nt < 4; ++nt)
        acc[mt][nt] = __builtin_amdgcn_mfma_f32_16x16x32_f16(
            af[mt], bfr[nt], acc[mt][nt], 0, 0, 0);
    __syncthreads();
  }

#pragma unroll
  for (int mt = 0; mt < 4; ++mt) {
#pragma unroll
    for (int nt = 0; nt < 4; ++nt) {
      int lc = wn * 64 + nt * 16 + mrow;
      float bv = buv[brow0 + lc];
#pragma unroll
      for (int reg = 0; reg < 4; ++reg) {
        int r = row0 + wm * 64 + mt * 16 + quad * 4 + reg;
        float val = silu_f(acc[mt][nt][reg] + bv);
        if (is_base) baseb[(size_t)r * 256 + dcol0 + lc] = val;
        else         dst16[(size_t)r * ldc_ + dcol0 + lc] = (_Float16)val;
      }
    }
  }
}

// ---------------- generic fp32 GEMM (fallback stage A + small tails) ----------------
__global__ __launch_bounds__(256) void gemm_f32(
    const float* __restrict__ A, int lda,
    const float* __restrict__ B, int ldb,
    float* __restrict__ C, int ldc,
    int M, int N, int K,
    const float* __restrict__ bias, int mode,
    const int* __restrict__ ids,
    const float* __restrict__ X,
    const float* __restrict__ alpha)
{
  __shared__ float As[16][68];
  __shared__ float Bs[16][68];
  int tid = threadIdx.x;
  int tx = tid & 15, ty = tid >> 4;
  int col0 = blockIdx.x * 64, row0 = blockIdx.y * 64;
  float acc[4][4] = {};
  int arow = tid >> 2;
  int ak   = (tid & 3) * 4;
  int bk   = tid >> 4;
  int bn   = (tid & 15) * 4;

  for (int kt = 0; kt < K; kt += 16) {
    float4 av = make_float4(0.f, 0.f, 0.f, 0.f);
    if (row0 + arow < M)
      av = *(const float4*)&A[(size_t)(row0 + arow) * lda + kt + ak];
    As[ak + 0][arow] = av.x; As[ak + 1][arow] = av.y;
    As[ak + 2][arow] = av.z; As[ak + 3][arow] = av.w;
    float4 bv = *(const float4*)&B[(size_t)(kt + bk) * ldb + col0 + bn];
    *(float4*)&Bs[bk][bn] = bv;
    __syncthreads();
#pragma unroll
    for (int k = 0; k < 16; ++k) {
      const float4 a4 = *(const float4*)&As[k][ty * 4];
      const float4 b4 = *(const float4*)&Bs[k][tx * 4];
      float a_[4] = {a4.x, a4.y, a4.z, a4.w};
      float b_[4] = {b4.x, b4.y, b4.z, b4.w};
#pragma unroll
      for (int i = 0; i < 4; ++i)
#pragma unroll
        for (int j = 0; j < 4; ++j)
          acc[i][j] = fmaf(a_[i], b_[j], acc[i][j]);
    }
    __syncthreads();
  }

#pragma unroll
  for (int i = 0; i < 4; ++i) {
    int r = row0 + ty * 4 + i;
    if (r >= M) continue;
#pragma unroll
    for (int j = 0; j < 4; ++j) {
      int c = col0 + tx * 4 + j;
      float val = acc[i][j] + (bias ? bias[c] : 0.0f);
      if (mode == OP_STORE) {
        C[(size_t)r * ldc + c] = val;
      } else if (mode == OP_SILU) {
        C[(size_t)r * ldc + c] = silu_f(val);
      } else if (mode == OP_RESID) {
        int hr = ids ? ids[r] : r;
        C[(size_t)hr * ldc + c] += val;
      } else { // OP_TR
        C[(size_t)r * ldc + c] = X[(size_t)r * ldc + c] + gelu_f(val) * alpha[0];
      }
    }
  }
}

// ---------------- weight transpose + cast: in(K x N f32) -> out(N x K f16) ----------
__global__ __launch_bounds__(256) void transpose_cast(
    const float* __restrict__ in, _Float16* __restrict__ out, int K, int N)
{
  in  += (size_t)blockIdx.z * K * N;
  out += (size_t)blockIdx.z * K * N;
  __shared__ float t[32][33];
  int k0 = blockIdx.y * 32, n0 = blockIdx.x * 32;
  int tx = threadIdx.x & 31, ty = threadIdx.x >> 5;
  for (int i = ty; i < 32; i += 8) {
    int k = k0 + i, n = n0 + tx;
    t[i][tx] = (k < K && n < N) ? in[(size_t)k * N + n] : 0.0f;
  }
  __syncthreads();
  for (int i = ty; i < 32; i += 8) {
    int n = n0 + i, k = k0 + tx;
    if (n < N && k < K) out[(size_t)n * K + k] = (_Float16)t[tx][i];
  }
}

// ---------------- weight transpose + hi/lo split ----------------
__global__ __launch_bounds__(256) void transpose_split(
    const float* __restrict__ in, _Float16* __restrict__ hi,
    _Float16* __restrict__ lo, int K, int N)
{
  __shared__ float t[32][33];
  int k0 = blockIdx.y * 32, n0 = blockIdx.x * 32;
  int tx = threadIdx.x & 31, ty = threadIdx.x >> 5;
  for (int i = ty; i < 32; i += 8) {
    int k = k0 + i, n = n0 + tx;
    t[i][tx] = (k < K && n < N) ? in[(size_t)k * N + n] : 0.0f;
  }
  __syncthreads();
  for (int i = ty; i < 32; i += 8) {
    int n = n0 + i, k = k0 + tx;
    if (n < N && k < K) {
      float x = t[tx][i];
      _Float16 h = (_Float16)x;
      hi[(size_t)n * K + k] = h;
      lo[(size_t)n * K + k] = (_Float16)(x - (float)h);
    }
  }
}

__global__ __launch_bounds__(256) void split_f16_kernel(
    const float* __restrict__ in, _Float16* __restrict__ hi,
    _Float16* __restrict__ lo, int n)
{
  int i = blockIdx.x * 256 + threadIdx.x;
  if (i < n) {
    float x = in[i];
    _Float16 h = (_Float16)x;
    hi[i] = h;
    lo[i] = (_Float16)(x - (float)h);
  }
}

// ---------------- layernorm over 512 + optional gather/leaky/norm2-out ----------
template <typename OUT>
__global__ __launch_bounds__(256) void ln_kernel(
    const float* __restrict__ src, const int* __restrict__ ids,
    OUT* __restrict__ dst, const float* __restrict__ g,
    const float* __restrict__ b, float eps, int leaky,
    float* __restrict__ nrm2)
{
  int r = blockIdx.x;
  int sr = ids ? ids[r] : r;
  int tid = threadIdx.x;
  float v0 = src[(size_t)sr * 512 + tid];
  float v1 = src[(size_t)sr * 512 + tid + 256];
  __shared__ float red[256], red2[256];
  red[tid] = v0 + v1;
  red2[tid] = v0 * v0 + v1 * v1;
  __syncthreads();
  for (int s = 128; s > 0; s >>= 1) {
    if (tid < s) { red[tid] += red[tid + s]; red2[tid] += red2[tid + s]; }
    __syncthreads();
  }
  float mean = red[0] * (1.0f / 512.0f);
  float var  = red2[0] * (1.0f / 512.0f) - mean * mean;
  float rs = rsqrtf(var + eps);
  float o0 = (v0 - mean) * rs * g[tid] + b[tid];
  float o1 = (v1 - mean) * rs * g[tid + 256] + b[tid + 256];
  if (leaky) {
    o0 = o0 > 0.0f ? o0 : 0.1f * o0;
    o1 = o1 > 0.0f ? o1 : 0.1f * o1;
  }
  dst[(size_t)r * 512 + tid] = (OUT)o0;
  dst[(size_t)r * 512 + tid + 256] = (OUT)o1;
  if (nrm2) {
    __syncthreads();
    red[tid] = o0 * o0 + o1 * o1;
    __syncthreads();
    for (int s = 128; s > 0; s >>= 1) {
      if (tid < s) red[tid] += red[tid + s];
      __syncthreads();
    }
    if (tid == 0) nrm2[r] = red[0];
  }
}

// ---------------- bitonic argsort of 4096 keys per sample ----------------
__global__ __launch_bounds__(1024) void sort_kernel(const float* __restrict__ norm2,
                                                    int* __restrict__ ids)
{
  __shared__ float key[4096];
  __shared__ int   val[4096];
  int s = blockIdx.x, tid = threadIdx.x;
  for (int i = tid; i < 4096; i += 1024) { key[i] = norm2[s * 4096 + i]; val[i] = i; }
  __syncthreads();
  for (int len = 2; len <= 4096; len <<= 1) {
    for (int j = len >> 1; j > 0; j >>= 1) {
      for (int t = tid; t < 2048; t += 1024) {
        int i1 = (t << 1) - (t & (j - 1));
        int i2 = i1 + j;
        bool up = ((i1 & len) == 0);
        float ka = key[i1], kb = key[i2];
        int va = val[i1], vb = val[i2];
        bool gt = (ka > kb) || (ka == kb && va > vb);
        if (gt == up) {
          key[i1] = kb; key[i2] = ka;
          val[i1] = vb; val[i2] = va;
        }
      }
      __syncthreads();
    }
  }
  for (int i = tid; i < 4096; i += 1024) ids[s * 4096 + i] = s * 4096 + val[i];
}

// ---------------- per-bucket attention scores: a = (relu(q k^T / 64))^2, f16 out ----
__global__ __launch_bounds__(256) void attn_kernel(
    const float* __restrict__ base, const float* __restrict__ gb,
    const float* __restrict__ bb, _Float16* __restrict__ a_out)
{
  int g = blockIdx.x, tid = threadIdx.x;
  int tx = tid & 15, ty = tid >> 4;
  __shared__ float qT[64][68], kT[64][68];
  float acc[4][4] = {};
  for (int s0 = 0; s0 < 256; s0 += 64) {
    for (int idx = tid; idx < 64 * 64; idx += 256) {
      int l = idx >> 6, s = idx & 63;
      float v = base[((size_t)g * 64 + l) * 256 + s0 + s];
      qT[s][l] = v * gb[s0 + s] + bb[s0 + s];
      kT[s][l] = v * gb[256 + s0 + s] + bb[256 + s0 + s];
    }
    __syncthreads();
#pragma unroll 4
    for (int s = 0; s < 64; ++s) {
      const float4 q4 = *(const float4*)&qT[s][ty * 4];
      const float4 k4 = *(const float4*)&kT[s][tx * 4];
      float q_[4] = {q4.x, q4.y, q4.z, q4.w};
      float k_[4] = {k4.x, k4.y, k4.z, k4.w};
#pragma unroll
      for (int i = 0; i < 4; ++i)
#pragma unroll
        for (int j = 0; j < 4; ++j)
          acc[i][j] = fmaf(q_[i], k_[j], acc[i][j]);
    }
    __syncthreads();
  }
#pragma unroll
  for (int i = 0; i < 4; ++i)
#pragma unroll
    for (int j = 0; j < 4; ++j) {
      float v = acc[i][j] * (1.0f / 64.0f);
      v = v > 0.0f ? v : 0.0f;
      v = v * v;
      a_out[((size_t)g * 64 + ty * 4 + i) * 64 + tx * 4 + j] = (_Float16)v;
    }
}

// ---------------- t = (a @ v) * u via MFMA; a,v,u,t f16. one wave per (64-col, bucket)
__global__ __launch_bounds__(64) void apply_mfma(
    const _Float16* __restrict__ a, const _Float16* __restrict__ v,
    const _Float16* __restrict__ u, _Float16* __restrict__ t, int CH)
{
  int g = blockIdx.y, e0 = blockIdx.x * 64, lane = threadIdx.x;
  __shared__ _Float16 vT[64][72];
  const _Float16* vrow = v + ((size_t)g * 64 + lane) * CH + e0;
  f16x8 vv[8];
#pragma unroll
  for (int ti = 0; ti < 8; ++ti) vv[ti] = *(const f16x8*)(vrow + ti * 8);
#pragma unroll
  for (int ti = 0; ti < 8; ++ti)
#pragma unroll
    for (int j = 0; j < 8; ++j) vT[ti * 8 + j][lane] = vv[ti][j];
  __syncthreads();

  int mrow = lane & 15, quad = lane >> 4;
  const _Float16* ag = a + (size_t)g * 4096;
  f32x4 acc[4][4] = {};
#pragma unroll
  for (int ks = 0; ks < 2; ++ks) {
    f16x8 af[4], bf[4];
#pragma unroll
    for (int mt = 0; mt < 4; ++mt)
      af[mt] = *(const f16x8*)(ag + (size_t)(mt * 16 + mrow) * 64 + ks * 32 + quad * 8);
#pragma unroll
    for (int nt = 0; nt < 4; ++nt)
      bf[nt] = *(const f16x8*)(&vT[nt * 16 + mrow][ks * 32 + quad * 8]);
#pragma unroll
    for (int mt = 0; mt < 4; ++mt)
#pragma unroll
      for (int nt = 0; nt < 4; ++nt)
        acc[mt][nt] = __builtin_amdgcn_mfma_f32_16x16x32_f16(
            af[mt], bf[nt], acc[mt][nt], 0, 0, 0);
  }
#pragma unroll
  for (int mt = 0; mt < 4; ++mt)
#pragma unroll
    for (int nt = 0; nt < 4; ++nt)
#pragma unroll
      for (int reg = 0; reg < 4; ++reg) {
        int r = mt * 16 + quad * 4 + reg;
        int c = e0 + nt * 16 + mrow;
        size_t idx = ((size_t)g * 64 + r) * CH + c;
        t[idx] = (_Float16)(acc[mt][nt][reg] * (float)u[idx]);
      }
}

// ---------------- mean over groups of 64 rows (optional gather) ----------------
__global__ __launch_bounds__(256) void bucketmean_kernel(
    const float* __restrict__ src, const int* __restrict__ ids,
    float* __restrict__ dst)
{
  int g = blockIdx.x, tid = threadIdx.x;
  float s0 = 0.0f, s1 = 0.0f;
  for (int i = 0; i < 64; ++i) {
    int r = g * 64 + i;
    if (ids) r = ids[r];
    s0 += src[(size_t)r * 512 + tid];
    s1 += src[(size_t)r * 512 + tid + 256];
  }
  dst[(size_t)g * 512 + tid] = s0 * (1.0f / 64.0f);
  dst[(size_t)g * 512 + tid + 256] = s1 * (1.0f / 64.0f);
}

__global__ void avg_kernel(const float* __restrict__ a, const float* __restrict__ b,
                           float* __restrict__ o, int n)
{
  int i = blockIdx.x * 256 + threadIdx.x;
  if (i < n) o[i] = 0.5f * (a[i] + b[i]);
}

__global__ void out_kernel(const float* __restrict__ y, const float* __restrict__ W,
                           const float* __restrict__ b, float* __restrict__ out)
{
  int tid = threadIdx.x;
  if (tid < 8) {
    int s = tid >> 1, j = tid & 1;
    float acc = b[j];
    for (int d = 0; d < 512; ++d) acc += y[s * 512 + d] * W[d * 2 + j];
    out[s * 2 + j] = acc;
  }
}

extern "C" void kernel_launch(void* const* d_in, const int* in_sizes, int n_in,
                              void* d_out, int out_size, void* d_ws, size_t ws_size,
                              hipStream_t stream)
{
  const float* xs       = (const float*)d_in[0];
  const float* W_in     = (const float*)d_in[1];
  const float* b_in     = (const float*)d_in[2];
  const float* ln_in_g  = (const float*)d_in[3];
  const float* ln_in_b  = (const float*)d_in[4];
  const float* blk_ln_g = (const float*)d_in[5];
  const float* blk_ln_b = (const float*)d_in[6];
  const float* blk_Wuv  = (const float*)d_in[7];
  const float* blk_buv  = (const float*)d_in[8];
  const float* blk_gam  = (const float*)d_in[9];
  const float* blk_bet  = (const float*)d_in[10];
  const float* blk_Wo   = (const float*)d_in[11];
  const float* blk_bo   = (const float*)d_in[12];
  const float* tr_W     = (const float*)d_in[13];
  const float* tr_b     = (const float*)d_in[14];
  const float* tr_a     = (const float*)d_in[15];
  const float* tr2_W    = (const float*)d_in[16];
  const float* tr2_b    = (const float*)d_in[17];
  const float* tr2_a    = (const float*)d_in[18];
  const float* out_W    = (const float*)d_in[19];
  const float* out_b    = (const float*)d_in[20];
  float* outp = (float*)d_out;

  const size_t R1 = R1C;

  // ---- persistent carve ----
  char* wsb = (char*)d_ws;
  size_t off = 0;
  auto carve = [&](size_t bytes) {
    char* r = wsb + off;
    off = (off + bytes + 255) & ~(size_t)255;
    return (void*)r;
  };
  float* h      = (float*)carve(R1 * 512 * 4);
  float* nb     = (float*)carve(R1 * 512 * 4);
  _Float16* nb_f16 = (_Float16*)nb;
  float* norm2b = (float*)carve(R1 * 4);
  int*   idsb   = (int*)carve(R1 * 4);
  float* gy     = (float*)carve((size_t)256 * 512 * 4);
  float* tl     = (float*)carve((size_t)256 * 512 * 4);
  float* gy2    = (float*)carve(4 * 512 * 4);
  float* ys0    = (float*)carve(4 * 512 * 4);
  float* ys1    = (float*)carve(4 * 512 * 4);
  float* yv     = (float*)carve(4 * 512 * 4);
  float* y2     = (float*)carve(4 * 512 * 4);
  _Float16* Wuvt = (_Float16*)carve((size_t)6 * 1792 * 512 * 2);
  _Float16* Wot  = (_Float16*)carve((size_t)6 * 512 * 768 * 2);
  size_t persistent = off;

  // ---- union region: stage-A split scratch OR per-block scratch ----
  size_t stageA_bytes = R1 * 768 * 2 * 2 + (size_t)512 * 768 * 2 * 2 + 1024;
  auto block_bytes = [&](size_t ch) {
    return R1 * 256 * 4 + (size_t)256 * 4096 * 2 + 3 * R1 * ch * 2 + 2048;
  };
  int CH = 0;
  bool splitA = false;
  const int cand[4] = {768, 384, 256, 128};
  for (int ci = 0; ci < 4; ++ci) {
    size_t bb2 = block_bytes(cand[ci]);
    size_t un = bb2 > stageA_bytes ? bb2 : stageA_bytes;
    if (persistent + un + 4096 <= ws_size) { CH = cand[ci]; splitA = true; break; }
  }
  if (!CH) {
    for (int ci = 0; ci < 4; ++ci)
      if (persistent + block_bytes(cand[ci]) + 4096 <= ws_size) { CH = cand[ci]; break; }
    if (!CH) CH = 128;
  }
  int nu = CH / 128;

  char* un = wsb + ((persistent + 255) & ~(size_t)255);
  // stage-A overlay
  _Float16* xs_hi = (_Float16*)un;
  _Float16* xs_lo = xs_hi + R1 * 768;
  _Float16* Wt_hi = xs_lo + R1 * 768;
  _Float16* Wt_lo = Wt_hi + (size_t)512 * 768;
  // block overlay (same memory; stage-A data dead by the time blocks run)
  float*    baseb = (float*)un;
  _Float16* ab16  = (_Float16*)(un + R1 * 256 * 4);
  _Float16* ub    = ab16 + (size_t)256 * 4096;
  _Float16* vb    = ub + R1 * (size_t)CH;
  _Float16* tb    = vb + R1 * (size_t)CH;

  dim3 blk(256);

  // ---- weight prep ----
  transpose_cast<<<dim3(56, 16, 6), blk, 0, stream>>>(blk_Wuv, Wuvt, 512, 1792);
  transpose_cast<<<dim3(16, 24, 6), blk, 0, stream>>>(blk_Wo, Wot, 768, 512);

  // ---- Stage A: input projection + LN(1e-8) + leaky + norm2 ----
  if (splitA) {
    split_f16_kernel<<<(int)(R1 * 768 / 256), blk, 0, stream>>>(xs, xs_hi, xs_lo,
                                                                (int)(R1 * 768));
    transpose_split<<<dim3(16, 24, 1), blk, 0, stream>>>(W_in, Wt_hi, Wt_lo, 768, 512);
    gemm_f16_split<<<dim3(4, 128), blk, 0, stream>>>(xs_hi, xs_lo, 768,
        Wt_hi, Wt_lo, 768, nb, 512, 768, b_in);
  } else {
    gemm_f32<<<dim3(8, 256), blk, 0, stream>>>(xs, 768, W_in, 512, nb, 512,
        16384, 512, 768, b_in, OP_STORE, nullptr, nullptr, nullptr);
  }
  ln_kernel<float><<<16384, 256, 0, stream>>>(nb, nullptr, h, ln_in_g, ln_in_b,
                                              1e-8f, 1, norm2b);
  sort_kernel<<<4, 1024, 0, stream>>>(norm2b, idsb);

  // ---- Iteration 1: 6 subnet blocks over 256 buckets ----
  for (int b = 0; b < 6; ++b) {
    const _Float16* Wuv_t = Wuvt + (size_t)b * 1792 * 512;
    const float*    buv   = blk_buv + b * 1792;
    const _Float16* Wo_t  = Wot + (size_t)b * 512 * 768;
    ln_kernel<_Float16><<<16384, 256, 0, stream>>>(h, idsb, nb_f16, blk_ln_g + b * 512,
                                                   blk_ln_b + b * 512, 1e-5f, 0, nullptr);
    for (int c0 = 0; c0 < 768; c0 += CH) {
      int incl = (c0 == 0) ? 2 : 0;
      gemm_f16_uvb<<<dim3(2 * nu + incl, 128), blk, 0, stream>>>(nb_f16, 512, Wuv_t,
          c0, nu, ub, vb, baseb, CH, 512, buv);
      if (c0 == 0)
        attn_kernel<<<256, 256, 0, stream>>>(baseb, blk_gam + b * 512,
                                             blk_bet + b * 512, ab16);
      apply_mfma<<<dim3(CH / 64, 256), 64, 0, stream>>>(ab16, vb, ub, tb, CH);
      const float* bo = (c0 + CH == 768) ? (blk_bo + b * 512) : nullptr;
      gemm_f16<<<dim3(4, 128), blk, 0, stream>>>(tb, CH, Wo_t + c0, 768,
          h, 512, CH, bo, OP_RESID, idsb);
    }
  }
  bucketmean_kernel<<<256, 256, 0, stream>>>(h, idsb, gy);

  // ---- ys0 = mean_buckets(tr_layer(gy)) ----
  gemm_f32<<<dim3(8, 4), blk, 0, stream>>>(gy, 512, tr_W, 512, tl, 512,
      256, 512, 512, tr_b, OP_TR, nullptr, gy, tr_a);
  bucketmean_kernel<<<4, 256, 0, stream>>>(tl, nullptr, ys0);

  // ---- Iteration 2: 64 rows/sample == 1 bucket; sort permutation provably cancels --
  for (int b = 0; b < 6; ++b) {
    const _Float16* Wuv_t = Wuvt + (size_t)b * 1792 * 512;
    const float*    buv   = blk_buv + b * 1792;
    const _Float16* Wo_t  = Wot + (size_t)b * 512 * 768;
    ln_kernel<_Float16><<<256, 256, 0, stream>>>(gy, nullptr, nb_f16, blk_ln_g + b * 512,
                                                 blk_ln_b + b * 512, 1e-5f, 0, nullptr);
    for (int c0 = 0; c0 < 768; c0 += CH) {
      int incl = (c0 == 0) ? 2 : 0;
      gemm_f16_uvb<<<dim3(2 * nu + incl, 2), blk, 0, stream>>>(nb_f16, 512, Wuv_t,
          c0, nu, ub, vb, baseb, CH, 512, buv);
      if (c0 == 0)
        attn_kernel<<<4, 256, 0, stream>>>(baseb, blk_gam + b * 512,
                                           blk_bet + b * 512, ab16);
      apply_mfma<<<dim3(CH / 64, 4), 64, 0, stream>>>(ab16, vb, ub, tb, CH);
      const float* bo = (c0 + CH == 768) ? (blk_bo + b * 512) : nullptr;
      gemm_f16<<<dim3(4, 2), blk, 0, stream>>>(tb, CH, Wo_t + c0, 768,
          gy, 512, CH, bo, OP_RESID, nullptr);
    }
  }
  bucketmean_kernel<<<4, 256, 0, stream>>>(gy, nullptr, gy2);

  // ---- tails ----
  gemm_f32<<<dim3(8, 1), blk, 0, stream>>>(gy2, 512, tr_W, 512, ys1, 512,
      4, 512, 512, tr_b, OP_TR, nullptr, gy2, tr_a);
  avg_kernel<<<8, 256, 0, stream>>>(ys0, ys1, yv, 2048);
  gemm_f32<<<dim3(8, 1), blk, 0, stream>>>(yv, 512, tr2_W, 512, y2, 512,
      4, 512, 512, tr2_b, OP_TR, nullptr, yv, tr2_a);
  out_kernel<<<1, 64, 0, stream>>>(y2, out_W, out_b, outp);
}

// Round 6
// 1867.288 us; speedup vs baseline: 3.5639x; 1.0690x over previous
//
#include <hip/hip_runtime.h>
#include <math.h>

#define R1C 16384

enum { OP_STORE = 0, OP_SILU = 1, OP_RESID = 2, OP_TR = 3 };

typedef _Float16 f16x8 __attribute__((ext_vector_type(8)));
typedef float f32x4 __attribute__((ext_vector_type(4)));

__device__ __forceinline__ float silu_f(float x) { return x / (1.0f + __expf(-x)); }
__device__ __forceinline__ float gelu_f(float x) {
  return 0.5f * x * (1.0f + erff(x * 0.70710678118654752f));
}

__device__ __forceinline__ void gll16(const void* g, const void* l) {
  __builtin_amdgcn_global_load_lds(
      (const __attribute__((address_space(1))) unsigned int*)g,
      (__attribute__((address_space(3))) unsigned int*)l, 16, 0, 0);
}

// swizzle: phys slot for (row m, kgroup kg) = m*4 + ((kg + (m>>1)) & 3)
// -> fragment ds_read_b128 is 2-way (free); staging stays 64B/row quarter-coalesced.

// ============ f16 MFMA GEMM: C(MxN f32) = A(MxK f16,row) @ Bt(NxK f16,row)^T ======
__global__ __launch_bounds__(256) void gemm_f16(
    const _Float16* __restrict__ A, int lda,
    const _Float16* __restrict__ Bt, int ldb,
    float* __restrict__ C, int ldc, int K,
    const float* __restrict__ bias, int mode,
    const int* __restrict__ ids)
{
  __shared__ _Float16 As[128 * 32];
  __shared__ _Float16 Bs[128 * 32];
  int tid = threadIdx.x;
  int lane = tid & 63, w = tid >> 6;
  int wm = w >> 1, wn = w & 1;
  int row0 = blockIdx.y * 128, col0 = blockIdx.x * 128;

  int p0 = w * 64 + lane;
  int p1 = 256 + w * 64 + lane;
  int m0 = p0 >> 2, k0e = (((p0 & 3) - (m0 >> 1)) & 3) * 8;
  int m1 = p1 >> 2, k1e = (((p1 & 3) - (m1 >> 1)) & 3) * 8;
  const _Float16* gA0 = A + (size_t)(row0 + m0) * lda + k0e;
  const _Float16* gA1 = A + (size_t)(row0 + m1) * lda + k1e;
  const _Float16* gB0 = Bt + (size_t)(col0 + m0) * ldb + k0e;
  const _Float16* gB1 = Bt + (size_t)(col0 + m1) * ldb + k1e;
  const _Float16* lA0 = As + (size_t)(w * 64) * 8;
  const _Float16* lA1 = As + (size_t)(256 + w * 64) * 8;
  const _Float16* lB0 = Bs + (size_t)(w * 64) * 8;
  const _Float16* lB1 = Bs + (size_t)(256 + w * 64) * 8;

  int mrow = lane & 15, quad = lane >> 4;
  const f16x8* aptr[4];
  const f16x8* bptr[4];
#pragma unroll
  for (int t = 0; t < 4; ++t) {
    int ml = wm * 64 + t * 16 + mrow;
    aptr[t] = (const f16x8*)(As + (size_t)(ml * 4 + ((quad + (ml >> 1)) & 3)) * 8);
    int nl = wn * 64 + t * 16 + mrow;
    bptr[t] = (const f16x8*)(Bs + (size_t)(nl * 4 + ((quad + (nl >> 1)) & 3)) * 8);
  }

  f32x4 acc[4][4] = {};

  for (int kt = 0; kt < K; kt += 32) {
    gll16(gA0, lA0); gll16(gA1, lA1);
    gll16(gB0, lB0); gll16(gB1, lB1);
    gA0 += 32; gA1 += 32; gB0 += 32; gB1 += 32;
    __syncthreads();
    f16x8 af[4], bfr[4];
#pragma unroll
    for (int t = 0; t < 4; ++t) { af[t] = *aptr[t]; bfr[t] = *bptr[t]; }
#pragma unroll
    for (int mt = 0; mt < 4; ++mt)
#pragma unroll
      for (int nt = 0; nt < 4; ++nt)
        acc[mt][nt] = __builtin_amdgcn_mfma_f32_16x16x32_f16(
            af[mt], bfr[nt], acc[mt][nt], 0, 0, 0);
    __syncthreads();
  }

#pragma unroll
  for (int mt = 0; mt < 4; ++mt) {
#pragma unroll
    for (int nt = 0; nt < 4; ++nt) {
      int c = col0 + wn * 64 + nt * 16 + mrow;
      float bv = bias ? bias[c] : 0.0f;
#pragma unroll
      for (int reg = 0; reg < 4; ++reg) {
        int r = row0 + wm * 64 + mt * 16 + quad * 4 + reg;
        float val = acc[mt][nt][reg] + bv;
        if (mode == OP_STORE) {
          C[(size_t)r * ldc + c] = val;
        } else if (mode == OP_SILU) {
          C[(size_t)r * ldc + c] = silu_f(val);
        } else { // OP_RESID
          int hr = ids ? ids[r] : r;
          C[(size_t)hr * ldc + c] += val;
        }
      }
    }
  }
}

// ============ split-f16 GEMM for stage A: C = (Ah+Al)@(Bh+Bl)^T, 3-term ==========
__global__ __launch_bounds__(256) void gemm_f16_split(
    const _Float16* __restrict__ Ah, const _Float16* __restrict__ Al, int lda,
    const _Float16* __restrict__ Bh, const _Float16* __restrict__ Bl, int ldb,
    float* __restrict__ C, int ldc, int K, const float* __restrict__ bias)
{
  __shared__ _Float16 AsH[128 * 32], AsL[128 * 32];
  __shared__ _Float16 BsH[128 * 32], BsL[128 * 32];
  int tid = threadIdx.x;
  int lane = tid & 63, w = tid >> 6;
  int wm = w >> 1, wn = w & 1;
  int row0 = blockIdx.y * 128, col0 = blockIdx.x * 128;

  int p0 = w * 64 + lane;
  int p1 = 256 + w * 64 + lane;
  int m0 = p0 >> 2, k0e = (((p0 & 3) - (m0 >> 1)) & 3) * 8;
  int m1 = p1 >> 2, k1e = (((p1 & 3) - (m1 >> 1)) & 3) * 8;
  size_t a0 = (size_t)(row0 + m0) * lda + k0e;
  size_t a1 = (size_t)(row0 + m1) * lda + k1e;
  size_t b0 = (size_t)(col0 + m0) * ldb + k0e;
  size_t b1 = (size_t)(col0 + m1) * ldb + k1e;
  size_t l0 = (size_t)(w * 64) * 8;
  size_t l1 = (size_t)(256 + w * 64) * 8;

  int mrow = lane & 15, quad = lane >> 4;
  size_t aoff[4], boff[4];
#pragma unroll
  for (int t = 0; t < 4; ++t) {
    int ml = wm * 64 + t * 16 + mrow;
    aoff[t] = (size_t)(ml * 4 + ((quad + (ml >> 1)) & 3)) * 8;
    int nl = wn * 64 + t * 16 + mrow;
    boff[t] = (size_t)(nl * 4 + ((quad + (nl >> 1)) & 3)) * 8;
  }

  f32x4 acc[4][4] = {};

  for (int kt = 0; kt < K; kt += 32) {
    gll16(Ah + a0, AsH + l0); gll16(Ah + a1, AsH + l1);
    gll16(Al + a0, AsL + l0); gll16(Al + a1, AsL + l1);
    gll16(Bh + b0, BsH + l0); gll16(Bh + b1, BsH + l1);
    gll16(Bl + b0, BsL + l0); gll16(Bl + b1, BsL + l1);
    a0 += 32; a1 += 32; b0 += 32; b1 += 32;
    __syncthreads();
    f16x8 ah[4], al_[4], bh[4], bl[4];
#pragma unroll
    for (int t = 0; t < 4; ++t) {
      ah[t]  = *(const f16x8*)(AsH + aoff[t]);
      al_[t] = *(const f16x8*)(AsL + aoff[t]);
      bh[t]  = *(const f16x8*)(BsH + boff[t]);
      bl[t]  = *(const f16x8*)(BsL + boff[t]);
    }
#pragma unroll
    for (int mt = 0; mt < 4; ++mt)
#pragma unroll
      for (int nt = 0; nt < 4; ++nt) {
        acc[mt][nt] = __builtin_amdgcn_mfma_f32_16x16x32_f16(
            ah[mt], bh[nt], acc[mt][nt], 0, 0, 0);
        acc[mt][nt] = __builtin_amdgcn_mfma_f32_16x16x32_f16(
            ah[mt], bl[nt], acc[mt][nt], 0, 0, 0);
        acc[mt][nt] = __builtin_amdgcn_mfma_f32_16x16x32_f16(
            al_[mt], bh[nt], acc[mt][nt], 0, 0, 0);
      }
    __syncthreads();
  }

#pragma unroll
  for (int mt = 0; mt < 4; ++mt)
#pragma unroll
    for (int nt = 0; nt < 4; ++nt) {
      int c = col0 + wn * 64 + nt * 16 + mrow;
      float bv = bias ? bias[c] : 0.0f;
#pragma unroll
      for (int reg = 0; reg < 4; ++reg) {
        int r = row0 + wm * 64 + mt * 16 + quad * 4 + reg;
        C[(size_t)r * ldc + c] = acc[mt][nt][reg] + bv;
      }
    }
}

// ============ fused UVB GEMM: silu(n @ Wuv + buv) -> u/v (f16), base (f32) ==========
__global__ __launch_bounds__(256) void gemm_f16_uvb(
    const _Float16* __restrict__ A, int lda,
    const _Float16* __restrict__ Bt,           // Wuv^T block (1792 x 512)
    int c0, int nu,
    _Float16* __restrict__ ub, _Float16* __restrict__ vb, float* __restrict__ baseb,
    int CH, int K, const float* __restrict__ buv)
{
  __shared__ _Float16 As[128 * 32];
  __shared__ _Float16 Bs[128 * 32];
  int tid = threadIdx.x;
  int lane = tid & 63, w = tid >> 6;
  int wm = w >> 1, wn = w & 1;
  int row0 = blockIdx.y * 128;

  int x = blockIdx.x;
  int xl, regbase, ldc_, is_base = 0;
  _Float16* dst16 = nullptr;
  if (x < nu)            { xl = x;          regbase = c0;        dst16 = ub; ldc_ = CH; }
  else if (x < 2 * nu)   { xl = x - nu;     regbase = 768 + c0;  dst16 = vb; ldc_ = CH; }
  else                   { xl = x - 2 * nu; regbase = 1536;      is_base = 1; ldc_ = 256; }
  int brow0 = regbase + xl * 128;
  int dcol0 = xl * 128;

  int p0 = w * 64 + lane;
  int p1 = 256 + w * 64 + lane;
  int m0 = p0 >> 2, k0e = (((p0 & 3) - (m0 >> 1)) & 3) * 8;
  int m1 = p1 >> 2, k1e = (((p1 & 3) - (m1 >> 1)) & 3) * 8;
  const _Float16* gA0 = A + (size_t)(row0 + m0) * lda + k0e;
  const _Float16* gA1 = A + (size_t)(row0 + m1) * lda + k1e;
  const _Float16* gB0 = Bt + (size_t)(brow0 + m0) * 512 + k0e;
  const _Float16* gB1 = Bt + (size_t)(brow0 + m1) * 512 + k1e;
  const _Float16* lA0 = As + (size_t)(w * 64) * 8;
  const _Float16* lA1 = As + (size_t)(256 + w * 64) * 8;
  const _Float16* lB0 = Bs + (size_t)(w * 64) * 8;
  const _Float16* lB1 = Bs + (size_t)(256 + w * 64) * 8;

  int mrow = lane & 15, quad = lane >> 4;
  const f16x8* aptr[4];
  const f16x8* bptr[4];
#pragma unroll
  for (int t = 0; t < 4; ++t) {
    int ml = wm * 64 + t * 16 + mrow;
    aptr[t] = (const f16x8*)(As + (size_t)(ml * 4 + ((quad + (ml >> 1)) & 3)) * 8);
    int nl = wn * 64 + t * 16 + mrow;
    bptr[t] = (const f16x8*)(Bs + (size_t)(nl * 4 + ((quad + (nl >> 1)) & 3)) * 8);
  }

  f32x4 acc[4][4] = {};

  for (int kt = 0; kt < K; kt += 32) {
    gll16(gA0, lA0); gll16(gA1, lA1);
    gll16(gB0, lB0); gll16(gB1, lB1);
    gA0 += 32; gA1 += 32; gB0 += 32; gB1 += 32;
    __syncthreads();
    f16x8 af[4], bfr[4];
#pragma unroll
    for (int t = 0; t < 4; ++t) { af[t] = *aptr[t]; bfr[t] = *bptr[t]; }
#pragma unroll
    for (int mt = 0; mt < 4; ++mt)
#pragma unroll
      for (int nt = 0; nt < 4; ++nt)
        acc[mt][nt] = __builtin_amdgcn_mfma_f32_16x16x32_f16(
            af[mt], bfr[nt], acc[mt][nt], 0, 0, 0);
    __syncthreads();
  }

#pragma unroll
  for (int mt = 0; mt < 4; ++mt) {
#pragma unroll
    for (int nt = 0; nt < 4; ++nt) {
      int lc = wn * 64 + nt * 16 + mrow;
      float bv = buv[brow0 + lc];
#pragma unroll
      for (int reg = 0; reg < 4; ++reg) {
        int r = row0 + wm * 64 + mt * 16 + quad * 4 + reg;
        float val = silu_f(acc[mt][nt][reg] + bv);
        if (is_base) baseb[(size_t)r * 256 + dcol0 + lc] = val;
        else         dst16[(size_t)r * ldc_ + dcol0 + lc] = (_Float16)val;
      }
    }
  }
}

// ============ fused attention: a = relu(qk^T/64)^2 in LDS, then t = (a@v)*u =========
// one workgroup per bucket; q,k,a f16; all MFMA.
__global__ __launch_bounds__(256) void attnapply_fused(
    const float* __restrict__ base, const float* __restrict__ gb,
    const float* __restrict__ bb, const _Float16* __restrict__ v,
    const _Float16* __restrict__ u, _Float16* __restrict__ t, int CH)
{
  __shared__ _Float16 smem[3 * 64 * 72];
  _Float16* qs = smem;               // [64][72] chunk of q (phase A)
  _Float16* ks = smem + 64 * 72;     // [64][72] chunk of k
  _Float16* al = smem + 2 * 64 * 72; // [64][72] a matrix
  _Float16* vT = smem;               // phase B: aliases qs (dead)

  int g = blockIdx.x, tid = threadIdx.x;
  int lane = tid & 63, w = tid >> 6;
  int mrow = lane & 15, quad = lane >> 4;
  int srow = tid >> 2, scol = (tid & 3) * 16;

  // ---- phase A: scores ----
  f32x4 acc[4] = {};
  for (int s0 = 0; s0 < 256; s0 += 64) {
    const float* bp = base + ((size_t)g * 64 + srow) * 256 + s0 + scol;
#pragma unroll
    for (int j4 = 0; j4 < 4; ++j4) {
      float4 xv = *(const float4*)(bp + j4 * 4);
      float xx[4] = {xv.x, xv.y, xv.z, xv.w};
#pragma unroll
      for (int j = 0; j < 4; ++j) {
        int s = s0 + scol + j4 * 4 + j;
        qs[srow * 72 + scol + j4 * 4 + j] = (_Float16)(xx[j] * gb[s] + bb[s]);
        ks[srow * 72 + scol + j4 * 4 + j] = (_Float16)(xx[j] * gb[256 + s] + bb[256 + s]);
      }
    }
    __syncthreads();
#pragma unroll
    for (int ks2 = 0; ks2 < 2; ++ks2) {
      f16x8 aq = *(const f16x8*)(qs + (w * 16 + mrow) * 72 + ks2 * 32 + quad * 8);
#pragma unroll
      for (int nt = 0; nt < 4; ++nt) {
        f16x8 bk = *(const f16x8*)(ks + (nt * 16 + mrow) * 72 + ks2 * 32 + quad * 8);
        acc[nt] = __builtin_amdgcn_mfma_f32_16x16x32_f16(aq, bk, acc[nt], 0, 0, 0);
      }
    }
    __syncthreads();
  }
  // epilogue -> a_lds (f16), C-layout: row=quad*4+reg, col=mrow
#pragma unroll
  for (int nt = 0; nt < 4; ++nt)
#pragma unroll
    for (int reg = 0; reg < 4; ++reg) {
      float val = acc[nt][reg] * (1.0f / 64.0f);
      val = val > 0.0f ? val : 0.0f;
      val = val * val;
      al[(w * 16 + quad * 4 + reg) * 72 + nt * 16 + mrow] = (_Float16)val;
    }
  __syncthreads();

  // ---- phase B: t = (a @ v) * u ----
  for (int e0 = 0; e0 < CH; e0 += 64) {
    const _Float16* vp = v + ((size_t)g * 64 + srow) * CH + e0 + scol;
    f16x8 x0 = *(const f16x8*)vp;
    f16x8 x1 = *(const f16x8*)(vp + 8);
#pragma unroll
    for (int j = 0; j < 8; ++j) {
      vT[(scol + j) * 72 + srow] = x0[j];
      vT[(scol + 8 + j) * 72 + srow] = x1[j];
    }
    __syncthreads();
    f32x4 acc2[4] = {};
#pragma unroll
    for (int ks2 = 0; ks2 < 2; ++ks2) {
      f16x8 af = *(const f16x8*)(al + (w * 16 + mrow) * 72 + ks2 * 32 + quad * 8);
#pragma unroll
      for (int nt = 0; nt < 4; ++nt) {
        f16x8 bf = *(const f16x8*)(vT + (nt * 16 + mrow) * 72 + ks2 * 32 + quad * 8);
        acc2[nt] = __builtin_amdgcn_mfma_f32_16x16x32_f16(af, bf, acc2[nt], 0, 0, 0);
      }
    }
#pragma unroll
    for (int nt = 0; nt < 4; ++nt)
#pragma unroll
      for (int reg = 0; reg < 4; ++reg) {
        int row = w * 16 + quad * 4 + reg;
        int col = e0 + nt * 16 + mrow;
        size_t idx = ((size_t)g * 64 + row) * CH + col;
        t[idx] = (_Float16)(acc2[nt][reg] * (float)u[idx]);
      }
    __syncthreads();
  }
}

// ---------------- generic fp32 GEMM (fallback stage A + small tails) ----------------
__global__ __launch_bounds__(256) void gemm_f32(
    const float* __restrict__ A, int lda,
    const float* __restrict__ B, int ldb,
    float* __restrict__ C, int ldc,
    int M, int N, int K,
    const float* __restrict__ bias, int mode,
    const int* __restrict__ ids,
    const float* __restrict__ X,
    const float* __restrict__ alpha)
{
  __shared__ float As[16][68];
  __shared__ float Bs[16][68];
  int tid = threadIdx.x;
  int tx = tid & 15, ty = tid >> 4;
  int col0 = blockIdx.x * 64, row0 = blockIdx.y * 64;
  float acc[4][4] = {};
  int arow = tid >> 2;
  int ak   = (tid & 3) * 4;
  int bk   = tid >> 4;
  int bn   = (tid & 15) * 4;

  for (int kt = 0; kt < K; kt += 16) {
    float4 av = make_float4(0.f, 0.f, 0.f, 0.f);
    if (row0 + arow < M)
      av = *(const float4*)&A[(size_t)(row0 + arow) * lda + kt + ak];
    As[ak + 0][arow] = av.x; As[ak + 1][arow] = av.y;
    As[ak + 2][arow] = av.z; As[ak + 3][arow] = av.w;
    float4 bv = *(const float4*)&B[(size_t)(kt + bk) * ldb + col0 + bn];
    *(float4*)&Bs[bk][bn] = bv;
    __syncthreads();
#pragma unroll
    for (int k = 0; k < 16; ++k) {
      const float4 a4 = *(const float4*)&As[k][ty * 4];
      const float4 b4 = *(const float4*)&Bs[k][tx * 4];
      float a_[4] = {a4.x, a4.y, a4.z, a4.w};
      float b_[4] = {b4.x, b4.y, b4.z, b4.w};
#pragma unroll
      for (int i = 0; i < 4; ++i)
#pragma unroll
        for (int j = 0; j < 4; ++j)
          acc[i][j] = fmaf(a_[i], b_[j], acc[i][j]);
    }
    __syncthreads();
  }

#pragma unroll
  for (int i = 0; i < 4; ++i) {
    int r = row0 + ty * 4 + i;
    if (r >= M) continue;
#pragma unroll
    for (int j = 0; j < 4; ++j) {
      int c = col0 + tx * 4 + j;
      float val = acc[i][j] + (bias ? bias[c] : 0.0f);
      if (mode == OP_STORE) {
        C[(size_t)r * ldc + c] = val;
      } else if (mode == OP_SILU) {
        C[(size_t)r * ldc + c] = silu_f(val);
      } else if (mode == OP_RESID) {
        int hr = ids ? ids[r] : r;
        C[(size_t)hr * ldc + c] += val;
      } else { // OP_TR
        C[(size_t)r * ldc + c] = X[(size_t)r * ldc + c] + gelu_f(val) * alpha[0];
      }
    }
  }
}

// ---------------- weight transpose + cast ----------------
__global__ __launch_bounds__(256) void transpose_cast(
    const float* __restrict__ in, _Float16* __restrict__ out, int K, int N)
{
  in  += (size_t)blockIdx.z * K * N;
  out += (size_t)blockIdx.z * K * N;
  __shared__ float t[32][33];
  int k0 = blockIdx.y * 32, n0 = blockIdx.x * 32;
  int tx = threadIdx.x & 31, ty = threadIdx.x >> 5;
  for (int i = ty; i < 32; i += 8) {
    int k = k0 + i, n = n0 + tx;
    t[i][tx] = (k < K && n < N) ? in[(size_t)k * N + n] : 0.0f;
  }
  __syncthreads();
  for (int i = ty; i < 32; i += 8) {
    int n = n0 + i, k = k0 + tx;
    if (n < N && k < K) out[(size_t)n * K + k] = (_Float16)t[tx][i];
  }
}

__global__ __launch_bounds__(256) void transpose_split(
    const float* __restrict__ in, _Float16* __restrict__ hi,
    _Float16* __restrict__ lo, int K, int N)
{
  __shared__ float t[32][33];
  int k0 = blockIdx.y * 32, n0 = blockIdx.x * 32;
  int tx = threadIdx.x & 31, ty = threadIdx.x >> 5;
  for (int i = ty; i < 32; i += 8) {
    int k = k0 + i, n = n0 + tx;
    t[i][tx] = (k < K && n < N) ? in[(size_t)k * N + n] : 0.0f;
  }
  __syncthreads();
  for (int i = ty; i < 32; i += 8) {
    int n = n0 + i, k = k0 + tx;
    if (n < N && k < K) {
      float x = t[tx][i];
      _Float16 h = (_Float16)x;
      hi[(size_t)n * K + k] = h;
      lo[(size_t)n * K + k] = (_Float16)(x - (float)h);
    }
  }
}

__global__ __launch_bounds__(256) void split_f16_kernel(
    const float* __restrict__ in, _Float16* __restrict__ hi,
    _Float16* __restrict__ lo, int n)
{
  int i = blockIdx.x * 256 + threadIdx.x;
  if (i < n) {
    float x = in[i];
    _Float16 h = (_Float16)x;
    hi[i] = h;
    lo[i] = (_Float16)(x - (float)h);
  }
}

// ---------------- layernorm over 512 + optional gather/leaky/norm2-out ----------
template <typename OUT>
__global__ __launch_bounds__(256) void ln_kernel(
    const float* __restrict__ src, const int* __restrict__ ids,
    OUT* __restrict__ dst, const float* __restrict__ g,
    const float* __restrict__ b, float eps, int leaky,
    float* __restrict__ nrm2)
{
  int r = blockIdx.x;
  int sr = ids ? ids[r] : r;
  int tid = threadIdx.x;
  float v0 = src[(size_t)sr * 512 + tid];
  float v1 = src[(size_t)sr * 512 + tid + 256];
  __shared__ float red[256], red2[256];
  red[tid] = v0 + v1;
  red2[tid] = v0 * v0 + v1 * v1;
  __syncthreads();
  for (int s = 128; s > 0; s >>= 1) {
    if (tid < s) { red[tid] += red[tid + s]; red2[tid] += red2[tid + s]; }
    __syncthreads();
  }
  float mean = red[0] * (1.0f / 512.0f);
  float var  = red2[0] * (1.0f / 512.0f) - mean * mean;
  float rs = rsqrtf(var + eps);
  float o0 = (v0 - mean) * rs * g[tid] + b[tid];
  float o1 = (v1 - mean) * rs * g[tid + 256] + b[tid + 256];
  if (leaky) {
    o0 = o0 > 0.0f ? o0 : 0.1f * o0;
    o1 = o1 > 0.0f ? o1 : 0.1f * o1;
  }
  dst[(size_t)r * 512 + tid] = (OUT)o0;
  dst[(size_t)r * 512 + tid + 256] = (OUT)o1;
  if (nrm2) {
    __syncthreads();
    red[tid] = o0 * o0 + o1 * o1;
    __syncthreads();
    for (int s = 128; s > 0; s >>= 1) {
      if (tid < s) red[tid] += red[tid + s];
      __syncthreads();
    }
    if (tid == 0) nrm2[r] = red[0];
  }
}

// ---------------- row gather: dst[r] = src[ids[r]] ----------------
__global__ __launch_bounds__(128) void permute_rows(
    const float* __restrict__ src, const int* __restrict__ ids,
    float* __restrict__ dst)
{
  int r = blockIdx.x, sr = ids[r];
  const float4* s = (const float4*)(src + (size_t)sr * 512);
  float4* d = (float4*)(dst + (size_t)r * 512);
  d[threadIdx.x] = s[threadIdx.x];
}

// ---------------- bitonic argsort of 4096 keys per sample ----------------
__global__ __launch_bounds__(1024) void sort_kernel(const float* __restrict__ norm2,
                                                    int* __restrict__ ids)
{
  __shared__ float key[4096];
  __shared__ int   val[4096];
  int s = blockIdx.x, tid = threadIdx.x;
  for (int i = tid; i < 4096; i += 1024) { key[i] = norm2[s * 4096 + i]; val[i] = i; }
  __syncthreads();
  for (int len = 2; len <= 4096; len <<= 1) {
    for (int j = len >> 1; j > 0; j >>= 1) {
      for (int t = tid; t < 2048; t += 1024) {
        int i1 = (t << 1) - (t & (j - 1));
        int i2 = i1 + j;
        bool up = ((i1 & len) == 0);
        float ka = key[i1], kb = key[i2];
        int va = val[i1], vb = val[i2];
        bool gt = (ka > kb) || (ka == kb && va > vb);
        if (gt == up) {
          key[i1] = kb; key[i2] = ka;
          val[i1] = vb; val[i2] = va;
        }
      }
      __syncthreads();
    }
  }
  for (int i = tid; i < 4096; i += 1024) ids[s * 4096 + i] = s * 4096 + val[i];
}

// ---------------- mean over groups of 64 rows (optional gather) ----------------
__global__ __launch_bounds__(256) void bucketmean_kernel(
    const float* __restrict__ src, const int* __restrict__ ids,
    float* __restrict__ dst)
{
  int g = blockIdx.x, tid = threadIdx.x;
  float s0 = 0.0f, s1 = 0.0f;
  for (int i = 0; i < 64; ++i) {
    int r = g * 64 + i;
    if (ids) r = ids[r];
    s0 += src[(size_t)r * 512 + tid];
    s1 += src[(size_t)r * 512 + tid + 256];
  }
  dst[(size_t)g * 512 + tid] = s0 * (1.0f / 64.0f);
  dst[(size_t)g * 512 + tid + 256] = s1 * (1.0f / 64.0f);
}

__global__ void avg_kernel(const float* __restrict__ a, const float* __restrict__ b,
                           float* __restrict__ o, int n)
{
  int i = blockIdx.x * 256 + threadIdx.x;
  if (i < n) o[i] = 0.5f * (a[i] + b[i]);
}

__global__ void out_kernel(const float* __restrict__ y, const float* __restrict__ W,
                           const float* __restrict__ b, float* __restrict__ out)
{
  int tid = threadIdx.x;
  if (tid < 8) {
    int s = tid >> 1, j = tid & 1;
    float acc = b[j];
    for (int d = 0; d < 512; ++d) acc += y[s * 512 + d] * W[d * 2 + j];
    out[s * 2 + j] = acc;
  }
}

extern "C" void kernel_launch(void* const* d_in, const int* in_sizes, int n_in,
                              void* d_out, int out_size, void* d_ws, size_t ws_size,
                              hipStream_t stream)
{
  const float* xs       = (const float*)d_in[0];
  const float* W_in     = (const float*)d_in[1];
  const float* b_in     = (const float*)d_in[2];
  const float* ln_in_g  = (const float*)d_in[3];
  const float* ln_in_b  = (const float*)d_in[4];
  const float* blk_ln_g = (const float*)d_in[5];
  const float* blk_ln_b = (const float*)d_in[6];
  const float* blk_Wuv  = (const float*)d_in[7];
  const float* blk_buv  = (const float*)d_in[8];
  const float* blk_gam  = (const float*)d_in[9];
  const float* blk_bet  = (const float*)d_in[10];
  const float* blk_Wo   = (const float*)d_in[11];
  const float* blk_bo   = (const float*)d_in[12];
  const float* tr_W     = (const float*)d_in[13];
  const float* tr_b     = (const float*)d_in[14];
  const float* tr_a     = (const float*)d_in[15];
  const float* tr2_W    = (const float*)d_in[16];
  const float* tr2_b    = (const float*)d_in[17];
  const float* tr2_a    = (const float*)d_in[18];
  const float* out_W    = (const float*)d_in[19];
  const float* out_b    = (const float*)d_in[20];
  float* outp = (float*)d_out;

  const size_t R1 = R1C;

  // ---- persistent carve ----
  char* wsb = (char*)d_ws;
  size_t off = 0;
  auto carve = [&](size_t bytes) {
    char* r = wsb + off;
    off = (off + bytes + 255) & ~(size_t)255;
    return (void*)r;
  };
  float* h      = (float*)carve(R1 * 512 * 4);   // unsorted residual (pre-permute)
  float* hslot  = (float*)carve(R1 * 512 * 4);   // sorted mode: hs; fallback: nb
  float* norm2b = (float*)carve(R1 * 4);
  int*   idsb   = (int*)carve(R1 * 4);
  float* gy     = (float*)carve((size_t)256 * 512 * 4);
  float* tl     = (float*)carve((size_t)256 * 512 * 4);
  float* gy2    = (float*)carve(4 * 512 * 4);
  float* ys0    = (float*)carve(4 * 512 * 4);
  float* ys1    = (float*)carve(4 * 512 * 4);
  float* yv     = (float*)carve(4 * 512 * 4);
  float* y2     = (float*)carve(4 * 512 * 4);
  _Float16* Wuvt = (_Float16*)carve((size_t)6 * 1792 * 512 * 2);
  _Float16* Wot  = (_Float16*)carve((size_t)6 * 512 * 768 * 2);
  size_t persistent = off;

  // ---- union sizing ----
  // sorted mode: stageA overlay = xs_hi/lo + Wt_hi/lo + nbA(f32)
  size_t stageA_sorted = 2 * R1 * 768 * 2 + 2 * (size_t)512 * 768 * 2 + R1 * 512 * 4 + 2048;
  size_t block768 = R1 * 256 * 4 + 3 * R1 * (size_t)768 * 2 + 2048;
  size_t un_sorted = stageA_sorted > block768 ? stageA_sorted : block768;
  bool sorted_mode = (persistent + un_sorted + 4096 <= ws_size);

  int CH = 768;
  bool splitA = true;
  if (!sorted_mode) {
    size_t stageA_fb = 2 * R1 * 768 * 2 + 2 * (size_t)512 * 768 * 2 + 1024;
    auto block_bytes = [&](size_t ch) {
      return R1 * 256 * 4 + 3 * R1 * ch * 2 + 2048;
    };
    CH = 0; splitA = false;
    const int cand[4] = {768, 384, 256, 128};
    for (int ci = 0; ci < 4; ++ci) {
      size_t bb2 = block_bytes(cand[ci]);
      size_t un2 = bb2 > stageA_fb ? bb2 : stageA_fb;
      if (persistent + un2 + 4096 <= ws_size) { CH = cand[ci]; splitA = true; break; }
    }
    if (!CH) {
      for (int ci = 0; ci < 4; ++ci)
        if (persistent + block_bytes(cand[ci]) + 4096 <= ws_size) { CH = cand[ci]; break; }
      if (!CH) CH = 128;
    }
  }
  int nu = CH / 128;

  char* un = wsb + ((persistent + 255) & ~(size_t)255);
  // stage-A overlay
  _Float16* xs_hi = (_Float16*)un;
  _Float16* xs_lo = xs_hi + R1 * 768;
  _Float16* Wt_hi = xs_lo + R1 * 768;
  _Float16* Wt_lo = Wt_hi + (size_t)512 * 768;
  float*    nbA   = sorted_mode ? (float*)(Wt_lo + (size_t)512 * 768) : hslot;
  // block overlay
  float*    baseb = (float*)un;
  _Float16* ub    = (_Float16*)(un + R1 * 256 * 4);
  _Float16* vb    = ub + R1 * (size_t)CH;
  _Float16* tb    = vb + R1 * (size_t)CH;
  // LN output n: sorted mode aliases tb (dead-range safe at CH=768); fallback uses hslot
  _Float16* nbuf  = sorted_mode ? tb : (_Float16*)hslot;
  // residual stream for iteration 1
  float* hres = sorted_mode ? hslot : h;
  const int* blkids = sorted_mode ? nullptr : idsb;

  dim3 blk(256);

  // ---- weight prep ----
  transpose_cast<<<dim3(56, 16, 6), blk, 0, stream>>>(blk_Wuv, Wuvt, 512, 1792);
  transpose_cast<<<dim3(16, 24, 6), blk, 0, stream>>>(blk_Wo, Wot, 768, 512);

  // ---- Stage A ----
  if (splitA) {
    split_f16_kernel<<<(int)(R1 * 768 / 256), blk, 0, stream>>>(xs, xs_hi, xs_lo,
                                                                (int)(R1 * 768));
    transpose_split<<<dim3(16, 24, 1), blk, 0, stream>>>(W_in, Wt_hi, Wt_lo, 768, 512);
    gemm_f16_split<<<dim3(4, 128), blk, 0, stream>>>(xs_hi, xs_lo, 768,
        Wt_hi, Wt_lo, 768, nbA, 512, 768, b_in);
  } else {
    gemm_f32<<<dim3(8, 256), blk, 0, stream>>>(xs, 768, W_in, 512, nbA, 512,
        16384, 512, 768, b_in, OP_STORE, nullptr, nullptr, nullptr);
  }
  ln_kernel<float><<<16384, 256, 0, stream>>>(nbA, nullptr, h, ln_in_g, ln_in_b,
                                              1e-8f, 1, norm2b);
  sort_kernel<<<4, 1024, 0, stream>>>(norm2b, idsb);
  if (sorted_mode)
    permute_rows<<<16384, 128, 0, stream>>>(h, idsb, hres);

  // ---- Iteration 1: 6 subnet blocks over 256 buckets ----
  for (int b = 0; b < 6; ++b) {
    const _Float16* Wuv_t = Wuvt + (size_t)b * 1792 * 512;
    const float*    buv   = blk_buv + b * 1792;
    const _Float16* Wo_t  = Wot + (size_t)b * 512 * 768;
    ln_kernel<_Float16><<<16384, 256, 0, stream>>>(hres, blkids, nbuf,
        blk_ln_g + b * 512, blk_ln_b + b * 512, 1e-5f, 0, nullptr);
    for (int c0 = 0; c0 < 768; c0 += CH) {
      int incl = (c0 == 0) ? 2 : 0;
      gemm_f16_uvb<<<dim3(2 * nu + incl, 128), blk, 0, stream>>>(nbuf, 512, Wuv_t,
          c0, nu, ub, vb, baseb, CH, 512, buv);
      attnapply_fused<<<256, 256, 0, stream>>>(baseb, blk_gam + b * 512,
          blk_bet + b * 512, vb, ub, tb, CH);
      const float* bo = (c0 + CH == 768) ? (blk_bo + b * 512) : nullptr;
      gemm_f16<<<dim3(4, 128), blk, 0, stream>>>(tb, CH, Wo_t + c0, 768,
          hres, 512, CH, bo, OP_RESID, blkids);
    }
  }
  bucketmean_kernel<<<256, 256, 0, stream>>>(hres, blkids, gy);

  // ---- ys0 = mean_buckets(tr_layer(gy)) ----
  gemm_f32<<<dim3(8, 4), blk, 0, stream>>>(gy, 512, tr_W, 512, tl, 512,
      256, 512, 512, tr_b, OP_TR, nullptr, gy, tr_a);
  bucketmean_kernel<<<4, 256, 0, stream>>>(tl, nullptr, ys0);

  // ---- Iteration 2: 64 rows/sample == 1 bucket; sort permutation cancels ----
  for (int b = 0; b < 6; ++b) {
    const _Float16* Wuv_t = Wuvt + (size_t)b * 1792 * 512;
    const float*    buv   = blk_buv + b * 1792;
    const _Float16* Wo_t  = Wot + (size_t)b * 512 * 768;
    ln_kernel<_Float16><<<256, 256, 0, stream>>>(gy, nullptr, nbuf, blk_ln_g + b * 512,
                                                 blk_ln_b + b * 512, 1e-5f, 0, nullptr);
    for (int c0 = 0; c0 < 768; c0 += CH) {
      int incl = (c0 == 0) ? 2 : 0;
      gemm_f16_uvb<<<dim3(2 * nu + incl, 2), blk, 0, stream>>>(nbuf, 512, Wuv_t,
          c0, nu, ub, vb, baseb, CH, 512, buv);
      attnapply_fused<<<4, 256, 0, stream>>>(baseb, blk_gam + b * 512,
          blk_bet + b * 512, vb, ub, tb, CH);
      const float* bo = (c0 + CH == 768) ? (blk_bo + b * 512) : nullptr;
      gemm_f16<<<dim3(4, 2), blk, 0, stream>>>(tb, CH, Wo_t + c0, 768,
          gy, 512, CH, bo, OP_RESID, nullptr);
    }
  }
  bucketmean_kernel<<<4, 256, 0, stream>>>(gy, nullptr, gy2);

  // ---- tails ----
  gemm_f32<<<dim3(8, 1), blk, 0, stream>>>(gy2, 512, tr_W, 512, ys1, 512,
      4, 512, 512, tr_b, OP_TR, nullptr, gy2, tr_a);
  avg_kernel<<<8, 256, 0, stream>>>(ys0, ys1, yv, 2048);
  gemm_f32<<<dim3(8, 1), blk, 0, stream>>>(yv, 512, tr2_W, 512, y2, 512,
      4, 512, 512, tr2_b, OP_TR, nullptr, yv, tr2_a);
  out_kernel<<<1, 64, 0, stream>>>(y2, out_W, out_b, outp);
}

// Round 7
// 1797.590 us; speedup vs baseline: 3.7020x; 1.0388x over previous
//
#include <hip/hip_runtime.h>
#include <math.h>

#define R1C 16384

enum { OP_STORE = 0, OP_SILU = 1, OP_RESID = 2, OP_TR = 3 };

typedef _Float16 f16x8 __attribute__((ext_vector_type(8)));
typedef float f32x4 __attribute__((ext_vector_type(4)));

__device__ __forceinline__ float silu_f(float x) { return x / (1.0f + __expf(-x)); }
__device__ __forceinline__ float gelu_f(float x) {
  return 0.5f * x * (1.0f + erff(x * 0.70710678118654752f));
}

__device__ __forceinline__ void gll16(const void* g, const void* l) {
  __builtin_amdgcn_global_load_lds(
      (const __attribute__((address_space(1))) unsigned int*)g,
      (__attribute__((address_space(3))) unsigned int*)l, 16, 0, 0);
}

// swizzle: phys slot for (row m, kgroup kg) = m*4 + ((kg + (m>>1)) & 3)
// -> fragment ds_read_b128 is 2-way (free); staging stays 64B/row quarter-coalesced.
// Double-buffered: one barrier/iter; tile k+1 staged while tile k computes.

// ============ f16 MFMA GEMM: C(MxN f32) = A(MxK f16,row) @ Bt(NxK f16,row)^T ======
__global__ __launch_bounds__(256) void gemm_f16(
    const _Float16* __restrict__ A, int lda,
    const _Float16* __restrict__ Bt, int ldb,
    float* __restrict__ C, int ldc, int K,
    const float* __restrict__ bias, int mode,
    const int* __restrict__ ids)
{
  const int BUF = 128 * 32;
  __shared__ _Float16 As[2 * BUF];
  __shared__ _Float16 Bs[2 * BUF];
  int tid = threadIdx.x;
  int lane = tid & 63, w = tid >> 6;
  int wm = w >> 1, wn = w & 1;
  int row0 = blockIdx.y * 128, col0 = blockIdx.x * 128;

  int p0 = w * 64 + lane;
  int p1 = 256 + w * 64 + lane;
  int m0 = p0 >> 2, k0e = (((p0 & 3) - (m0 >> 1)) & 3) * 8;
  int m1 = p1 >> 2, k1e = (((p1 & 3) - (m1 >> 1)) & 3) * 8;
  const _Float16* gA0 = A + (size_t)(row0 + m0) * lda + k0e;
  const _Float16* gA1 = A + (size_t)(row0 + m1) * lda + k1e;
  const _Float16* gB0 = Bt + (size_t)(col0 + m0) * ldb + k0e;
  const _Float16* gB1 = Bt + (size_t)(col0 + m1) * ldb + k1e;
  const _Float16* lA0 = As + (size_t)(w * 64) * 8;
  const _Float16* lA1 = As + (size_t)(256 + w * 64) * 8;
  const _Float16* lB0 = Bs + (size_t)(w * 64) * 8;
  const _Float16* lB1 = Bs + (size_t)(256 + w * 64) * 8;

  int mrow = lane & 15, quad = lane >> 4;
  const f16x8* aptr[4];
  const f16x8* bptr[4];
#pragma unroll
  for (int t = 0; t < 4; ++t) {
    int ml = wm * 64 + t * 16 + mrow;
    aptr[t] = (const f16x8*)(As + (size_t)(ml * 4 + ((quad + (ml >> 1)) & 3)) * 8);
    int nl = wn * 64 + t * 16 + mrow;
    bptr[t] = (const f16x8*)(Bs + (size_t)(nl * 4 + ((quad + (nl >> 1)) & 3)) * 8);
  }

  f32x4 acc[4][4] = {};

  // prologue: tile 0 -> buffer 0
  gll16(gA0, lA0); gll16(gA1, lA1);
  gll16(gB0, lB0); gll16(gB1, lB1);
  gA0 += 32; gA1 += 32; gB0 += 32; gB1 += 32;

  for (int kt = 0; kt < K; kt += 32) {
    int cur = (kt >> 5) & 1;
    __syncthreads();                       // drains tile-cur staging
    if (kt + 32 < K) {                     // stage tile k+1 into other buffer
      int nx = cur ^ 1;
      gll16(gA0, lA0 + nx * BUF); gll16(gA1, lA1 + nx * BUF);
      gll16(gB0, lB0 + nx * BUF); gll16(gB1, lB1 + nx * BUF);
      gA0 += 32; gA1 += 32; gB0 += 32; gB1 += 32;
    }
    int fo = cur * (BUF / 8);
    f16x8 af[4], bfr[4];
#pragma unroll
    for (int t = 0; t < 4; ++t) { af[t] = *(aptr[t] + fo); bfr[t] = *(bptr[t] + fo); }
#pragma unroll
    for (int mt = 0; mt < 4; ++mt)
#pragma unroll
      for (int nt = 0; nt < 4; ++nt)
        acc[mt][nt] = __builtin_amdgcn_mfma_f32_16x16x32_f16(
            af[mt], bfr[nt], acc[mt][nt], 0, 0, 0);
  }

#pragma unroll
  for (int mt = 0; mt < 4; ++mt) {
#pragma unroll
    for (int nt = 0; nt < 4; ++nt) {
      int c = col0 + wn * 64 + nt * 16 + mrow;
      float bv = bias ? bias[c] : 0.0f;
#pragma unroll
      for (int reg = 0; reg < 4; ++reg) {
        int r = row0 + wm * 64 + mt * 16 + quad * 4 + reg;
        float val = acc[mt][nt][reg] + bv;
        if (mode == OP_STORE) {
          C[(size_t)r * ldc + c] = val;
        } else if (mode == OP_SILU) {
          C[(size_t)r * ldc + c] = silu_f(val);
        } else { // OP_RESID
          int hr = ids ? ids[r] : r;
          C[(size_t)hr * ldc + c] += val;
        }
      }
    }
  }
}

// ============ split-f16 GEMM for stage A: C = (Ah+Al)@(Bh+Bl)^T, 3-term ==========
__global__ __launch_bounds__(256) void gemm_f16_split(
    const _Float16* __restrict__ Ah, const _Float16* __restrict__ Al, int lda,
    const _Float16* __restrict__ Bh, const _Float16* __restrict__ Bl, int ldb,
    float* __restrict__ C, int ldc, int K, const float* __restrict__ bias)
{
  const int BUF = 128 * 32;
  __shared__ _Float16 AsH[2 * BUF], AsL[2 * BUF];
  __shared__ _Float16 BsH[2 * BUF], BsL[2 * BUF];
  int tid = threadIdx.x;
  int lane = tid & 63, w = tid >> 6;
  int wm = w >> 1, wn = w & 1;
  int row0 = blockIdx.y * 128, col0 = blockIdx.x * 128;

  int p0 = w * 64 + lane;
  int p1 = 256 + w * 64 + lane;
  int m0 = p0 >> 2, k0e = (((p0 & 3) - (m0 >> 1)) & 3) * 8;
  int m1 = p1 >> 2, k1e = (((p1 & 3) - (m1 >> 1)) & 3) * 8;
  size_t a0 = (size_t)(row0 + m0) * lda + k0e;
  size_t a1 = (size_t)(row0 + m1) * lda + k1e;
  size_t b0 = (size_t)(col0 + m0) * ldb + k0e;
  size_t b1 = (size_t)(col0 + m1) * ldb + k1e;
  size_t l0 = (size_t)(w * 64) * 8;
  size_t l1 = (size_t)(256 + w * 64) * 8;

  int mrow = lane & 15, quad = lane >> 4;
  size_t aoff[4], boff[4];
#pragma unroll
  for (int t = 0; t < 4; ++t) {
    int ml = wm * 64 + t * 16 + mrow;
    aoff[t] = (size_t)(ml * 4 + ((quad + (ml >> 1)) & 3)) * 8;
    int nl = wn * 64 + t * 16 + mrow;
    boff[t] = (size_t)(nl * 4 + ((quad + (nl >> 1)) & 3)) * 8;
  }

  f32x4 acc[4][4] = {};

  gll16(Ah + a0, AsH + l0); gll16(Ah + a1, AsH + l1);
  gll16(Al + a0, AsL + l0); gll16(Al + a1, AsL + l1);
  gll16(Bh + b0, BsH + l0); gll16(Bh + b1, BsH + l1);
  gll16(Bl + b0, BsL + l0); gll16(Bl + b1, BsL + l1);
  a0 += 32; a1 += 32; b0 += 32; b1 += 32;

  for (int kt = 0; kt < K; kt += 32) {
    int cur = (kt >> 5) & 1;
    __syncthreads();
    if (kt + 32 < K) {
      int nx = cur ^ 1;
      size_t o = (size_t)nx * BUF;
      gll16(Ah + a0, AsH + l0 + o); gll16(Ah + a1, AsH + l1 + o);
      gll16(Al + a0, AsL + l0 + o); gll16(Al + a1, AsL + l1 + o);
      gll16(Bh + b0, BsH + l0 + o); gll16(Bh + b1, BsH + l1 + o);
      gll16(Bl + b0, BsL + l0 + o); gll16(Bl + b1, BsL + l1 + o);
      a0 += 32; a1 += 32; b0 += 32; b1 += 32;
    }
    size_t o = (size_t)cur * BUF;
    f16x8 ah[4], al_[4], bh[4], bl[4];
#pragma unroll
    for (int t = 0; t < 4; ++t) {
      ah[t]  = *(const f16x8*)(AsH + aoff[t] + o);
      al_[t] = *(const f16x8*)(AsL + aoff[t] + o);
      bh[t]  = *(const f16x8*)(BsH + boff[t] + o);
      bl[t]  = *(const f16x8*)(BsL + boff[t] + o);
    }
#pragma unroll
    for (int mt = 0; mt < 4; ++mt)
#pragma unroll
      for (int nt = 0; nt < 4; ++nt) {
        acc[mt][nt] = __builtin_amdgcn_mfma_f32_16x16x32_f16(
            ah[mt], bh[nt], acc[mt][nt], 0, 0, 0);
        acc[mt][nt] = __builtin_amdgcn_mfma_f32_16x16x32_f16(
            ah[mt], bl[nt], acc[mt][nt], 0, 0, 0);
        acc[mt][nt] = __builtin_amdgcn_mfma_f32_16x16x32_f16(
            al_[mt], bh[nt], acc[mt][nt], 0, 0, 0);
      }
  }

#pragma unroll
  for (int mt = 0; mt < 4; ++mt)
#pragma unroll
    for (int nt = 0; nt < 4; ++nt) {
      int c = col0 + wn * 64 + nt * 16 + mrow;
      float bv = bias ? bias[c] : 0.0f;
#pragma unroll
      for (int reg = 0; reg < 4; ++reg) {
        int r = row0 + wm * 64 + mt * 16 + quad * 4 + reg;
        C[(size_t)r * ldc + c] = acc[mt][nt][reg] + bv;
      }
    }
}

// ============ fused UVB GEMM: silu(n @ Wuv + buv) -> u/v (f16), base (f32) ==========
__global__ __launch_bounds__(256) void gemm_f16_uvb(
    const _Float16* __restrict__ A, int lda,
    const _Float16* __restrict__ Bt,           // Wuv^T block (1792 x 512)
    int c0, int nu,
    _Float16* __restrict__ ub, _Float16* __restrict__ vb, float* __restrict__ baseb,
    int CH, int K, const float* __restrict__ buv)
{
  const int BUF = 128 * 32;
  __shared__ _Float16 As[2 * BUF];
  __shared__ _Float16 Bs[2 * BUF];
  int tid = threadIdx.x;
  int lane = tid & 63, w = tid >> 6;
  int wm = w >> 1, wn = w & 1;
  int row0 = blockIdx.y * 128;

  int x = blockIdx.x;
  int xl, regbase, ldc_, is_base = 0;
  _Float16* dst16 = nullptr;
  if (x < nu)            { xl = x;          regbase = c0;        dst16 = ub; ldc_ = CH; }
  else if (x < 2 * nu)   { xl = x - nu;     regbase = 768 + c0;  dst16 = vb; ldc_ = CH; }
  else                   { xl = x - 2 * nu; regbase = 1536;      is_base = 1; ldc_ = 256; }
  int brow0 = regbase + xl * 128;
  int dcol0 = xl * 128;

  int p0 = w * 64 + lane;
  int p1 = 256 + w * 64 + lane;
  int m0 = p0 >> 2, k0e = (((p0 & 3) - (m0 >> 1)) & 3) * 8;
  int m1 = p1 >> 2, k1e = (((p1 & 3) - (m1 >> 1)) & 3) * 8;
  const _Float16* gA0 = A + (size_t)(row0 + m0) * lda + k0e;
  const _Float16* gA1 = A + (size_t)(row0 + m1) * lda + k1e;
  const _Float16* gB0 = Bt + (size_t)(brow0 + m0) * 512 + k0e;
  const _Float16* gB1 = Bt + (size_t)(brow0 + m1) * 512 + k1e;
  const _Float16* lA0 = As + (size_t)(w * 64) * 8;
  const _Float16* lA1 = As + (size_t)(256 + w * 64) * 8;
  const _Float16* lB0 = Bs + (size_t)(w * 64) * 8;
  const _Float16* lB1 = Bs + (size_t)(256 + w * 64) * 8;

  int mrow = lane & 15, quad = lane >> 4;
  const f16x8* aptr[4];
  const f16x8* bptr[4];
#pragma unroll
  for (int t = 0; t < 4; ++t) {
    int ml = wm * 64 + t * 16 + mrow;
    aptr[t] = (const f16x8*)(As + (size_t)(ml * 4 + ((quad + (ml >> 1)) & 3)) * 8);
    int nl = wn * 64 + t * 16 + mrow;
    bptr[t] = (const f16x8*)(Bs + (size_t)(nl * 4 + ((quad + (nl >> 1)) & 3)) * 8);
  }

  f32x4 acc[4][4] = {};

  gll16(gA0, lA0); gll16(gA1, lA1);
  gll16(gB0, lB0); gll16(gB1, lB1);
  gA0 += 32; gA1 += 32; gB0 += 32; gB1 += 32;

  for (int kt = 0; kt < K; kt += 32) {
    int cur = (kt >> 5) & 1;
    __syncthreads();
    if (kt + 32 < K) {
      int nx = cur ^ 1;
      gll16(gA0, lA0 + nx * BUF); gll16(gA1, lA1 + nx * BUF);
      gll16(gB0, lB0 + nx * BUF); gll16(gB1, lB1 + nx * BUF);
      gA0 += 32; gA1 += 32; gB0 += 32; gB1 += 32;
    }
    int fo = cur * (BUF / 8);
    f16x8 af[4], bfr[4];
#pragma unroll
    for (int t = 0; t < 4; ++t) { af[t] = *(aptr[t] + fo); bfr[t] = *(bptr[t] + fo); }
#pragma unroll
    for (int mt = 0; mt < 4; ++mt)
#pragma unroll
      for (int nt = 0; nt < 4; ++nt)
        acc[mt][nt] = __builtin_amdgcn_mfma_f32_16x16x32_f16(
            af[mt], bfr[nt], acc[mt][nt], 0, 0, 0);
  }

#pragma unroll
  for (int mt = 0; mt < 4; ++mt) {
#pragma unroll
    for (int nt = 0; nt < 4; ++nt) {
      int lc = wn * 64 + nt * 16 + mrow;
      float bv = buv[brow0 + lc];
#pragma unroll
      for (int reg = 0; reg < 4; ++reg) {
        int r = row0 + wm * 64 + mt * 16 + quad * 4 + reg;
        float val = silu_f(acc[mt][nt][reg] + bv);
        if (is_base) baseb[(size_t)r * 256 + dcol0 + lc] = val;
        else         dst16[(size_t)r * ldc_ + dcol0 + lc] = (_Float16)val;
      }
    }
  }
}

// ============ fused attention: a = relu(qk^T/64)^2 in LDS, then t = (a@v)*u =========
__global__ __launch_bounds__(256) void attnapply_fused(
    const float* __restrict__ base, const float* __restrict__ gb,
    const float* __restrict__ bb, const _Float16* __restrict__ v,
    const _Float16* __restrict__ u, _Float16* __restrict__ t, int CH)
{
  __shared__ _Float16 smem[3 * 64 * 72];
  _Float16* qs = smem;
  _Float16* ks = smem + 64 * 72;
  _Float16* al = smem + 2 * 64 * 72;
  _Float16* vT = smem;               // phase B aliases qs (dead)

  int g = blockIdx.x, tid = threadIdx.x;
  int lane = tid & 63, w = tid >> 6;
  int mrow = lane & 15, quad = lane >> 4;
  int srow = tid >> 2, scol = (tid & 3) * 16;

  // ---- phase A: scores ----
  f32x4 acc[4] = {};
  for (int s0 = 0; s0 < 256; s0 += 64) {
    const float* bp = base + ((size_t)g * 64 + srow) * 256 + s0 + scol;
#pragma unroll
    for (int j4 = 0; j4 < 4; ++j4) {
      float4 xv = *(const float4*)(bp + j4 * 4);
      float xx[4] = {xv.x, xv.y, xv.z, xv.w};
#pragma unroll
      for (int j = 0; j < 4; ++j) {
        int s = s0 + scol + j4 * 4 + j;
        qs[srow * 72 + scol + j4 * 4 + j] = (_Float16)(xx[j] * gb[s] + bb[s]);
        ks[srow * 72 + scol + j4 * 4 + j] = (_Float16)(xx[j] * gb[256 + s] + bb[256 + s]);
      }
    }
    __syncthreads();
#pragma unroll
    for (int ks2 = 0; ks2 < 2; ++ks2) {
      f16x8 aq = *(const f16x8*)(qs + (w * 16 + mrow) * 72 + ks2 * 32 + quad * 8);
#pragma unroll
      for (int nt = 0; nt < 4; ++nt) {
        f16x8 bk = *(const f16x8*)(ks + (nt * 16 + mrow) * 72 + ks2 * 32 + quad * 8);
        acc[nt] = __builtin_amdgcn_mfma_f32_16x16x32_f16(aq, bk, acc[nt], 0, 0, 0);
      }
    }
    __syncthreads();
  }
#pragma unroll
  for (int nt = 0; nt < 4; ++nt)
#pragma unroll
    for (int reg = 0; reg < 4; ++reg) {
      float val = acc[nt][reg] * (1.0f / 64.0f);
      val = val > 0.0f ? val : 0.0f;
      val = val * val;
      al[(w * 16 + quad * 4 + reg) * 72 + nt * 16 + mrow] = (_Float16)val;
    }
  __syncthreads();

  // ---- phase B: t = (a @ v) * u ----
  for (int e0 = 0; e0 < CH; e0 += 64) {
    const _Float16* vp = v + ((size_t)g * 64 + srow) * CH + e0 + scol;
    f16x8 x0 = *(const f16x8*)vp;
    f16x8 x1 = *(const f16x8*)(vp + 8);
#pragma unroll
    for (int j = 0; j < 8; ++j) {
      vT[(scol + j) * 72 + srow] = x0[j];
      vT[(scol + 8 + j) * 72 + srow] = x1[j];
    }
    __syncthreads();
    f32x4 acc2[4] = {};
#pragma unroll
    for (int ks2 = 0; ks2 < 2; ++ks2) {
      f16x8 af = *(const f16x8*)(al + (w * 16 + mrow) * 72 + ks2 * 32 + quad * 8);
#pragma unroll
      for (int nt = 0; nt < 4; ++nt) {
        f16x8 bf = *(const f16x8*)(vT + (nt * 16 + mrow) * 72 + ks2 * 32 + quad * 8);
        acc2[nt] = __builtin_amdgcn_mfma_f32_16x16x32_f16(af, bf, acc2[nt], 0, 0, 0);
      }
    }
#pragma unroll
    for (int nt = 0; nt < 4; ++nt)
#pragma unroll
      for (int reg = 0; reg < 4; ++reg) {
        int row = w * 16 + quad * 4 + reg;
        int col = e0 + nt * 16 + mrow;
        size_t idx = ((size_t)g * 64 + row) * CH + col;
        t[idx] = (_Float16)(acc2[nt][reg] * (float)u[idx]);
      }
    __syncthreads();
  }
}

// ---------------- generic fp32 GEMM (fallback stage A + small tails) ----------------
__global__ __launch_bounds__(256) void gemm_f32(
    const float* __restrict__ A, int lda,
    const float* __restrict__ B, int ldb,
    float* __restrict__ C, int ldc,
    int M, int N, int K,
    const float* __restrict__ bias, int mode,
    const int* __restrict__ ids,
    const float* __restrict__ X,
    const float* __restrict__ alpha)
{
  __shared__ float As[16][68];
  __shared__ float Bs[16][68];
  int tid = threadIdx.x;
  int tx = tid & 15, ty = tid >> 4;
  int col0 = blockIdx.x * 64, row0 = blockIdx.y * 64;
  float acc[4][4] = {};
  int arow = tid >> 2;
  int ak   = (tid & 3) * 4;
  int bk   = tid >> 4;
  int bn   = (tid & 15) * 4;

  for (int kt = 0; kt < K; kt += 16) {
    float4 av = make_float4(0.f, 0.f, 0.f, 0.f);
    if (row0 + arow < M)
      av = *(const float4*)&A[(size_t)(row0 + arow) * lda + kt + ak];
    As[ak + 0][arow] = av.x; As[ak + 1][arow] = av.y;
    As[ak + 2][arow] = av.z; As[ak + 3][arow] = av.w;
    float4 bv = *(const float4*)&B[(size_t)(kt + bk) * ldb + col0 + bn];
    *(float4*)&Bs[bk][bn] = bv;
    __syncthreads();
#pragma unroll
    for (int k = 0; k < 16; ++k) {
      const float4 a4 = *(const float4*)&As[k][ty * 4];
      const float4 b4 = *(const float4*)&Bs[k][tx * 4];
      float a_[4] = {a4.x, a4.y, a4.z, a4.w};
      float b_[4] = {b4.x, b4.y, b4.z, b4.w};
#pragma unroll
      for (int i = 0; i < 4; ++i)
#pragma unroll
        for (int j = 0; j < 4; ++j)
          acc[i][j] = fmaf(a_[i], b_[j], acc[i][j]);
    }
    __syncthreads();
  }

#pragma unroll
  for (int i = 0; i < 4; ++i) {
    int r = row0 + ty * 4 + i;
    if (r >= M) continue;
#pragma unroll
    for (int j = 0; j < 4; ++j) {
      int c = col0 + tx * 4 + j;
      float val = acc[i][j] + (bias ? bias[c] : 0.0f);
      if (mode == OP_STORE) {
        C[(size_t)r * ldc + c] = val;
      } else if (mode == OP_SILU) {
        C[(size_t)r * ldc + c] = silu_f(val);
      } else if (mode == OP_RESID) {
        int hr = ids ? ids[r] : r;
        C[(size_t)hr * ldc + c] += val;
      } else { // OP_TR
        C[(size_t)r * ldc + c] = X[(size_t)r * ldc + c] + gelu_f(val) * alpha[0];
      }
    }
  }
}

// ---------------- weight transpose + cast ----------------
__global__ __launch_bounds__(256) void transpose_cast(
    const float* __restrict__ in, _Float16* __restrict__ out, int K, int N)
{
  in  += (size_t)blockIdx.z * K * N;
  out += (size_t)blockIdx.z * K * N;
  __shared__ float t[32][33];
  int k0 = blockIdx.y * 32, n0 = blockIdx.x * 32;
  int tx = threadIdx.x & 31, ty = threadIdx.x >> 5;
  for (int i = ty; i < 32; i += 8) {
    int k = k0 + i, n = n0 + tx;
    t[i][tx] = (k < K && n < N) ? in[(size_t)k * N + n] : 0.0f;
  }
  __syncthreads();
  for (int i = ty; i < 32; i += 8) {
    int n = n0 + i, k = k0 + tx;
    if (n < N && k < K) out[(size_t)n * K + k] = (_Float16)t[tx][i];
  }
}

__global__ __launch_bounds__(256) void transpose_split(
    const float* __restrict__ in, _Float16* __restrict__ hi,
    _Float16* __restrict__ lo, int K, int N)
{
  __shared__ float t[32][33];
  int k0 = blockIdx.y * 32, n0 = blockIdx.x * 32;
  int tx = threadIdx.x & 31, ty = threadIdx.x >> 5;
  for (int i = ty; i < 32; i += 8) {
    int k = k0 + i, n = n0 + tx;
    t[i][tx] = (k < K && n < N) ? in[(size_t)k * N + n] : 0.0f;
  }
  __syncthreads();
  for (int i = ty; i < 32; i += 8) {
    int n = n0 + i, k = k0 + tx;
    if (n < N && k < K) {
      float x = t[tx][i];
      _Float16 h = (_Float16)x;
      hi[(size_t)n * K + k] = h;
      lo[(size_t)n * K + k] = (_Float16)(x - (float)h);
    }
  }
}

__global__ __launch_bounds__(256) void split_f16_kernel(
    const float* __restrict__ in, _Float16* __restrict__ hi,
    _Float16* __restrict__ lo, int n)
{
  int i = blockIdx.x * 256 + threadIdx.x;
  if (i < n) {
    float x = in[i];
    _Float16 h = (_Float16)x;
    hi[i] = h;
    lo[i] = (_Float16)(x - (float)h);
  }
}

// ---------------- layernorm over 512 + optional gather/leaky/norm2-out ----------
template <typename OUT>
__global__ __launch_bounds__(256) void ln_kernel(
    const float* __restrict__ src, const int* __restrict__ ids,
    OUT* __restrict__ dst, const float* __restrict__ g,
    const float* __restrict__ b, float eps, int leaky,
    float* __restrict__ nrm2)
{
  int r = blockIdx.x;
  int sr = ids ? ids[r] : r;
  int tid = threadIdx.x;
  float v0 = src[(size_t)sr * 512 + tid];
  float v1 = src[(size_t)sr * 512 + tid + 256];
  __shared__ float red[256], red2[256];
  red[tid] = v0 + v1;
  red2[tid] = v0 * v0 + v1 * v1;
  __syncthreads();
  for (int s = 128; s > 0; s >>= 1) {
    if (tid < s) { red[tid] += red[tid + s]; red2[tid] += red2[tid + s]; }
    __syncthreads();
  }
  float mean = red[0] * (1.0f / 512.0f);
  float var  = red2[0] * (1.0f / 512.0f) - mean * mean;
  float rs = rsqrtf(var + eps);
  float o0 = (v0 - mean) * rs * g[tid] + b[tid];
  float o1 = (v1 - mean) * rs * g[tid + 256] + b[tid + 256];
  if (leaky) {
    o0 = o0 > 0.0f ? o0 : 0.1f * o0;
    o1 = o1 > 0.0f ? o1 : 0.1f * o1;
  }
  dst[(size_t)r * 512 + tid] = (OUT)o0;
  dst[(size_t)r * 512 + tid + 256] = (OUT)o1;
  if (nrm2) {
    __syncthreads();
    red[tid] = o0 * o0 + o1 * o1;
    __syncthreads();
    for (int s = 128; s > 0; s >>= 1) {
      if (tid < s) red[tid] += red[tid + s];
      __syncthreads();
    }
    if (tid == 0) nrm2[r] = red[0];
  }
}

// ---------------- row gather: dst[r] = src[ids[r]] ----------------
__global__ __launch_bounds__(128) void permute_rows(
    const float* __restrict__ src, const int* __restrict__ ids,
    float* __restrict__ dst)
{
  int r = blockIdx.x, sr = ids[r];
  const float4* s = (const float4*)(src + (size_t)sr * 512);
  float4* d = (float4*)(dst + (size_t)r * 512);
  d[threadIdx.x] = s[threadIdx.x];
}

// ---------------- bitonic argsort of 4096 keys per sample ----------------
__global__ __launch_bounds__(1024) void sort_kernel(const float* __restrict__ norm2,
                                                    int* __restrict__ ids)
{
  __shared__ float key[4096];
  __shared__ int   val[4096];
  int s = blockIdx.x, tid = threadIdx.x;
  for (int i = tid; i < 4096; i += 1024) { key[i] = norm2[s * 4096 + i]; val[i] = i; }
  __syncthreads();
  for (int len = 2; len <= 4096; len <<= 1) {
    for (int j = len >> 1; j > 0; j >>= 1) {
      for (int t = tid; t < 2048; t += 1024) {
        int i1 = (t << 1) - (t & (j - 1));
        int i2 = i1 + j;
        bool up = ((i1 & len) == 0);
        float ka = key[i1], kb = key[i2];
        int va = val[i1], vb = val[i2];
        bool gt = (ka > kb) || (ka == kb && va > vb);
        if (gt == up) {
          key[i1] = kb; key[i2] = ka;
          val[i1] = vb; val[i2] = va;
        }
      }
      __syncthreads();
    }
  }
  for (int i = tid; i < 4096; i += 1024) ids[s * 4096 + i] = s * 4096 + val[i];
}

// ---------------- mean over groups of 64 rows (optional gather) ----------------
__global__ __launch_bounds__(256) void bucketmean_kernel(
    const float* __restrict__ src, const int* __restrict__ ids,
    float* __restrict__ dst)
{
  int g = blockIdx.x, tid = threadIdx.x;
  float s0 = 0.0f, s1 = 0.0f;
  for (int i = 0; i < 64; ++i) {
    int r = g * 64 + i;
    if (ids) r = ids[r];
    s0 += src[(size_t)r * 512 + tid];
    s1 += src[(size_t)r * 512 + tid + 256];
  }
  dst[(size_t)g * 512 + tid] = s0 * (1.0f / 64.0f);
  dst[(size_t)g * 512 + tid + 256] = s1 * (1.0f / 64.0f);
}

__global__ void avg_kernel(const float* __restrict__ a, const float* __restrict__ b,
                           float* __restrict__ o, int n)
{
  int i = blockIdx.x * 256 + threadIdx.x;
  if (i < n) o[i] = 0.5f * (a[i] + b[i]);
}

__global__ void out_kernel(const float* __restrict__ y, const float* __restrict__ W,
                           const float* __restrict__ b, float* __restrict__ out)
{
  int tid = threadIdx.x;
  if (tid < 8) {
    int s = tid >> 1, j = tid & 1;
    float acc = b[j];
    for (int d = 0; d < 512; ++d) acc += y[s * 512 + d] * W[d * 2 + j];
    out[s * 2 + j] = acc;
  }
}

extern "C" void kernel_launch(void* const* d_in, const int* in_sizes, int n_in,
                              void* d_out, int out_size, void* d_ws, size_t ws_size,
                              hipStream_t stream)
{
  const float* xs       = (const float*)d_in[0];
  const float* W_in     = (const float*)d_in[1];
  const float* b_in     = (const float*)d_in[2];
  const float* ln_in_g  = (const float*)d_in[3];
  const float* ln_in_b  = (const float*)d_in[4];
  const float* blk_ln_g = (const float*)d_in[5];
  const float* blk_ln_b = (const float*)d_in[6];
  const float* blk_Wuv  = (const float*)d_in[7];
  const float* blk_buv  = (const float*)d_in[8];
  const float* blk_gam  = (const float*)d_in[9];
  const float* blk_bet  = (const float*)d_in[10];
  const float* blk_Wo   = (const float*)d_in[11];
  const float* blk_bo   = (const float*)d_in[12];
  const float* tr_W     = (const float*)d_in[13];
  const float* tr_b     = (const float*)d_in[14];
  const float* tr_a     = (const float*)d_in[15];
  const float* tr2_W    = (const float*)d_in[16];
  const float* tr2_b    = (const float*)d_in[17];
  const float* tr2_a    = (const float*)d_in[18];
  const float* out_W    = (const float*)d_in[19];
  const float* out_b    = (const float*)d_in[20];
  float* outp = (float*)d_out;

  const size_t R1 = R1C;

  // ---- persistent carve ----
  char* wsb = (char*)d_ws;
  size_t off = 0;
  auto carve = [&](size_t bytes) {
    char* r = wsb + off;
    off = (off + bytes + 255) & ~(size_t)255;
    return (void*)r;
  };
  float* h      = (float*)carve(R1 * 512 * 4);   // unsorted residual (pre-permute)
  float* hslot  = (float*)carve(R1 * 512 * 4);   // sorted mode: hs; fallback: nb
  float* norm2b = (float*)carve(R1 * 4);
  int*   idsb   = (int*)carve(R1 * 4);
  float* gy     = (float*)carve((size_t)256 * 512 * 4);
  float* tl     = (float*)carve((size_t)256 * 512 * 4);
  float* gy2    = (float*)carve(4 * 512 * 4);
  float* ys0    = (float*)carve(4 * 512 * 4);
  float* ys1    = (float*)carve(4 * 512 * 4);
  float* yv     = (float*)carve(4 * 512 * 4);
  float* y2     = (float*)carve(4 * 512 * 4);
  _Float16* Wuvt = (_Float16*)carve((size_t)6 * 1792 * 512 * 2);
  _Float16* Wot  = (_Float16*)carve((size_t)6 * 512 * 768 * 2);
  size_t persistent = off;

  // ---- union sizing ----
  size_t stageA_sorted = 2 * R1 * 768 * 2 + 2 * (size_t)512 * 768 * 2 + R1 * 512 * 4 + 2048;
  size_t block768 = R1 * 256 * 4 + 3 * R1 * (size_t)768 * 2 + 2048;
  size_t un_sorted = stageA_sorted > block768 ? stageA_sorted : block768;
  bool sorted_mode = (persistent + un_sorted + 4096 <= ws_size);

  int CH = 768;
  bool splitA = true;
  if (!sorted_mode) {
    size_t stageA_fb = 2 * R1 * 768 * 2 + 2 * (size_t)512 * 768 * 2 + 1024;
    auto block_bytes = [&](size_t ch) {
      return R1 * 256 * 4 + 3 * R1 * ch * 2 + 2048;
    };
    CH = 0; splitA = false;
    const int cand[4] = {768, 384, 256, 128};
    for (int ci = 0; ci < 4; ++ci) {
      size_t bb2 = block_bytes(cand[ci]);
      size_t un2 = bb2 > stageA_fb ? bb2 : stageA_fb;
      if (persistent + un2 + 4096 <= ws_size) { CH = cand[ci]; splitA = true; break; }
    }
    if (!CH) {
      for (int ci = 0; ci < 4; ++ci)
        if (persistent + block_bytes(cand[ci]) + 4096 <= ws_size) { CH = cand[ci]; break; }
      if (!CH) CH = 128;
    }
  }
  int nu = CH / 128;

  char* un = wsb + ((persistent + 255) & ~(size_t)255);
  // stage-A overlay
  _Float16* xs_hi = (_Float16*)un;
  _Float16* xs_lo = xs_hi + R1 * 768;
  _Float16* Wt_hi = xs_lo + R1 * 768;
  _Float16* Wt_lo = Wt_hi + (size_t)512 * 768;
  float*    nbA   = sorted_mode ? (float*)(Wt_lo + (size_t)512 * 768) : hslot;
  // block overlay
  float*    baseb = (float*)un;
  _Float16* ub    = (_Float16*)(un + R1 * 256 * 4);
  _Float16* vb    = ub + R1 * (size_t)CH;
  _Float16* tb    = vb + R1 * (size_t)CH;
  _Float16* nbuf  = sorted_mode ? tb : (_Float16*)hslot;
  float* hres = sorted_mode ? hslot : h;
  const int* blkids = sorted_mode ? nullptr : idsb;

  dim3 blk(256);

  // ---- weight prep ----
  transpose_cast<<<dim3(56, 16, 6), blk, 0, stream>>>(blk_Wuv, Wuvt, 512, 1792);
  transpose_cast<<<dim3(16, 24, 6), blk, 0, stream>>>(blk_Wo, Wot, 768, 512);

  // ---- Stage A ----
  if (splitA) {
    split_f16_kernel<<<(int)(R1 * 768 / 256), blk, 0, stream>>>(xs, xs_hi, xs_lo,
                                                                (int)(R1 * 768));
    transpose_split<<<dim3(16, 24, 1), blk, 0, stream>>>(W_in, Wt_hi, Wt_lo, 768, 512);
    gemm_f16_split<<<dim3(4, 128), blk, 0, stream>>>(xs_hi, xs_lo, 768,
        Wt_hi, Wt_lo, 768, nbA, 512, 768, b_in);
  } else {
    gemm_f32<<<dim3(8, 256), blk, 0, stream>>>(xs, 768, W_in, 512, nbA, 512,
        16384, 512, 768, b_in, OP_STORE, nullptr, nullptr, nullptr);
  }
  ln_kernel<float><<<16384, 256, 0, stream>>>(nbA, nullptr, h, ln_in_g, ln_in_b,
                                              1e-8f, 1, norm2b);
  sort_kernel<<<4, 1024, 0, stream>>>(norm2b, idsb);
  if (sorted_mode)
    permute_rows<<<16384, 128, 0, stream>>>(h, idsb, hres);

  // ---- Iteration 1: 6 subnet blocks over 256 buckets ----
  for (int b = 0; b < 6; ++b) {
    const _Float16* Wuv_t = Wuvt + (size_t)b * 1792 * 512;
    const float*    buv   = blk_buv + b * 1792;
    const _Float16* Wo_t  = Wot + (size_t)b * 512 * 768;
    ln_kernel<_Float16><<<16384, 256, 0, stream>>>(hres, blkids, nbuf,
        blk_ln_g + b * 512, blk_ln_b + b * 512, 1e-5f, 0, nullptr);
    for (int c0 = 0; c0 < 768; c0 += CH) {
      int incl = (c0 == 0) ? 2 : 0;
      gemm_f16_uvb<<<dim3(2 * nu + incl, 128), blk, 0, stream>>>(nbuf, 512, Wuv_t,
          c0, nu, ub, vb, baseb, CH, 512, buv);
      attnapply_fused<<<256, 256, 0, stream>>>(baseb, blk_gam + b * 512,
          blk_bet + b * 512, vb, ub, tb, CH);
      const float* bo = (c0 + CH == 768) ? (blk_bo + b * 512) : nullptr;
      gemm_f16<<<dim3(4, 128), blk, 0, stream>>>(tb, CH, Wo_t + c0, 768,
          hres, 512, CH, bo, OP_RESID, blkids);
    }
  }
  bucketmean_kernel<<<256, 256, 0, stream>>>(hres, blkids, gy);

  // ---- ys0 = mean_buckets(tr_layer(gy)) ----
  gemm_f32<<<dim3(8, 4), blk, 0, stream>>>(gy, 512, tr_W, 512, tl, 512,
      256, 512, 512, tr_b, OP_TR, nullptr, gy, tr_a);
  bucketmean_kernel<<<4, 256, 0, stream>>>(tl, nullptr, ys0);

  // ---- Iteration 2: 64 rows/sample == 1 bucket; sort permutation cancels ----
  for (int b = 0; b < 6; ++b) {
    const _Float16* Wuv_t = Wuvt + (size_t)b * 1792 * 512;
    const float*    buv   = blk_buv + b * 1792;
    const _Float16* Wo_t  = Wot + (size_t)b * 512 * 768;
    ln_kernel<_Float16><<<256, 256, 0, stream>>>(gy, nullptr, nbuf, blk_ln_g + b * 512,
                                                 blk_ln_b + b * 512, 1e-5f, 0, nullptr);
    for (int c0 = 0; c0 < 768; c0 += CH) {
      int incl = (c0 == 0) ? 2 : 0;
      gemm_f16_uvb<<<dim3(2 * nu + incl, 2), blk, 0, stream>>>(nbuf, 512, Wuv_t,
          c0, nu, ub, vb, baseb, CH, 512, buv);
      attnapply_fused<<<4, 256, 0, stream>>>(baseb, blk_gam + b * 512,
          blk_bet + b * 512, vb, ub, tb, CH);
      const float* bo = (c0 + CH == 768) ? (blk_bo + b * 512) : nullptr;
      gemm_f16<<<dim3(4, 2), blk, 0, stream>>>(tb, CH, Wo_t + c0, 768,
          gy, 512, CH, bo, OP_RESID, nullptr);
    }
  }
  bucketmean_kernel<<<4, 256, 0, stream>>>(gy, nullptr, gy2);

  // ---- tails ----
  gemm_f32<<<dim3(8, 1), blk, 0, stream>>>(gy2, 512, tr_W, 512, ys1, 512,
      4, 512, 512, tr_b, OP_TR, nullptr, gy2, tr_a);
  avg_kernel<<<8, 256, 0, stream>>>(ys0, ys1, yv, 2048);
  gemm_f32<<<dim3(8, 1), blk, 0, stream>>>(yv, 512, tr2_W, 512, y2, 512,
      4, 512, 512, tr2_b, OP_TR, nullptr, yv, tr2_a);
  out_kernel<<<1, 64, 0, stream>>>(y2, out_W, out_b, outp);
}

// Round 8
// 1612.265 us; speedup vs baseline: 4.1276x; 1.1149x over previous
//
#include <hip/hip_runtime.h>
#include <math.h>

#define R1C 16384

enum { OP_STORE = 0, OP_SILU = 1, OP_RESID = 2, OP_TR = 3 };

typedef _Float16 f16x8 __attribute__((ext_vector_type(8)));
typedef float f32x4 __attribute__((ext_vector_type(4)));

__device__ __forceinline__ float silu_f(float x) { return x / (1.0f + __expf(-x)); }
__device__ __forceinline__ float gelu_f(float x) {
  return 0.5f * x * (1.0f + erff(x * 0.70710678118654752f));
}

__device__ __forceinline__ void gll16(const void* g, const void* l) {
  __builtin_amdgcn_global_load_lds(
      (const __attribute__((address_space(1))) unsigned int*)g,
      (__attribute__((address_space(3))) unsigned int*)l, 16, 0, 0);
}

// swizzle: phys slot for (row m, kgroup kg) = m*4 + ((kg + (m>>1)) & 3); 2-way = free.
// 512-thread wgs: 8 waves x (2x4) 16x16 tiles -> acc 32 AGPR/wave -> ~50% occupancy.
// Double-buffered LDS, one barrier per K-iter.

// ============ f16 MFMA GEMM: C(MxN f32) = A(MxK f16,row) @ Bt(NxK f16,row)^T ======
__global__ __launch_bounds__(512) void gemm_f16(
    const _Float16* __restrict__ A, int lda,
    const _Float16* __restrict__ Bt, int ldb,
    float* __restrict__ C, int ldc, int K,
    const float* __restrict__ bias, int mode,
    const int* __restrict__ ids)
{
  const int BUF = 128 * 32;
  __shared__ _Float16 As[2 * BUF];
  __shared__ _Float16 Bs[2 * BUF];
  int tid = threadIdx.x;
  int lane = tid & 63, w = tid >> 6;        // 8 waves
  int wm = w >> 1, wn = w & 1;              // wm 0..3 (32-row strip), wn 0..1
  int row0 = blockIdx.y * 128, col0 = blockIdx.x * 128;

  int m0 = tid >> 2;
  int k0e = (((tid & 3) - (m0 >> 1)) & 3) * 8;
  const _Float16* gA0 = A + (size_t)(row0 + m0) * lda + k0e;
  const _Float16* gB0 = Bt + (size_t)(col0 + m0) * ldb + k0e;
  const _Float16* lA0 = As + (size_t)(w * 64) * 8;   // wave-uniform base; slot = tid
  const _Float16* lB0 = Bs + (size_t)(w * 64) * 8;

  int mrow = lane & 15, quad = lane >> 4;
  const f16x8* aptr[2];
  const f16x8* bptr[4];
#pragma unroll
  for (int t = 0; t < 2; ++t) {
    int ml = wm * 32 + t * 16 + mrow;
    aptr[t] = (const f16x8*)(As + (size_t)(ml * 4 + ((quad + (ml >> 1)) & 3)) * 8);
  }
#pragma unroll
  for (int nt = 0; nt < 4; ++nt) {
    int nl = wn * 64 + nt * 16 + mrow;
    bptr[nt] = (const f16x8*)(Bs + (size_t)(nl * 4 + ((quad + (nl >> 1)) & 3)) * 8);
  }

  f32x4 acc[2][4] = {};

  gll16(gA0, lA0); gll16(gB0, lB0);
  gA0 += 32; gB0 += 32;

  for (int kt = 0; kt < K; kt += 32) {
    int cur = (kt >> 5) & 1;
    __syncthreads();
    if (kt + 32 < K) {
      int nx = cur ^ 1;
      gll16(gA0, lA0 + nx * BUF); gll16(gB0, lB0 + nx * BUF);
      gA0 += 32; gB0 += 32;
    }
    int fo = cur * (BUF / 8);
    f16x8 af[2], bfr[4];
#pragma unroll
    for (int t = 0; t < 2; ++t) af[t] = *(aptr[t] + fo);
#pragma unroll
    for (int nt = 0; nt < 4; ++nt) bfr[nt] = *(bptr[nt] + fo);
#pragma unroll
    for (int mt = 0; mt < 2; ++mt)
#pragma unroll
      for (int nt = 0; nt < 4; ++nt)
        acc[mt][nt] = __builtin_amdgcn_mfma_f32_16x16x32_f16(
            af[mt], bfr[nt], acc[mt][nt], 0, 0, 0);
  }

#pragma unroll
  for (int mt = 0; mt < 2; ++mt) {
#pragma unroll
    for (int nt = 0; nt < 4; ++nt) {
      int c = col0 + wn * 64 + nt * 16 + mrow;
      float bv = bias ? bias[c] : 0.0f;
#pragma unroll
      for (int reg = 0; reg < 4; ++reg) {
        int r = row0 + wm * 32 + mt * 16 + quad * 4 + reg;
        float val = acc[mt][nt][reg] + bv;
        if (mode == OP_STORE) {
          C[(size_t)r * ldc + c] = val;
        } else if (mode == OP_SILU) {
          C[(size_t)r * ldc + c] = silu_f(val);
        } else { // OP_RESID
          int hr = ids ? ids[r] : r;
          C[(size_t)hr * ldc + c] += val;
        }
      }
    }
  }
}

// ============ split-f16 GEMM for stage A: C = (Ah+Al)@(Bh+Bl)^T, 3-term ==========
__global__ __launch_bounds__(512) void gemm_f16_split(
    const _Float16* __restrict__ Ah, const _Float16* __restrict__ Al, int lda,
    const _Float16* __restrict__ Bh, const _Float16* __restrict__ Bl, int ldb,
    float* __restrict__ C, int ldc, int K, const float* __restrict__ bias)
{
  const int BUF = 128 * 32;
  __shared__ _Float16 AsH[2 * BUF], AsL[2 * BUF];
  __shared__ _Float16 BsH[2 * BUF], BsL[2 * BUF];
  int tid = threadIdx.x;
  int lane = tid & 63, w = tid >> 6;
  int wm = w >> 1, wn = w & 1;
  int row0 = blockIdx.y * 128, col0 = blockIdx.x * 128;

  int m0 = tid >> 2;
  int k0e = (((tid & 3) - (m0 >> 1)) & 3) * 8;
  size_t a0 = (size_t)(row0 + m0) * lda + k0e;
  size_t b0 = (size_t)(col0 + m0) * ldb + k0e;
  size_t l0 = (size_t)(w * 64) * 8;

  int mrow = lane & 15, quad = lane >> 4;
  size_t aoff[2], boff[4];
#pragma unroll
  for (int t = 0; t < 2; ++t) {
    int ml = wm * 32 + t * 16 + mrow;
    aoff[t] = (size_t)(ml * 4 + ((quad + (ml >> 1)) & 3)) * 8;
  }
#pragma unroll
  for (int nt = 0; nt < 4; ++nt) {
    int nl = wn * 64 + nt * 16 + mrow;
    boff[nt] = (size_t)(nl * 4 + ((quad + (nl >> 1)) & 3)) * 8;
  }

  f32x4 acc[2][4] = {};

  gll16(Ah + a0, AsH + l0); gll16(Al + a0, AsL + l0);
  gll16(Bh + b0, BsH + l0); gll16(Bl + b0, BsL + l0);
  a0 += 32; b0 += 32;

  for (int kt = 0; kt < K; kt += 32) {
    int cur = (kt >> 5) & 1;
    __syncthreads();
    if (kt + 32 < K) {
      size_t o = (size_t)(cur ^ 1) * BUF;
      gll16(Ah + a0, AsH + l0 + o); gll16(Al + a0, AsL + l0 + o);
      gll16(Bh + b0, BsH + l0 + o); gll16(Bl + b0, BsL + l0 + o);
      a0 += 32; b0 += 32;
    }
    size_t o = (size_t)cur * BUF;
    f16x8 ah[2], al_[2], bh[4], bl[4];
#pragma unroll
    for (int t = 0; t < 2; ++t) {
      ah[t]  = *(const f16x8*)(AsH + aoff[t] + o);
      al_[t] = *(const f16x8*)(AsL + aoff[t] + o);
    }
#pragma unroll
    for (int nt = 0; nt < 4; ++nt) {
      bh[nt] = *(const f16x8*)(BsH + boff[nt] + o);
      bl[nt] = *(const f16x8*)(BsL + boff[nt] + o);
    }
#pragma unroll
    for (int mt = 0; mt < 2; ++mt)
#pragma unroll
      for (int nt = 0; nt < 4; ++nt) {
        acc[mt][nt] = __builtin_amdgcn_mfma_f32_16x16x32_f16(
            ah[mt], bh[nt], acc[mt][nt], 0, 0, 0);
        acc[mt][nt] = __builtin_amdgcn_mfma_f32_16x16x32_f16(
            ah[mt], bl[nt], acc[mt][nt], 0, 0, 0);
        acc[mt][nt] = __builtin_amdgcn_mfma_f32_16x16x32_f16(
            al_[mt], bh[nt], acc[mt][nt], 0, 0, 0);
      }
  }

#pragma unroll
  for (int mt = 0; mt < 2; ++mt)
#pragma unroll
    for (int nt = 0; nt < 4; ++nt) {
      int c = col0 + wn * 64 + nt * 16 + mrow;
      float bv = bias ? bias[c] : 0.0f;
#pragma unroll
      for (int reg = 0; reg < 4; ++reg) {
        int r = row0 + wm * 32 + mt * 16 + quad * 4 + reg;
        C[(size_t)r * ldc + c] = acc[mt][nt][reg] + bv;
      }
    }
}

// ============ fused UVB GEMM: silu(n @ Wuv + buv) -> u/v (f16), base (f32) ==========
__global__ __launch_bounds__(512) void gemm_f16_uvb(
    const _Float16* __restrict__ A, int lda,
    const _Float16* __restrict__ Bt,           // Wuv^T block (1792 x 512)
    int c0, int nu,
    _Float16* __restrict__ ub, _Float16* __restrict__ vb, float* __restrict__ baseb,
    int CH, int K, const float* __restrict__ buv)
{
  const int BUF = 128 * 32;
  __shared__ _Float16 As[2 * BUF];
  __shared__ _Float16 Bs[2 * BUF];
  int tid = threadIdx.x;
  int lane = tid & 63, w = tid >> 6;
  int wm = w >> 1, wn = w & 1;
  int row0 = blockIdx.y * 128;

  int x = blockIdx.x;
  int xl, regbase, ldc_, is_base = 0;
  _Float16* dst16 = nullptr;
  if (x < nu)            { xl = x;          regbase = c0;        dst16 = ub; ldc_ = CH; }
  else if (x < 2 * nu)   { xl = x - nu;     regbase = 768 + c0;  dst16 = vb; ldc_ = CH; }
  else                   { xl = x - 2 * nu; regbase = 1536;      is_base = 1; ldc_ = 256; }
  int brow0 = regbase + xl * 128;
  int dcol0 = xl * 128;

  int m0 = tid >> 2;
  int k0e = (((tid & 3) - (m0 >> 1)) & 3) * 8;
  const _Float16* gA0 = A + (size_t)(row0 + m0) * lda + k0e;
  const _Float16* gB0 = Bt + (size_t)(brow0 + m0) * 512 + k0e;
  const _Float16* lA0 = As + (size_t)(w * 64) * 8;
  const _Float16* lB0 = Bs + (size_t)(w * 64) * 8;

  int mrow = lane & 15, quad = lane >> 4;
  const f16x8* aptr[2];
  const f16x8* bptr[4];
#pragma unroll
  for (int t = 0; t < 2; ++t) {
    int ml = wm * 32 + t * 16 + mrow;
    aptr[t] = (const f16x8*)(As + (size_t)(ml * 4 + ((quad + (ml >> 1)) & 3)) * 8);
  }
#pragma unroll
  for (int nt = 0; nt < 4; ++nt) {
    int nl = wn * 64 + nt * 16 + mrow;
    bptr[nt] = (const f16x8*)(Bs + (size_t)(nl * 4 + ((quad + (nl >> 1)) & 3)) * 8);
  }

  f32x4 acc[2][4] = {};

  gll16(gA0, lA0); gll16(gB0, lB0);
  gA0 += 32; gB0 += 32;

  for (int kt = 0; kt < K; kt += 32) {
    int cur = (kt >> 5) & 1;
    __syncthreads();
    if (kt + 32 < K) {
      int nx = cur ^ 1;
      gll16(gA0, lA0 + nx * BUF); gll16(gB0, lB0 + nx * BUF);
      gA0 += 32; gB0 += 32;
    }
    int fo = cur * (BUF / 8);
    f16x8 af[2], bfr[4];
#pragma unroll
    for (int t = 0; t < 2; ++t) af[t] = *(aptr[t] + fo);
#pragma unroll
    for (int nt = 0; nt < 4; ++nt) bfr[nt] = *(bptr[nt] + fo);
#pragma unroll
    for (int mt = 0; mt < 2; ++mt)
#pragma unroll
      for (int nt = 0; nt < 4; ++nt)
        acc[mt][nt] = __builtin_amdgcn_mfma_f32_16x16x32_f16(
            af[mt], bfr[nt], acc[mt][nt], 0, 0, 0);
  }

#pragma unroll
  for (int mt = 0; mt < 2; ++mt) {
#pragma unroll
    for (int nt = 0; nt < 4; ++nt) {
      int lc = wn * 64 + nt * 16 + mrow;
      float bv = buv[brow0 + lc];
#pragma unroll
      for (int reg = 0; reg < 4; ++reg) {
        int r = row0 + wm * 32 + mt * 16 + quad * 4 + reg;
        float val = silu_f(acc[mt][nt][reg] + bv);
        if (is_base) baseb[(size_t)r * 256 + dcol0 + lc] = val;
        else         dst16[(size_t)r * ldc_ + dcol0 + lc] = (_Float16)val;
      }
    }
  }
}

// ============ fused attention: a = relu(qk^T/64)^2 in LDS, then t = (a@v)*u =========
// grid (nch, n_buckets): each wg recomputes scores (cheap) and does ech cols of PV.
__global__ __launch_bounds__(256) void attnapply_fused(
    const float* __restrict__ base, const float* __restrict__ gb,
    const float* __restrict__ bb, const _Float16* __restrict__ v,
    const _Float16* __restrict__ u, _Float16* __restrict__ t, int CH, int ech)
{
  __shared__ _Float16 smem[3 * 64 * 72];
  _Float16* qs = smem;
  _Float16* ks = smem + 64 * 72;
  _Float16* al = smem + 2 * 64 * 72;
  _Float16* vT = smem;               // phase B aliases qs (dead)

  int g = blockIdx.y, tid = threadIdx.x;
  int e_lo = blockIdx.x * ech, e_hi = e_lo + ech;
  int lane = tid & 63, w = tid >> 6;
  int mrow = lane & 15, quad = lane >> 4;
  int srow = tid >> 2, scol = (tid & 3) * 16;

  // ---- phase A: scores ----
  f32x4 acc[4] = {};
  for (int s0 = 0; s0 < 256; s0 += 64) {
    const float* bp = base + ((size_t)g * 64 + srow) * 256 + s0 + scol;
#pragma unroll
    for (int j4 = 0; j4 < 4; ++j4) {
      float4 xv = *(const float4*)(bp + j4 * 4);
      float xx[4] = {xv.x, xv.y, xv.z, xv.w};
#pragma unroll
      for (int j = 0; j < 4; ++j) {
        int s = s0 + scol + j4 * 4 + j;
        qs[srow * 72 + scol + j4 * 4 + j] = (_Float16)(xx[j] * gb[s] + bb[s]);
        ks[srow * 72 + scol + j4 * 4 + j] = (_Float16)(xx[j] * gb[256 + s] + bb[256 + s]);
      }
    }
    __syncthreads();
#pragma unroll
    for (int ks2 = 0; ks2 < 2; ++ks2) {
      f16x8 aq = *(const f16x8*)(qs + (w * 16 + mrow) * 72 + ks2 * 32 + quad * 8);
#pragma unroll
      for (int nt = 0; nt < 4; ++nt) {
        f16x8 bk = *(const f16x8*)(ks + (nt * 16 + mrow) * 72 + ks2 * 32 + quad * 8);
        acc[nt] = __builtin_amdgcn_mfma_f32_16x16x32_f16(aq, bk, acc[nt], 0, 0, 0);
      }
    }
    __syncthreads();
  }
#pragma unroll
  for (int nt = 0; nt < 4; ++nt)
#pragma unroll
    for (int reg = 0; reg < 4; ++reg) {
      float val = acc[nt][reg] * (1.0f / 64.0f);
      val = val > 0.0f ? val : 0.0f;
      val = val * val;
      al[(w * 16 + quad * 4 + reg) * 72 + nt * 16 + mrow] = (_Float16)val;
    }
  __syncthreads();

  // ---- phase B: t = (a @ v) * u on [e_lo, e_hi) ----
  for (int e0 = e_lo; e0 < e_hi; e0 += 64) {
    const _Float16* vp = v + ((size_t)g * 64 + srow) * CH + e0 + scol;
    f16x8 x0 = *(const f16x8*)vp;
    f16x8 x1 = *(const f16x8*)(vp + 8);
#pragma unroll
    for (int j = 0; j < 8; ++j) {
      vT[(scol + j) * 72 + srow] = x0[j];
      vT[(scol + 8 + j) * 72 + srow] = x1[j];
    }
    __syncthreads();
    f32x4 acc2[4] = {};
#pragma unroll
    for (int ks2 = 0; ks2 < 2; ++ks2) {
      f16x8 af = *(const f16x8*)(al + (w * 16 + mrow) * 72 + ks2 * 32 + quad * 8);
#pragma unroll
      for (int nt = 0; nt < 4; ++nt) {
        f16x8 bf = *(const f16x8*)(vT + (nt * 16 + mrow) * 72 + ks2 * 32 + quad * 8);
        acc2[nt] = __builtin_amdgcn_mfma_f32_16x16x32_f16(af, bf, acc2[nt], 0, 0, 0);
      }
    }
#pragma unroll
    for (int nt = 0; nt < 4; ++nt)
#pragma unroll
      for (int reg = 0; reg < 4; ++reg) {
        int row = w * 16 + quad * 4 + reg;
        int col = e0 + nt * 16 + mrow;
        size_t idx = ((size_t)g * 64 + row) * CH + col;
        t[idx] = (_Float16)(acc2[nt][reg] * (float)u[idx]);
      }
    __syncthreads();
  }
}

// ---------------- generic fp32 GEMM (fallback stage A + small tails) ----------------
__global__ __launch_bounds__(256) void gemm_f32(
    const float* __restrict__ A, int lda,
    const float* __restrict__ B, int ldb,
    float* __restrict__ C, int ldc,
    int M, int N, int K,
    const float* __restrict__ bias, int mode,
    const int* __restrict__ ids,
    const float* __restrict__ X,
    const float* __restrict__ alpha)
{
  __shared__ float As[16][68];
  __shared__ float Bs[16][68];
  int tid = threadIdx.x;
  int tx = tid & 15, ty = tid >> 4;
  int col0 = blockIdx.x * 64, row0 = blockIdx.y * 64;
  float acc[4][4] = {};
  int arow = tid >> 2;
  int ak   = (tid & 3) * 4;
  int bk   = tid >> 4;
  int bn   = (tid & 15) * 4;

  for (int kt = 0; kt < K; kt += 16) {
    float4 av = make_float4(0.f, 0.f, 0.f, 0.f);
    if (row0 + arow < M)
      av = *(const float4*)&A[(size_t)(row0 + arow) * lda + kt + ak];
    As[ak + 0][arow] = av.x; As[ak + 1][arow] = av.y;
    As[ak + 2][arow] = av.z; As[ak + 3][arow] = av.w;
    float4 bv = *(const float4*)&B[(size_t)(kt + bk) * ldb + col0 + bn];
    *(float4*)&Bs[bk][bn] = bv;
    __syncthreads();
#pragma unroll
    for (int k = 0; k < 16; ++k) {
      const float4 a4 = *(const float4*)&As[k][ty * 4];
      const float4 b4 = *(const float4*)&Bs[k][tx * 4];
      float a_[4] = {a4.x, a4.y, a4.z, a4.w};
      float b_[4] = {b4.x, b4.y, b4.z, b4.w};
#pragma unroll
      for (int i = 0; i < 4; ++i)
#pragma unroll
        for (int j = 0; j < 4; ++j)
          acc[i][j] = fmaf(a_[i], b_[j], acc[i][j]);
    }
    __syncthreads();
  }

#pragma unroll
  for (int i = 0; i < 4; ++i) {
    int r = row0 + ty * 4 + i;
    if (r >= M) continue;
#pragma unroll
    for (int j = 0; j < 4; ++j) {
      int c = col0 + tx * 4 + j;
      float val = acc[i][j] + (bias ? bias[c] : 0.0f);
      if (mode == OP_STORE) {
        C[(size_t)r * ldc + c] = val;
      } else if (mode == OP_SILU) {
        C[(size_t)r * ldc + c] = silu_f(val);
      } else if (mode == OP_RESID) {
        int hr = ids ? ids[r] : r;
        C[(size_t)hr * ldc + c] += val;
      } else { // OP_TR
        C[(size_t)r * ldc + c] = X[(size_t)r * ldc + c] + gelu_f(val) * alpha[0];
      }
    }
  }
}

// ---------------- weight transpose + cast ----------------
__global__ __launch_bounds__(256) void transpose_cast(
    const float* __restrict__ in, _Float16* __restrict__ out, int K, int N)
{
  in  += (size_t)blockIdx.z * K * N;
  out += (size_t)blockIdx.z * K * N;
  __shared__ float t[32][33];
  int k0 = blockIdx.y * 32, n0 = blockIdx.x * 32;
  int tx = threadIdx.x & 31, ty = threadIdx.x >> 5;
  for (int i = ty; i < 32; i += 8) {
    int k = k0 + i, n = n0 + tx;
    t[i][tx] = (k < K && n < N) ? in[(size_t)k * N + n] : 0.0f;
  }
  __syncthreads();
  for (int i = ty; i < 32; i += 8) {
    int n = n0 + i, k = k0 + tx;
    if (n < N && k < K) out[(size_t)n * K + k] = (_Float16)t[tx][i];
  }
}

__global__ __launch_bounds__(256) void transpose_split(
    const float* __restrict__ in, _Float16* __restrict__ hi,
    _Float16* __restrict__ lo, int K, int N)
{
  __shared__ float t[32][33];
  int k0 = blockIdx.y * 32, n0 = blockIdx.x * 32;
  int tx = threadIdx.x & 31, ty = threadIdx.x >> 5;
  for (int i = ty; i < 32; i += 8) {
    int k = k0 + i, n = n0 + tx;
    t[i][tx] = (k < K && n < N) ? in[(size_t)k * N + n] : 0.0f;
  }
  __syncthreads();
  for (int i = ty; i < 32; i += 8) {
    int n = n0 + i, k = k0 + tx;
    if (n < N && k < K) {
      float x = t[tx][i];
      _Float16 h = (_Float16)x;
      hi[(size_t)n * K + k] = h;
      lo[(size_t)n * K + k] = (_Float16)(x - (float)h);
    }
  }
}

__global__ __launch_bounds__(256) void split_f16_kernel(
    const float* __restrict__ in, _Float16* __restrict__ hi,
    _Float16* __restrict__ lo, int n)
{
  int i = blockIdx.x * 256 + threadIdx.x;
  if (i < n) {
    float x = in[i];
    _Float16 h = (_Float16)x;
    hi[i] = h;
    lo[i] = (_Float16)(x - (float)h);
  }
}

// ---------------- layernorm over 512 + optional gather/leaky/norm2-out ----------
template <typename OUT>
__global__ __launch_bounds__(256) void ln_kernel(
    const float* __restrict__ src, const int* __restrict__ ids,
    OUT* __restrict__ dst, const float* __restrict__ g,
    const float* __restrict__ b, float eps, int leaky,
    float* __restrict__ nrm2)
{
  int r = blockIdx.x;
  int sr = ids ? ids[r] : r;
  int tid = threadIdx.x;
  float v0 = src[(size_t)sr * 512 + tid];
  float v1 = src[(size_t)sr * 512 + tid + 256];
  __shared__ float red[256], red2[256];
  red[tid] = v0 + v1;
  red2[tid] = v0 * v0 + v1 * v1;
  __syncthreads();
  for (int s = 128; s > 0; s >>= 1) {
    if (tid < s) { red[tid] += red[tid + s]; red2[tid] += red2[tid + s]; }
    __syncthreads();
  }
  float mean = red[0] * (1.0f / 512.0f);
  float var  = red2[0] * (1.0f / 512.0f) - mean * mean;
  float rs = rsqrtf(var + eps);
  float o0 = (v0 - mean) * rs * g[tid] + b[tid];
  float o1 = (v1 - mean) * rs * g[tid + 256] + b[tid + 256];
  if (leaky) {
    o0 = o0 > 0.0f ? o0 : 0.1f * o0;
    o1 = o1 > 0.0f ? o1 : 0.1f * o1;
  }
  dst[(size_t)r * 512 + tid] = (OUT)o0;
  dst[(size_t)r * 512 + tid + 256] = (OUT)o1;
  if (nrm2) {
    __syncthreads();
    red[tid] = o0 * o0 + o1 * o1;
    __syncthreads();
    for (int s = 128; s > 0; s >>= 1) {
      if (tid < s) red[tid] += red[tid + s];
      __syncthreads();
    }
    if (tid == 0) nrm2[r] = red[0];
  }
}

// ---------------- row gather: dst[r] = src[ids[r]] ----------------
__global__ __launch_bounds__(128) void permute_rows(
    const float* __restrict__ src, const int* __restrict__ ids,
    float* __restrict__ dst)
{
  int r = blockIdx.x, sr = ids[r];
  const float4* s = (const float4*)(src + (size_t)sr * 512);
  float4* d = (float4*)(dst + (size_t)r * 512);
  d[threadIdx.x] = s[threadIdx.x];
}

// ---------------- bitonic argsort of 4096 keys per sample ----------------
__global__ __launch_bounds__(1024) void sort_kernel(const float* __restrict__ norm2,
                                                    int* __restrict__ ids)
{
  __shared__ float key[4096];
  __shared__ int   val[4096];
  int s = blockIdx.x, tid = threadIdx.x;
  for (int i = tid; i < 4096; i += 1024) { key[i] = norm2[s * 4096 + i]; val[i] = i; }
  __syncthreads();
  for (int len = 2; len <= 4096; len <<= 1) {
    for (int j = len >> 1; j > 0; j >>= 1) {
      for (int t = tid; t < 2048; t += 1024) {
        int i1 = (t << 1) - (t & (j - 1));
        int i2 = i1 + j;
        bool up = ((i1 & len) == 0);
        float ka = key[i1], kb = key[i2];
        int va = val[i1], vb = val[i2];
        bool gt = (ka > kb) || (ka == kb && va > vb);
        if (gt == up) {
          key[i1] = kb; key[i2] = ka;
          val[i1] = vb; val[i2] = va;
        }
      }
      __syncthreads();
    }
  }
  for (int i = tid; i < 4096; i += 1024) ids[s * 4096 + i] = s * 4096 + val[i];
}

// ---------------- mean over groups of 64 rows (optional gather) ----------------
__global__ __launch_bounds__(256) void bucketmean_kernel(
    const float* __restrict__ src, const int* __restrict__ ids,
    float* __restrict__ dst)
{
  int g = blockIdx.x, tid = threadIdx.x;
  float s0 = 0.0f, s1 = 0.0f;
  for (int i = 0; i < 64; ++i) {
    int r = g * 64 + i;
    if (ids) r = ids[r];
    s0 += src[(size_t)r * 512 + tid];
    s1 += src[(size_t)r * 512 + tid + 256];
  }
  dst[(size_t)g * 512 + tid] = s0 * (1.0f / 64.0f);
  dst[(size_t)g * 512 + tid + 256] = s1 * (1.0f / 64.0f);
}

__global__ void avg_kernel(const float* __restrict__ a, const float* __restrict__ b,
                           float* __restrict__ o, int n)
{
  int i = blockIdx.x * 256 + threadIdx.x;
  if (i < n) o[i] = 0.5f * (a[i] + b[i]);
}

__global__ void out_kernel(const float* __restrict__ y, const float* __restrict__ W,
                           const float* __restrict__ b, float* __restrict__ out)
{
  int tid = threadIdx.x;
  if (tid < 8) {
    int s = tid >> 1, j = tid & 1;
    float acc = b[j];
    for (int d = 0; d < 512; ++d) acc += y[s * 512 + d] * W[d * 2 + j];
    out[s * 2 + j] = acc;
  }
}

extern "C" void kernel_launch(void* const* d_in, const int* in_sizes, int n_in,
                              void* d_out, int out_size, void* d_ws, size_t ws_size,
                              hipStream_t stream)
{
  const float* xs       = (const float*)d_in[0];
  const float* W_in     = (const float*)d_in[1];
  const float* b_in     = (const float*)d_in[2];
  const float* ln_in_g  = (const float*)d_in[3];
  const float* ln_in_b  = (const float*)d_in[4];
  const float* blk_ln_g = (const float*)d_in[5];
  const float* blk_ln_b = (const float*)d_in[6];
  const float* blk_Wuv  = (const float*)d_in[7];
  const float* blk_buv  = (const float*)d_in[8];
  const float* blk_gam  = (const float*)d_in[9];
  const float* blk_bet  = (const float*)d_in[10];
  const float* blk_Wo   = (const float*)d_in[11];
  const float* blk_bo   = (const float*)d_in[12];
  const float* tr_W     = (const float*)d_in[13];
  const float* tr_b     = (const float*)d_in[14];
  const float* tr_a     = (const float*)d_in[15];
  const float* tr2_W    = (const float*)d_in[16];
  const float* tr2_b    = (const float*)d_in[17];
  const float* tr2_a    = (const float*)d_in[18];
  const float* out_W    = (const float*)d_in[19];
  const float* out_b    = (const float*)d_in[20];
  float* outp = (float*)d_out;

  const size_t R1 = R1C;

  // ---- persistent carve ----
  char* wsb = (char*)d_ws;
  size_t off = 0;
  auto carve = [&](size_t bytes) {
    char* r = wsb + off;
    off = (off + bytes + 255) & ~(size_t)255;
    return (void*)r;
  };
  float* h      = (float*)carve(R1 * 512 * 4);   // unsorted residual (pre-permute)
  float* hslot  = (float*)carve(R1 * 512 * 4);   // sorted mode: hs; fallback: nb
  float* norm2b = (float*)carve(R1 * 4);
  int*   idsb   = (int*)carve(R1 * 4);
  float* gy     = (float*)carve((size_t)256 * 512 * 4);
  float* tl     = (float*)carve((size_t)256 * 512 * 4);
  float* gy2    = (float*)carve(4 * 512 * 4);
  float* ys0    = (float*)carve(4 * 512 * 4);
  float* ys1    = (float*)carve(4 * 512 * 4);
  float* yv     = (float*)carve(4 * 512 * 4);
  float* y2     = (float*)carve(4 * 512 * 4);
  _Float16* Wuvt = (_Float16*)carve((size_t)6 * 1792 * 512 * 2);
  _Float16* Wot  = (_Float16*)carve((size_t)6 * 512 * 768 * 2);
  size_t persistent = off;

  // ---- union sizing ----
  size_t stageA_sorted = 2 * R1 * 768 * 2 + 2 * (size_t)512 * 768 * 2 + R1 * 512 * 4 + 2048;
  size_t block768 = R1 * 256 * 4 + 3 * R1 * (size_t)768 * 2 + 2048;
  size_t un_sorted = stageA_sorted > block768 ? stageA_sorted : block768;
  bool sorted_mode = (persistent + un_sorted + 4096 <= ws_size);

  int CH = 768;
  bool splitA = true;
  if (!sorted_mode) {
    size_t stageA_fb = 2 * R1 * 768 * 2 + 2 * (size_t)512 * 768 * 2 + 1024;
    auto block_bytes = [&](size_t ch) {
      return R1 * 256 * 4 + 3 * R1 * ch * 2 + 2048;
    };
    CH = 0; splitA = false;
    const int cand[4] = {768, 384, 256, 128};
    for (int ci = 0; ci < 4; ++ci) {
      size_t bb2 = block_bytes(cand[ci]);
      size_t un2 = bb2 > stageA_fb ? bb2 : stageA_fb;
      if (persistent + un2 + 4096 <= ws_size) { CH = cand[ci]; splitA = true; break; }
    }
    if (!CH) {
      for (int ci = 0; ci < 4; ++ci)
        if (persistent + block_bytes(cand[ci]) + 4096 <= ws_size) { CH = cand[ci]; break; }
      if (!CH) CH = 128;
    }
  }
  int nu = CH / 128;
  int ech = CH >= 256 ? 256 : CH;     // attnapply chunk width
  int nch = CH / ech;

  char* un = wsb + ((persistent + 255) & ~(size_t)255);
  // stage-A overlay
  _Float16* xs_hi = (_Float16*)un;
  _Float16* xs_lo = xs_hi + R1 * 768;
  _Float16* Wt_hi = xs_lo + R1 * 768;
  _Float16* Wt_lo = Wt_hi + (size_t)512 * 768;
  float*    nbA   = sorted_mode ? (float*)(Wt_lo + (size_t)512 * 768) : hslot;
  // block overlay
  float*    baseb = (float*)un;
  _Float16* ub    = (_Float16*)(un + R1 * 256 * 4);
  _Float16* vb    = ub + R1 * (size_t)CH;
  _Float16* tb    = vb + R1 * (size_t)CH;
  _Float16* nbuf  = sorted_mode ? tb : (_Float16*)hslot;
  float* hres = sorted_mode ? hslot : h;
  const int* blkids = sorted_mode ? nullptr : idsb;

  dim3 blk(256);
  dim3 blk5(512);

  // ---- weight prep ----
  transpose_cast<<<dim3(56, 16, 6), blk, 0, stream>>>(blk_Wuv, Wuvt, 512, 1792);
  transpose_cast<<<dim3(16, 24, 6), blk, 0, stream>>>(blk_Wo, Wot, 768, 512);

  // ---- Stage A ----
  if (splitA) {
    split_f16_kernel<<<(int)(R1 * 768 / 256), blk, 0, stream>>>(xs, xs_hi, xs_lo,
                                                                (int)(R1 * 768));
    transpose_split<<<dim3(16, 24, 1), blk, 0, stream>>>(W_in, Wt_hi, Wt_lo, 768, 512);
    gemm_f16_split<<<dim3(4, 128), blk5, 0, stream>>>(xs_hi, xs_lo, 768,
        Wt_hi, Wt_lo, 768, nbA, 512, 768, b_in);
  } else {
    gemm_f32<<<dim3(8, 256), blk, 0, stream>>>(xs, 768, W_in, 512, nbA, 512,
        16384, 512, 768, b_in, OP_STORE, nullptr, nullptr, nullptr);
  }
  ln_kernel<float><<<16384, 256, 0, stream>>>(nbA, nullptr, h, ln_in_g, ln_in_b,
                                              1e-8f, 1, norm2b);
  sort_kernel<<<4, 1024, 0, stream>>>(norm2b, idsb);
  if (sorted_mode)
    permute_rows<<<16384, 128, 0, stream>>>(h, idsb, hres);

  // ---- Iteration 1: 6 subnet blocks over 256 buckets ----
  for (int b = 0; b < 6; ++b) {
    const _Float16* Wuv_t = Wuvt + (size_t)b * 1792 * 512;
    const float*    buv   = blk_buv + b * 1792;
    const _Float16* Wo_t  = Wot + (size_t)b * 512 * 768;
    ln_kernel<_Float16><<<16384, 256, 0, stream>>>(hres, blkids, nbuf,
        blk_ln_g + b * 512, blk_ln_b + b * 512, 1e-5f, 0, nullptr);
    for (int c0 = 0; c0 < 768; c0 += CH) {
      int incl = (c0 == 0) ? 2 : 0;
      gemm_f16_uvb<<<dim3(2 * nu + incl, 128), blk5, 0, stream>>>(nbuf, 512, Wuv_t,
          c0, nu, ub, vb, baseb, CH, 512, buv);
      attnapply_fused<<<dim3(nch, 256), blk, 0, stream>>>(baseb, blk_gam + b * 512,
          blk_bet + b * 512, vb, ub, tb, CH, ech);
      const float* bo = (c0 + CH == 768) ? (blk_bo + b * 512) : nullptr;
      gemm_f16<<<dim3(4, 128), blk5, 0, stream>>>(tb, CH, Wo_t + c0, 768,
          hres, 512, CH, bo, OP_RESID, blkids);
    }
  }
  bucketmean_kernel<<<256, 256, 0, stream>>>(hres, blkids, gy);

  // ---- ys0 = mean_buckets(tr_layer(gy)) ----
  gemm_f32<<<dim3(8, 4), blk, 0, stream>>>(gy, 512, tr_W, 512, tl, 512,
      256, 512, 512, tr_b, OP_TR, nullptr, gy, tr_a);
  bucketmean_kernel<<<4, 256, 0, stream>>>(tl, nullptr, ys0);

  // ---- Iteration 2: 64 rows/sample == 1 bucket; sort permutation cancels ----
  for (int b = 0; b < 6; ++b) {
    const _Float16* Wuv_t = Wuvt + (size_t)b * 1792 * 512;
    const float*    buv   = blk_buv + b * 1792;
    const _Float16* Wo_t  = Wot + (size_t)b * 512 * 768;
    ln_kernel<_Float16><<<256, 256, 0, stream>>>(gy, nullptr, nbuf, blk_ln_g + b * 512,
                                                 blk_ln_b + b * 512, 1e-5f, 0, nullptr);
    for (int c0 = 0; c0 < 768; c0 += CH) {
      int incl = (c0 == 0) ? 2 : 0;
      gemm_f16_uvb<<<dim3(2 * nu + incl, 2), blk5, 0, stream>>>(nbuf, 512, Wuv_t,
          c0, nu, ub, vb, baseb, CH, 512, buv);
      attnapply_fused<<<dim3(nch, 4), blk, 0, stream>>>(baseb, blk_gam + b * 512,
          blk_bet + b * 512, vb, ub, tb, CH, ech);
      const float* bo = (c0 + CH == 768) ? (blk_bo + b * 512) : nullptr;
      gemm_f16<<<dim3(4, 2), blk5, 0, stream>>>(tb, CH, Wo_t + c0, 768,
          gy, 512, CH, bo, OP_RESID, nullptr);
    }
  }
  bucketmean_kernel<<<4, 256, 0, stream>>>(gy, nullptr, gy2);

  // ---- tails ----
  gemm_f32<<<dim3(8, 1), blk, 0, stream>>>(gy2, 512, tr_W, 512, ys1, 512,
      4, 512, 512, tr_b, OP_TR, nullptr, gy2, tr_a);
  avg_kernel<<<8, 256, 0, stream>>>(ys0, ys1, yv, 2048);
  gemm_f32<<<dim3(8, 1), blk, 0, stream>>>(yv, 512, tr2_W, 512, y2, 512,
      4, 512, 512, tr2_b, OP_TR, nullptr, yv, tr2_a);
  out_kernel<<<1, 64, 0, stream>>>(y2, out_W, out_b, outp);
}